// Round 1
// baseline (3467.410 us; speedup 1.0000x reference)
//
#include <hip/hip_runtime.h>
#include <hip/hip_bf16.h>
#include <math.h>

// ---------------- Threefry-2x32 (JAX-exact, 20 rounds) ----------------
__device__ inline void threefry2x32(unsigned k0, unsigned k1,
                                    unsigned x0, unsigned x1,
                                    unsigned& o0, unsigned& o1) {
  unsigned ks[3] = {k0, k1, k0 ^ k1 ^ 0x1BD11BDAu};
  const int rot[2][4] = {{13, 15, 26, 6}, {17, 29, 16, 24}};
  x0 += ks[0];
  x1 += ks[1];
  #pragma unroll
  for (int i = 0; i < 5; i++) {
    const int* r = rot[i & 1];
    #pragma unroll
    for (int j = 0; j < 4; j++) {
      x0 += x1;
      x1 = (x1 << r[j]) | (x1 >> (32 - r[j]));
      x1 ^= x0;
    }
    x0 += ks[(i + 1) % 3];
    x1 += ks[(i + 2) % 3] + (unsigned)(i + 1);
  }
  o0 = x0;
  o1 = x1;
}

__global__ void idx_kernel(int* __restrict__ idx, int L, int U, int layer) {
  int total = L * U, half = total / 2;
  int i = blockIdx.x * blockDim.x + threadIdx.x;
  if (i >= half) return;
  unsigned k0, k1;
  threefry2x32(0u, 42u, 0u, (unsigned)layer, k0, k1);  // fold_in(key(42), l)
  unsigned o0, o1;
  threefry2x32(k0, k1, (unsigned)i, (unsigned)(half + i), o0, o1);
  idx[i] = (int)(o0 & (unsigned)(L - 1));          // span is pow2 -> bits & (L-1)
  idx[half + i] = (int)(o1 & (unsigned)(L - 1));
}

// ---------------- fp32 GEMM: C[M,N] = A[M,K] @ W[N,K]^T + bias (+R) (relu?) ----
__global__ __launch_bounds__(256) void gemm_kernel(
    const float* __restrict__ A, const float* __restrict__ W,
    const float* __restrict__ bias, const float* R, float* C,
    int M, int N, int K, int relu) {
  __shared__ float As[16][68];
  __shared__ float Ws[16][68];
  int tid = threadIdx.x;
  int row0 = blockIdx.x * 64, col0 = blockIdx.y * 64;
  int tx = tid & 15, ty = tid >> 4;
  int lr = tid >> 2, lc = (tid & 3) << 2;
  float acc[4][4] = {{0.f}};
  for (int k0 = 0; k0 < K; k0 += 16) {
    float4 av = *(const float4*)(A + (size_t)(row0 + lr) * K + k0 + lc);
    float4 wv = *(const float4*)(W + (size_t)(col0 + lr) * K + k0 + lc);
    __syncthreads();
    As[lc + 0][lr] = av.x; As[lc + 1][lr] = av.y; As[lc + 2][lr] = av.z; As[lc + 3][lr] = av.w;
    Ws[lc + 0][lr] = wv.x; Ws[lc + 1][lr] = wv.y; Ws[lc + 2][lr] = wv.z; Ws[lc + 3][lr] = wv.w;
    __syncthreads();
    #pragma unroll
    for (int kk = 0; kk < 16; kk++) {
      float4 a = *(const float4*)&As[kk][ty << 2];
      float4 b = *(const float4*)&Ws[kk][tx << 2];
      float av4[4] = {a.x, a.y, a.z, a.w};
      float bv4[4] = {b.x, b.y, b.z, b.w};
      #pragma unroll
      for (int i = 0; i < 4; i++)
        #pragma unroll
        for (int j = 0; j < 4; j++) acc[i][j] += av4[i] * bv4[j];
    }
  }
  #pragma unroll
  for (int i = 0; i < 4; i++) {
    int r = row0 + (ty << 2) + i;
    #pragma unroll
    for (int j = 0; j < 4; j++) {
      int c = col0 + (tx << 2) + j;
      float v = acc[i][j] + bias[c];
      if (R) v += R[(size_t)r * N + c];
      if (relu) v = fmaxf(v, 0.f);
      C[(size_t)r * N + c] = v;
    }
  }
}

// ---------------- embedding: circular conv (k=3, Cin=64) + positional enc ----
__global__ __launch_bounds__(256) void embed_kernel(
    const float* __restrict__ x_enc, const float* __restrict__ tok_w,
    float* __restrict__ X, int B, int L) {
  __shared__ float xr[3][64];
  int bt = blockIdx.x;
  int t = bt % L, b = bt / L;
  int tid = threadIdx.x;
  if (tid < 192) {
    int k = tid / 64, c = tid % 64;
    int ts = (t - 1 + k + L) % L;
    xr[k][c] = x_enc[((size_t)(b * L + ts)) * 64 + c] + 1e-10f;
  }
  __syncthreads();
  for (int o = tid; o < 512; o += 256) {
    float s = 0.f;
    const float* wp = tok_w + (size_t)o * 192;  // [o][c][k]
    #pragma unroll 4
    for (int c = 0; c < 64; c++) {
      s += xr[0][c] * wp[c * 3 + 0] + xr[1][c] * wp[c * 3 + 1] + xr[2][c] * wp[c * 3 + 2];
    }
    int i2 = o >> 1;
    float div = expf((float)(2 * i2) * (-9.210340371976184f / 512.f));
    float ang = (float)t * div;
    float pe = (o & 1) ? cosf(ang) : sinf(ang);
    X[(size_t)bt * 512 + o] = s + pe;
  }
}

// ---------------- K transpose per head: KT[b,h,d,t] = K[b,t,h*64+d] --------
__global__ __launch_bounds__(256) void transposeK_kernel(
    const float* __restrict__ Kf, float* __restrict__ KT, int B, int H, int L) {
  __shared__ float tile[64][65];
  int bh = blockIdx.y;
  int h = bh % H, b = bh / H;
  int t0 = blockIdx.x * 64;
  int tid = threadIdx.x;
  for (int it = 0; it < 16; it++) {
    int r = it * 4 + (tid >> 6), c = tid & 63;
    tile[r][c] = Kf[((size_t)(b * L + t0 + r)) * 512 + h * 64 + c];
  }
  __syncthreads();
  for (int it = 0; it < 16; it++) {
    int d = it * 4 + (tid >> 6), t = tid & 63;
    KT[((size_t)bh * 64 + d) * L + t0 + t] = tile[t][d];
  }
}

// ---------------- sparsity measure M (fp32, wave per (b,h,t)) --------------
__global__ __launch_bounds__(256) void sparsity_kernel(
    const float* __restrict__ Q, const float* __restrict__ Kf,
    const int* __restrict__ idx, float* __restrict__ M,
    int B, int H, int L, int U) {
  int gid = blockIdx.x * blockDim.x + threadIdx.x;
  int wid = gid >> 6;
  int lane = threadIdx.x & 63;
  if (wid >= B * H * L) return;
  int t = wid % L, h = (wid / L) % H, b = wid / (L * H);
  float dot = 0.f;
  if (lane < U) {
    int kt = idx[t * U + lane];
    const float* qrow = Q + ((size_t)(b * L + t)) * 512 + h * 64;
    const float* krow = Kf + ((size_t)(b * L + kt)) * 512 + h * 64;
    #pragma unroll 8
    for (int d = 0; d < 64; d++) dot += qrow[d] * krow[d];
  }
  float mx = (lane < U) ? dot : -INFINITY;
  float sm = (lane < U) ? dot : 0.f;
  #pragma unroll
  for (int off = 32; off; off >>= 1) {
    mx = fmaxf(mx, __shfl_xor(mx, off));
    sm += __shfl_xor(sm, off);
  }
  if (lane == 0) M[wid] = mx - sm / (float)L;
}

// ---------------- top-k (iterative argmax, block per (b,h)) ----------------
__global__ __launch_bounds__(256) void topk_kernel(
    const float* __restrict__ M, int* __restrict__ top, int L, int U) {
  __shared__ float mv[1024];
  __shared__ float rv[256];
  __shared__ int ri[256];
  int bh = blockIdx.x, tid = threadIdx.x;
  for (int t = tid; t < L; t += 256) mv[t] = M[(size_t)bh * L + t];
  __syncthreads();
  for (int it = 0; it < U; it++) {
    float bestv = -INFINITY;
    int besti = L;
    for (int t = tid; t < L; t += 256) {
      float v = mv[t];
      if (v > bestv || (v == bestv && t < besti)) { bestv = v; besti = t; }
    }
    rv[tid] = bestv; ri[tid] = besti;
    __syncthreads();
    for (int s = 128; s > 0; s >>= 1) {
      if (tid < s) {
        if (rv[tid + s] > rv[tid] || (rv[tid + s] == rv[tid] && ri[tid + s] < ri[tid])) {
          rv[tid] = rv[tid + s]; ri[tid] = ri[tid + s];
        }
      }
      __syncthreads();
    }
    if (tid == 0) { top[bh * U + it] = ri[0]; mv[ri[0]] = -INFINITY; }
    __syncthreads();
  }
}

// ---------------- V mean over t (block per (b,h)) --------------------------
__global__ void vmean_kernel(const float* __restrict__ V, float* __restrict__ Vmean,
                             int B, int H, int L) {
  int bh = blockIdx.x;
  int h = bh % H, b = bh / H;
  int d = threadIdx.x;
  float s = 0.f;
  const float* vb = V + (size_t)b * L * 512 + h * 64 + d;
  for (int t = 0; t < L; t++) s += vb[(size_t)t * 512];
  Vmean[bh * 64 + d] = s / (float)L;
}

// ---------------- broadcast ctx = Vmean ------------------------------------
__global__ void bcast_ctx_kernel(const float* __restrict__ Vmean, float* __restrict__ ATT,
                                 int B, int L) {
  size_t i = (size_t)blockIdx.x * 256 + threadIdx.x;
  if (i >= (size_t)B * L * 512) return;
  int c = (int)(i % 512);
  int b = (int)(i / ((size_t)512 * L));
  ATT[i] = Vmean[b * 512 + c];
}

// ---------------- full attention for top-u queries -------------------------
__global__ __launch_bounds__(256) void attn_kernel(
    const float* __restrict__ Q, const float* __restrict__ KT,
    const float* __restrict__ V, const int* __restrict__ top,
    float* __restrict__ ATT, int B, int H, int L, int U) {
  __shared__ float qs[64];
  __shared__ float sc[1024];
  __shared__ float red[256];
  int u = blockIdx.x % U, h = (blockIdx.x / U) % H, b = blockIdx.x / (U * H);
  int tid = threadIdx.x;
  int tq = top[(b * H + h) * U + u];
  if (tid < 64) qs[tid] = Q[((size_t)(b * L + tq)) * 512 + h * 64 + tid];
  __syncthreads();
  const float* ktbase = KT + ((size_t)(b * H + h) * 64) * L;
  for (int t = tid; t < L; t += 256) {
    float s = 0.f;
    #pragma unroll 8
    for (int d = 0; d < 64; d++) s += qs[d] * ktbase[(size_t)d * L + t];
    sc[t] = s * 0.125f;  // 1/sqrt(64)
  }
  __syncthreads();
  float mx = -INFINITY;
  for (int t = tid; t < L; t += 256) mx = fmaxf(mx, sc[t]);
  red[tid] = mx;
  __syncthreads();
  for (int s = 128; s > 0; s >>= 1) {
    if (tid < s) red[tid] = fmaxf(red[tid], red[tid + s]);
    __syncthreads();
  }
  mx = red[0];
  __syncthreads();
  float sm = 0.f;
  for (int t = tid; t < L; t += 256) {
    float e = expf(sc[t] - mx);
    sc[t] = e;
    sm += e;
  }
  red[tid] = sm;
  __syncthreads();
  for (int s = 128; s > 0; s >>= 1) {
    if (tid < s) red[tid] += red[tid + s];
    __syncthreads();
  }
  float inv = 1.f / red[0];
  __syncthreads();
  int d = tid & 63, g = tid >> 6;
  float acc = 0.f;
  const float* vbase = V + (size_t)b * L * 512 + h * 64 + d;
  for (int t = g; t < L; t += 4) acc += sc[t] * vbase[(size_t)t * 512];
  red[tid] = acc;
  __syncthreads();
  if (tid < 64) {
    float r = red[tid] + red[tid + 64] + red[tid + 128] + red[tid + 192];
    ATT[((size_t)(b * L + tq)) * 512 + h * 64 + tid] = r * inv;
  }
}

// ---------------- row LayerNorm --------------------------------------------
__global__ __launch_bounds__(256) void ln_kernel(
    const float* __restrict__ Xin, const float* __restrict__ g,
    const float* __restrict__ bta, float* __restrict__ Xout, int rows) {
  __shared__ float red[256];
  int r = blockIdx.x, tid = threadIdx.x;
  const float* xr = Xin + (size_t)r * 512;
  float v0 = xr[tid], v1 = xr[tid + 256];
  red[tid] = v0 + v1;
  __syncthreads();
  for (int s = 128; s > 0; s >>= 1) {
    if (tid < s) red[tid] += red[tid + s];
    __syncthreads();
  }
  float mean = red[0] / 512.f;
  __syncthreads();
  float d0 = v0 - mean, d1 = v1 - mean;
  red[tid] = d0 * d0 + d1 * d1;
  __syncthreads();
  for (int s = 128; s > 0; s >>= 1) {
    if (tid < s) red[tid] += red[tid + s];
    __syncthreads();
  }
  float rs = rsqrtf(red[0] / 512.f + 1e-5f);
  float* out = Xout + (size_t)r * 512;
  out[tid] = d0 * rs * g[tid] + bta[tid];
  out[tid + 256] = d1 * rs * g[tid + 256] + bta[tid + 256];
}

// ---------------- im2col for k=3 circular conv ------------------------------
__global__ void im2col_kernel(const float* __restrict__ X, float* __restrict__ XCOL,
                              int B, int L) {
  size_t i = (size_t)blockIdx.x * 256 + threadIdx.x;
  size_t total = (size_t)B * L * 1536;
  if (i >= total) return;
  int c = (int)(i % 512);
  int k = (int)((i / 512) % 3);
  size_t row = i / 1536;
  int t = (int)(row % L), b = (int)(row / L);
  int ts = (t - 1 + k + L) % L;
  XCOL[i] = X[((size_t)(b * L + ts)) * 512 + c];
}

// ---------------- conv weight permute: w[o][c][k] -> wcol[o][k*512+c] -------
__global__ void wperm_kernel(const float* __restrict__ w, float* __restrict__ wcol) {
  int i = blockIdx.x * 256 + threadIdx.x;
  if (i >= 512 * 512 * 3) return;
  int k = i % 3, c = (i / 3) % 512, o = i / 1536;
  wcol[(size_t)o * 1536 + k * 512 + c] = w[i];
}

// ---------------- BatchNorm stats (sum, sumsq per channel) ------------------
__global__ void zero_kernel(float* p, int n) {
  int i = blockIdx.x * 256 + threadIdx.x;
  if (i < n) p[i] = 0.f;
}

__global__ __launch_bounds__(256) void bnstat_kernel(
    const float* __restrict__ Y, float* __restrict__ acc, int rows) {
  int tid = threadIdx.x;
  int c0 = tid, c1 = tid + 256;
  float s0 = 0, s1 = 0, q0 = 0, q1 = 0;
  for (int r = blockIdx.x; r < rows; r += gridDim.x) {
    float v0 = Y[(size_t)r * 512 + c0];
    float v1 = Y[(size_t)r * 512 + c1];
    s0 += v0; q0 += v0 * v0;
    s1 += v1; q1 += v1 * v1;
  }
  atomicAdd(&acc[c0], s0);
  atomicAdd(&acc[c1], s1);
  atomicAdd(&acc[512 + c0], q0);
  atomicAdd(&acc[512 + c1], q1);
}

// ---------------- fused BN + ELU + MaxPool(3,2,pad1) ------------------------
__global__ void bnpool_kernel(const float* __restrict__ Y, const float* __restrict__ acc,
                              const float* __restrict__ g, const float* __restrict__ be,
                              float* __restrict__ Xout, int B, int L, int rows) {
  int Lout = L / 2;
  size_t i = (size_t)blockIdx.x * 256 + threadIdx.x;
  if (i >= (size_t)B * Lout * 512) return;
  int c = (int)(i % 512);
  size_t orow = i / 512;
  int to = (int)(orow % Lout), b = (int)(orow / Lout);
  float mu = acc[c] / (float)rows;
  float var = acc[512 + c] / (float)rows - mu * mu;
  float rs = rsqrtf(var + 1e-5f) * g[c];
  float mx = -INFINITY;
  #pragma unroll
  for (int dj = -1; dj <= 1; dj++) {
    int j = 2 * to + dj;
    if (j < 0 || j >= L) continue;
    float v = (Y[((size_t)(b * L + j)) * 512 + c] - mu) * rs + be[c];
    v = v > 0.f ? v : expm1f(v);
    mx = fmaxf(mx, v);
  }
  Xout[i] = mx;
}

// ---------------- final mean over rows --------------------------------------
__global__ void meanrows_kernel(const float* __restrict__ Xin, float* __restrict__ out, int L) {
  int b = blockIdx.x, d = threadIdx.x;  // 512 threads
  float s = 0.f;
  for (int t = 0; t < L; t++) s += Xin[((size_t)(b * L + t)) * 512 + d];
  out[b * 512 + d] = s / (float)L;
}

// ============================================================================
extern "C" void kernel_launch(void* const* d_in, const int* in_sizes, int n_in,
                              void* d_out, int out_size, void* d_ws, size_t ws_size,
                              hipStream_t stream) {
  const float* x_enc = (const float*)d_in[0];
  const float* tok_w = (const float*)d_in[1];
  const float* Wq = (const float*)d_in[2];
  const float* bq = (const float*)d_in[3];
  const float* Wk = (const float*)d_in[4];
  const float* bk = (const float*)d_in[5];
  const float* Wv = (const float*)d_in[6];
  const float* bv = (const float*)d_in[7];
  const float* Wo = (const float*)d_in[8];
  const float* bo = (const float*)d_in[9];
  const float* c1w = (const float*)d_in[10];
  const float* c1b = (const float*)d_in[11];
  const float* c2w = (const float*)d_in[12];
  const float* c2b = (const float*)d_in[13];
  const float* n1g = (const float*)d_in[14];
  const float* n1b = (const float*)d_in[15];
  const float* n2g = (const float*)d_in[16];
  const float* n2b = (const float*)d_in[17];
  const float* dcw = (const float*)d_in[18];
  const float* dcb = (const float*)d_in[19];
  const float* bng = (const float*)d_in[20];
  const float* bnb = (const float*)d_in[21];
  const float* fng = (const float*)d_in[22];
  const float* fnb = (const float*)d_in[23];

  const int B = 8, H = 8;
  const size_t NX = 4194304;  // 8*1024*512 floats

  float* ws = (float*)d_ws;
  float* X = ws;                 // [B,L,512]
  float* XLN = ws + NX;          // LN1 output (FFN residual base)
  float* BIG = ws + 2 * NX;      // 4*NX region: Q,K,V,ATT | FFN hidden | XCOL+Y
  float* Qb = BIG;
  float* Kb = BIG + NX;
  float* Vb = BIG + 2 * NX;
  float* ATT = BIG + 3 * NX;
  float* KT = ws + 6 * NX;       // [B,H,64,L]
  float* WCOL = ws + 7 * NX;     // 512*1536
  float* MBUF = WCOL + 786432;   // [B,H,L] max 65536
  float* VMEAN = MBUF + 65536;   // [B,H,64]
  float* BNACC = VMEAN + 4096;   // 1024
  int* IDX = (int*)(BNACC + 1024);  // max 1024*35
  int* TOP = IDX + 35840;           // max 64*35

  embed_kernel<<<B * 1024, 256, 0, stream>>>(x_enc, tok_w, X, B, 1024);

  int L = 1024;
  for (int l = 0; l < 3; l++) {
    int U = (L == 256) ? 30 : 35;
    int rows = B * L;
    dim3 g512(rows / 64, 8);

    gemm_kernel<<<g512, 256, 0, stream>>>(X, Wq + (size_t)l * 262144, bq + l * 512,
                                          nullptr, Qb, rows, 512, 512, 0);
    gemm_kernel<<<g512, 256, 0, stream>>>(X, Wk + (size_t)l * 262144, bk + l * 512,
                                          nullptr, Kb, rows, 512, 512, 0);
    gemm_kernel<<<g512, 256, 0, stream>>>(X, Wv + (size_t)l * 262144, bv + l * 512,
                                          nullptr, Vb, rows, 512, 512, 0);

    int half = L * U / 2;
    idx_kernel<<<(half + 255) / 256, 256, 0, stream>>>(IDX, L, U, l);
    transposeK_kernel<<<dim3(L / 64, B * H), 256, 0, stream>>>(Kb, KT, B, H, L);
    sparsity_kernel<<<(B * H * L) / 4, 256, 0, stream>>>(Qb, Kb, IDX, MBUF, B, H, L, U);
    topk_kernel<<<B * H, 256, 0, stream>>>(MBUF, TOP, L, U);
    vmean_kernel<<<B * H, 64, 0, stream>>>(Vb, VMEAN, B, H, L);
    bcast_ctx_kernel<<<(rows * 512) / 256, 256, 0, stream>>>(VMEAN, ATT, B, L);
    attn_kernel<<<B * H * U, 256, 0, stream>>>(Qb, KT, Vb, TOP, ATT, B, H, L, U);

    // O-proj + residual (in-place X)
    gemm_kernel<<<g512, 256, 0, stream>>>(ATT, Wo + (size_t)l * 262144, bo + l * 512,
                                          X, X, rows, 512, 512, 0);
    ln_kernel<<<rows, 256, 0, stream>>>(X, n1g + l * 512, n1b + l * 512, XLN, rows);
    // FFN
    gemm_kernel<<<dim3(rows / 64, 32), 256, 0, stream>>>(
        XLN, c1w + (size_t)l * 1048576, c1b + l * 2048, nullptr, BIG, rows, 2048, 512, 1);
    gemm_kernel<<<g512, 256, 0, stream>>>(BIG, c2w + (size_t)l * 1048576, c2b + l * 512,
                                          XLN, X, rows, 512, 2048, 0);
    ln_kernel<<<rows, 256, 0, stream>>>(X, n2g + l * 512, n2b + l * 512, X, rows);

    if (l < 2) {
      im2col_kernel<<<(rows * 1536) / 256, 256, 0, stream>>>(X, BIG, B, L);
      wperm_kernel<<<786432 / 256, 256, 0, stream>>>(dcw + (size_t)l * 786432, WCOL);
      float* Y = ATT;  // BIG+3*NX, beyond XCOL (rows*1536 <= 3*NX)
      gemm_kernel<<<g512, 256, 0, stream>>>(BIG, WCOL, dcb + l * 512, nullptr, Y,
                                            rows, 512, 1536, 0);
      zero_kernel<<<4, 256, 0, stream>>>(BNACC, 1024);
      bnstat_kernel<<<128, 256, 0, stream>>>(Y, BNACC, rows);
      bnpool_kernel<<<(rows / 2 * 512) / 256, 256, 0, stream>>>(
          Y, BNACC, bng + l * 512, bnb + l * 512, X, B, L, rows);
      L >>= 1;
    }
  }

  int rowsF = B * L;  // L = 256
  ln_kernel<<<rowsF, 256, 0, stream>>>(X, fng, fnb, XLN, rowsF);
  meanrows_kernel<<<B, 512, 0, stream>>>(XLN, (float*)d_out, L);
}

// Round 2
// 2017.546 us; speedup vs baseline: 1.7186x; 1.7186x over previous
//
#include <hip/hip_runtime.h>
#include <hip/hip_bf16.h>
#include <math.h>

typedef __hip_bfloat16 bf16;
typedef short bf16x8 __attribute__((ext_vector_type(8)));
typedef float f32x4 __attribute__((ext_vector_type(4)));

// ---------------- Threefry-2x32 (JAX-exact, 20 rounds) ----------------
__device__ inline void threefry2x32(unsigned k0, unsigned k1,
                                    unsigned x0, unsigned x1,
                                    unsigned& o0, unsigned& o1) {
  unsigned ks[3] = {k0, k1, k0 ^ k1 ^ 0x1BD11BDAu};
  const int rot[2][4] = {{13, 15, 26, 6}, {17, 29, 16, 24}};
  x0 += ks[0];
  x1 += ks[1];
  #pragma unroll
  for (int i = 0; i < 5; i++) {
    const int* r = rot[i & 1];
    #pragma unroll
    for (int j = 0; j < 4; j++) {
      x0 += x1;
      x1 = (x1 << r[j]) | (x1 >> (32 - r[j]));
      x1 ^= x0;
    }
    x0 += ks[(i + 1) % 3];
    x1 += ks[(i + 2) % 3] + (unsigned)(i + 1);
  }
  o0 = x0;
  o1 = x1;
}

__global__ void idx_kernel(int* __restrict__ idx, int L, int U, int layer) {
  int total = L * U, half = total / 2;
  int i = blockIdx.x * blockDim.x + threadIdx.x;
  if (i >= half) return;
  unsigned k0, k1;
  threefry2x32(0u, 42u, 0u, (unsigned)layer, k0, k1);
  unsigned o0, o1;
  threefry2x32(k0, k1, (unsigned)i, (unsigned)(half + i), o0, o1);
  idx[i] = (int)(o0 & (unsigned)(L - 1));
  idx[half + i] = (int)(o1 & (unsigned)(L - 1));
}

// ---------------- bf16 MFMA GEMM: C = A[M,K] @ W[N,K]^T (+bias)(+R)(relu) ---
// 128x128 tile, BK=32, 4 waves, 16x16x32 MFMA, reg-staged LDS w/ prefetch.
__global__ __launch_bounds__(256) void bgemm_kernel(
    const bf16* __restrict__ A, const bf16* __restrict__ W,
    const float* __restrict__ bias, const float* __restrict__ R, int rmod,
    float* __restrict__ C, bf16* __restrict__ Cb,
    int M, int N, int K, int relu, int outmode) {
  __shared__ bf16 As[128 * 32];
  __shared__ bf16 Ws[128 * 32];
  int tid = threadIdx.x;
  int lane = tid & 63, w = tid >> 6;
  size_t row0 = (size_t)blockIdx.x * 128, col0 = (size_t)blockIdx.y * 128;
  int srow = (w << 4) + (lane >> 2);      // staging row within 64-row half
  int scol = (lane & 3) << 3;             // staging k-offset (8 elems)
  const bf16* ag0 = A + (row0 + srow) * K + scol;
  const bf16* ag1 = A + (row0 + 64 + srow) * K + scol;
  const bf16* wg0 = W + (col0 + srow) * K + scol;
  const bf16* wg1 = W + (col0 + 64 + srow) * K + scol;
  int wb0 = (w << 9) + (lane << 3);       // elem offset in LDS tile
  int wb1 = wb0 + 2048;
  int wr = (w >> 1) << 6, wc = (w & 1) << 6;
  int fr = lane & 15, fk = (lane >> 4) << 3;
  f32x4 acc[4][4] = {};
  bf16x8 ra0 = *(const bf16x8*)ag0;
  bf16x8 ra1 = *(const bf16x8*)ag1;
  bf16x8 rw0 = *(const bf16x8*)wg0;
  bf16x8 rw1 = *(const bf16x8*)wg1;
  for (int k0 = 0; k0 < K; k0 += 32) {
    __syncthreads();
    *(bf16x8*)(As + wb0) = ra0;
    *(bf16x8*)(As + wb1) = ra1;
    *(bf16x8*)(Ws + wb0) = rw0;
    *(bf16x8*)(Ws + wb1) = rw1;
    if (k0 + 32 < K) {
      ag0 += 32; ag1 += 32; wg0 += 32; wg1 += 32;
      ra0 = *(const bf16x8*)ag0;
      ra1 = *(const bf16x8*)ag1;
      rw0 = *(const bf16x8*)wg0;
      rw1 = *(const bf16x8*)wg1;
    }
    __syncthreads();
    bf16x8 af[4], bfv[4];
    #pragma unroll
    for (int m = 0; m < 4; m++)
      af[m] = *(const bf16x8*)(As + (wr + m * 16 + fr) * 32 + fk);
    #pragma unroll
    for (int n = 0; n < 4; n++)
      bfv[n] = *(const bf16x8*)(Ws + (wc + n * 16 + fr) * 32 + fk);
    #pragma unroll
    for (int m = 0; m < 4; m++)
      #pragma unroll
      for (int n = 0; n < 4; n++)
        acc[m][n] = __builtin_amdgcn_mfma_f32_16x16x32_bf16(af[m], bfv[n], acc[m][n], 0, 0, 0);
  }
  int cr = (lane >> 4) << 2;
  int cc0 = lane & 15;
  #pragma unroll
  for (int m = 0; m < 4; m++) {
    #pragma unroll
    for (int n = 0; n < 4; n++) {
      #pragma unroll
      for (int r = 0; r < 4; r++) {
        size_t rr = row0 + wr + m * 16 + cr + r;
        size_t cc = col0 + wc + n * 16 + cc0;
        float v = acc[m][n][r];
        if (bias) v += bias[cc];
        if (R) v += rmod ? R[(rr % rmod) * N + cc] : R[rr * N + cc];
        if (relu) v = fmaxf(v, 0.f);
        if (outmode != 2) C[rr * N + cc] = v;
        if (outmode) Cb[rr * N + cc] = __float2bfloat16(v);
      }
    }
  }
}

// ---------------- weight/activation casts -----------------------------------
__global__ void cast4_kernel(const float* __restrict__ s, bf16* __restrict__ d, int n4) {
  int i = blockIdx.x * 256 + threadIdx.x;
  if (i >= n4) return;
  float4 v = ((const float4*)s)[i];
  d[i * 4 + 0] = __float2bfloat16(v.x);
  d[i * 4 + 1] = __float2bfloat16(v.y);
  d[i * 4 + 2] = __float2bfloat16(v.z);
  d[i * 4 + 3] = __float2bfloat16(v.w);
}

// dcw [o][c][k] -> wcol[o][k*512+c] bf16
__global__ void wperm_kernel(const float* __restrict__ w, bf16* __restrict__ wcol) {
  int i = blockIdx.x * 256 + threadIdx.x;
  if (i >= 512 * 1536) return;
  int o = i / 1536, r = i % 1536, k = r / 512, c = r % 512;
  wcol[i] = __float2bfloat16(w[o * 1536 + c * 3 + k]);
}

// tok_w [o][c][k] (c<64,k<3) -> [o][k*64+c] bf16
__global__ void tokperm_kernel(const float* __restrict__ w, bf16* __restrict__ d) {
  int i = blockIdx.x * 256 + threadIdx.x;
  if (i >= 512 * 192) return;
  int o = i / 192, r = i % 192, k = r / 64, c = r % 64;
  d[i] = __float2bfloat16(w[o * 192 + c * 3 + k]);
}

// PE table [1024][512] fp32
__global__ void pe_kernel(float* __restrict__ PE) {
  int t = blockIdx.x, o = threadIdx.x;
  int i2 = o >> 1;
  float div = expf((float)(2 * i2) * (-9.210340371976184f / 512.f));
  float ang = (float)t * div;
  PE[t * 512 + o] = (o & 1) ? cosf(ang) : sinf(ang);
}

// embedding im2col: x_enc -> [B*L, 192] bf16 (j = k*64+c), +1e-10
__global__ void im2col_e_kernel(const float* __restrict__ x, bf16* __restrict__ d,
                                int B, int L) {
  size_t i = (size_t)blockIdx.x * 256 + threadIdx.x;
  if (i >= (size_t)B * L * 192) return;
  int j = (int)(i % 192);
  size_t row = i / 192;
  int k = j >> 6, c = j & 63;
  int t = (int)(row % L), b = (int)(row / L);
  int ts = (t - 1 + k) & (L - 1);
  d[i] = __float2bfloat16(x[((size_t)(b * L + ts)) * 64 + c] + 1e-10f);
}

// ---------------- K transpose per head: KT[b,h,d,t] --------------------------
__global__ __launch_bounds__(256) void transposeK_kernel(
    const float* __restrict__ Kf, float* __restrict__ KT, int B, int H, int L) {
  __shared__ float tile[64][65];
  int bh = blockIdx.y;
  int h = bh % H, b = bh / H;
  int t0 = blockIdx.x * 64;
  int tid = threadIdx.x;
  for (int it = 0; it < 16; it++) {
    int r = it * 4 + (tid >> 6), c = tid & 63;
    tile[r][c] = Kf[((size_t)(b * L + t0 + r)) * 512 + h * 64 + c];
  }
  __syncthreads();
  for (int it = 0; it < 16; it++) {
    int d = it * 4 + (tid >> 6), t = tid & 63;
    KT[((size_t)bh * 64 + d) * L + t0 + t] = tile[t][d];
  }
}

// ---------------- sparsity measure M ----------------------------------------
__global__ __launch_bounds__(256) void sparsity_kernel(
    const float* __restrict__ Q, const float* __restrict__ Kf,
    const int* __restrict__ idx, float* __restrict__ M,
    int B, int H, int L, int U) {
  int gid = blockIdx.x * blockDim.x + threadIdx.x;
  int wid = gid >> 6;
  int lane = threadIdx.x & 63;
  if (wid >= B * H * L) return;
  int t = wid % L, h = (wid / L) % H, b = wid / (L * H);
  float dot = 0.f;
  if (lane < U) {
    int kt = idx[t * U + lane];
    const float* qrow = Q + ((size_t)(b * L + t)) * 512 + h * 64;
    const float* krow = Kf + ((size_t)(b * L + kt)) * 512 + h * 64;
    #pragma unroll 8
    for (int d = 0; d < 64; d++) dot += qrow[d] * krow[d];
  }
  float mx = (lane < U) ? dot : -INFINITY;
  float sm = (lane < U) ? dot : 0.f;
  #pragma unroll
  for (int off = 32; off; off >>= 1) {
    mx = fmaxf(mx, __shfl_xor(mx, off));
    sm += __shfl_xor(sm, off);
  }
  if (lane == 0) M[wid] = mx - sm / (float)L;
}

// ---------------- top-k (iterative argmax) ----------------------------------
__global__ __launch_bounds__(256) void topk_kernel(
    const float* __restrict__ M, int* __restrict__ top, int L, int U) {
  __shared__ float mv[1024];
  __shared__ float rv[256];
  __shared__ int ri[256];
  int bh = blockIdx.x, tid = threadIdx.x;
  for (int t = tid; t < L; t += 256) mv[t] = M[(size_t)bh * L + t];
  __syncthreads();
  for (int it = 0; it < U; it++) {
    float bestv = -INFINITY;
    int besti = L;
    for (int t = tid; t < L; t += 256) {
      float v = mv[t];
      if (v > bestv || (v == bestv && t < besti)) { bestv = v; besti = t; }
    }
    rv[tid] = bestv; ri[tid] = besti;
    __syncthreads();
    for (int s = 128; s > 0; s >>= 1) {
      if (tid < s) {
        if (rv[tid + s] > rv[tid] || (rv[tid + s] == rv[tid] && ri[tid + s] < ri[tid])) {
          rv[tid] = rv[tid + s]; ri[tid] = ri[tid + s];
        }
      }
      __syncthreads();
    }
    if (tid == 0) { top[bh * U + it] = ri[0]; mv[ri[0]] = -INFINITY; }
    __syncthreads();
  }
}

// ---------------- V mean over t ---------------------------------------------
__global__ void vmean_kernel(const float* __restrict__ V, float* __restrict__ Vmean,
                             int B, int H, int L) {
  int bh = blockIdx.x;
  int h = bh % H, b = bh / H;
  int d = threadIdx.x;
  float s = 0.f;
  const float* vb = V + (size_t)b * L * 512 + h * 64 + d;
  for (int t = 0; t < L; t++) s += vb[(size_t)t * 512];
  Vmean[bh * 64 + d] = s / (float)L;
}

// ---------------- broadcast ctx = Vmean (bf16 out) ---------------------------
__global__ void bcast_ctx_kernel(const float* __restrict__ Vmean, bf16* __restrict__ ATTb,
                                 int B, int L) {
  size_t i = (size_t)blockIdx.x * 256 + threadIdx.x;
  if (i >= (size_t)B * L * 512) return;
  int c = (int)(i % 512);
  int b = (int)(i / ((size_t)512 * L));
  ATTb[i] = __float2bfloat16(Vmean[b * 512 + c]);
}

// ---------------- full attention for top-u queries (bf16 out) ---------------
__global__ __launch_bounds__(256) void attn_kernel(
    const float* __restrict__ Q, const float* __restrict__ KT,
    const float* __restrict__ V, const int* __restrict__ top,
    bf16* __restrict__ ATTb, int B, int H, int L, int U) {
  __shared__ float qs[64];
  __shared__ float sc[1024];
  __shared__ float red[256];
  int u = blockIdx.x % U, h = (blockIdx.x / U) % H, b = blockIdx.x / (U * H);
  int tid = threadIdx.x;
  int tq = top[(b * H + h) * U + u];
  if (tid < 64) qs[tid] = Q[((size_t)(b * L + tq)) * 512 + h * 64 + tid];
  __syncthreads();
  const float* ktbase = KT + ((size_t)(b * H + h) * 64) * L;
  for (int t = tid; t < L; t += 256) {
    float s = 0.f;
    #pragma unroll 8
    for (int d = 0; d < 64; d++) s += qs[d] * ktbase[(size_t)d * L + t];
    sc[t] = s * 0.125f;
  }
  __syncthreads();
  float mx = -INFINITY;
  for (int t = tid; t < L; t += 256) mx = fmaxf(mx, sc[t]);
  red[tid] = mx;
  __syncthreads();
  for (int s = 128; s > 0; s >>= 1) {
    if (tid < s) red[tid] = fmaxf(red[tid], red[tid + s]);
    __syncthreads();
  }
  mx = red[0];
  __syncthreads();
  float sm = 0.f;
  for (int t = tid; t < L; t += 256) {
    float e = expf(sc[t] - mx);
    sc[t] = e;
    sm += e;
  }
  red[tid] = sm;
  __syncthreads();
  for (int s = 128; s > 0; s >>= 1) {
    if (tid < s) red[tid] += red[tid + s];
    __syncthreads();
  }
  float inv = 1.f / red[0];
  __syncthreads();
  int d = tid & 63, g = tid >> 6;
  float acc = 0.f;
  const float* vbase = V + (size_t)b * L * 512 + h * 64 + d;
  for (int t = g; t < L; t += 4) acc += sc[t] * vbase[(size_t)t * 512];
  red[tid] = acc;
  __syncthreads();
  if (tid < 64) {
    float r = red[tid] + red[tid + 64] + red[tid + 128] + red[tid + 192];
    ATTb[((size_t)(b * L + tq)) * 512 + h * 64 + tid] = __float2bfloat16(r * inv);
  }
}

// ---------------- row LayerNorm (+ optional bf16 out) ------------------------
__global__ __launch_bounds__(256) void ln_kernel(
    const float* __restrict__ Xin, const float* __restrict__ g,
    const float* __restrict__ bta, float* __restrict__ Xout,
    bf16* __restrict__ Xoutb, int rows) {
  __shared__ float red[256];
  int r = blockIdx.x, tid = threadIdx.x;
  const float* xr = Xin + (size_t)r * 512;
  float v0 = xr[tid], v1 = xr[tid + 256];
  red[tid] = v0 + v1;
  __syncthreads();
  for (int s = 128; s > 0; s >>= 1) {
    if (tid < s) red[tid] += red[tid + s];
    __syncthreads();
  }
  float mean = red[0] / 512.f;
  __syncthreads();
  float d0 = v0 - mean, d1 = v1 - mean;
  red[tid] = d0 * d0 + d1 * d1;
  __syncthreads();
  for (int s = 128; s > 0; s >>= 1) {
    if (tid < s) red[tid] += red[tid + s];
    __syncthreads();
  }
  float rs = rsqrtf(red[0] / 512.f + 1e-5f);
  float o0 = d0 * rs * g[tid] + bta[tid];
  float o1 = d1 * rs * g[tid + 256] + bta[tid + 256];
  float* out = Xout + (size_t)r * 512;
  out[tid] = o0;
  out[tid + 256] = o1;
  if (Xoutb) {
    Xoutb[(size_t)r * 512 + tid] = __float2bfloat16(o0);
    Xoutb[(size_t)r * 512 + tid + 256] = __float2bfloat16(o1);
  }
}

// ---------------- im2col for k=3 circular conv (bf16 out) -------------------
__global__ void im2col_kernel(const float* __restrict__ X, bf16* __restrict__ XCOL,
                              int B, int L) {
  size_t i = (size_t)blockIdx.x * 256 + threadIdx.x;
  size_t total = (size_t)B * L * 1536;
  if (i >= total) return;
  int c = (int)(i % 512);
  int k = (int)((i / 512) % 3);
  size_t row = i / 1536;
  int t = (int)(row % L), b = (int)(row / L);
  int ts = (t - 1 + k + L) % L;
  XCOL[i] = __float2bfloat16(X[((size_t)(b * L + ts)) * 512 + c]);
}

// ---------------- BatchNorm stats -------------------------------------------
__global__ void zero_kernel(float* p, int n) {
  int i = blockIdx.x * 256 + threadIdx.x;
  if (i < n) p[i] = 0.f;
}

__global__ __launch_bounds__(256) void bnstat_kernel(
    const float* __restrict__ Y, float* __restrict__ acc, int rows) {
  int tid = threadIdx.x;
  int c0 = tid, c1 = tid + 256;
  float s0 = 0, s1 = 0, q0 = 0, q1 = 0;
  for (int r = blockIdx.x; r < rows; r += gridDim.x) {
    float v0 = Y[(size_t)r * 512 + c0];
    float v1 = Y[(size_t)r * 512 + c1];
    s0 += v0; q0 += v0 * v0;
    s1 += v1; q1 += v1 * v1;
  }
  atomicAdd(&acc[c0], s0);
  atomicAdd(&acc[c1], s1);
  atomicAdd(&acc[512 + c0], q0);
  atomicAdd(&acc[512 + c1], q1);
}

// ---------------- fused BN + ELU + MaxPool(3,2,1) (+bf16 out) ---------------
__global__ void bnpool_kernel(const float* __restrict__ Y, const float* __restrict__ acc,
                              const float* __restrict__ g, const float* __restrict__ be,
                              float* __restrict__ Xout, bf16* __restrict__ Xoutb,
                              int B, int L, int rows) {
  int Lout = L / 2;
  size_t i = (size_t)blockIdx.x * 256 + threadIdx.x;
  if (i >= (size_t)B * Lout * 512) return;
  int c = (int)(i % 512);
  size_t orow = i / 512;
  int to = (int)(orow % Lout), b = (int)(orow / Lout);
  float mu = acc[c] / (float)rows;
  float var = acc[512 + c] / (float)rows - mu * mu;
  float rs = rsqrtf(var + 1e-5f) * g[c];
  float mx = -INFINITY;
  #pragma unroll
  for (int dj = -1; dj <= 1; dj++) {
    int j = 2 * to + dj;
    if (j < 0 || j >= L) continue;
    float v = (Y[((size_t)(b * L + j)) * 512 + c] - mu) * rs + be[c];
    v = v > 0.f ? v : expm1f(v);
    mx = fmaxf(mx, v);
  }
  Xout[i] = mx;
  Xoutb[i] = __float2bfloat16(mx);
}

// ---------------- final mean over rows --------------------------------------
__global__ void meanrows_kernel(const float* __restrict__ Xin, float* __restrict__ out, int L) {
  int b = blockIdx.x, d = threadIdx.x;
  float s = 0.f;
  for (int t = 0; t < L; t++) s += Xin[((size_t)(b * L + t)) * 512 + d];
  out[b * 512 + d] = s / (float)L;
}

// ============================================================================
extern "C" void kernel_launch(void* const* d_in, const int* in_sizes, int n_in,
                              void* d_out, int out_size, void* d_ws, size_t ws_size,
                              hipStream_t stream) {
  const float* x_enc = (const float*)d_in[0];
  const float* tok_w = (const float*)d_in[1];
  const float* Wq = (const float*)d_in[2];
  const float* bq = (const float*)d_in[3];
  const float* Wk = (const float*)d_in[4];
  const float* bk = (const float*)d_in[5];
  const float* Wv = (const float*)d_in[6];
  const float* bv = (const float*)d_in[7];
  const float* Wo = (const float*)d_in[8];
  const float* bo = (const float*)d_in[9];
  const float* c1w = (const float*)d_in[10];
  const float* c1b = (const float*)d_in[11];
  const float* c2w = (const float*)d_in[12];
  const float* c2b = (const float*)d_in[13];
  const float* n1g = (const float*)d_in[14];
  const float* n1b = (const float*)d_in[15];
  const float* n2g = (const float*)d_in[16];
  const float* n2b = (const float*)d_in[17];
  const float* dcw = (const float*)d_in[18];
  const float* dcb = (const float*)d_in[19];
  const float* bng = (const float*)d_in[20];
  const float* bnb = (const float*)d_in[21];
  const float* fng = (const float*)d_in[22];
  const float* fnb = (const float*)d_in[23];

  const int B = 8, H = 8;
  const size_t NX = 4194304;  // 8*1024*512

  float* ws = (float*)d_ws;
  float* X    = ws;                  // fp32 [B,L,512]
  float* XLN  = ws + NX;             // fp32; also aliased as KT
  float* KT   = XLN;
  float* Qf   = ws + 2 * NX;
  float* Kf   = ws + 3 * NX;
  float* Vf   = ws + 4 * NX;
  bf16* INb   = (bf16*)(ws + 5 * NX);          // bf16 [rows,512] (Xb/XLNb)
  bf16* ATTb  = (bf16*)(ws + 5 * NX + NX / 2); // bf16 [rows,512]
  bf16* H2b   = (bf16*)Qf;                     // bf16 [8192,2048] aliases Q..K
  bf16* XCOLb = (bf16*)Vf;                     // bf16 [rows,1536] aliases V..INb
  float* Yc   = Qf;                            // conv out fp32 aliases Q
  float* WB   = ws + 6 * NX;
  bf16* Wqb  = (bf16*)(WB);
  bf16* Wkb  = (bf16*)(WB + 131072);
  bf16* Wvb  = (bf16*)(WB + 262144);
  bf16* Wob  = (bf16*)(WB + 393216);
  bf16* c1wb = (bf16*)(WB + 524288);
  bf16* c2wb = (bf16*)(WB + 1048576);
  bf16* wcvb = (bf16*)(WB + 1572864);
  bf16* tokwb = (bf16*)(WB + 1966080);
  float* PE   = WB + 2015232;
  float* MBUF = PE + 524288;
  float* VMEAN = MBUF + 65536;
  float* BNACC = VMEAN + 4096;
  int* IDX = (int*)(BNACC + 1024);
  int* TOP = IDX + 35840;

  // ---- embedding as GEMM ----
  pe_kernel<<<1024, 512, 0, stream>>>(PE);
  tokperm_kernel<<<(512 * 192 + 255) / 256, 256, 0, stream>>>(tok_w, tokwb);
  im2col_e_kernel<<<(int)(((size_t)B * 1024 * 192 + 255) / 256), 256, 0, stream>>>(
      x_enc, INb, B, 1024);
  bgemm_kernel<<<dim3(64, 4), 256, 0, stream>>>(INb, tokwb, nullptr, PE, 1024,
                                                X, nullptr, 8192, 512, 192, 0, 0);
  cast4_kernel<<<4096, 256, 0, stream>>>(X, INb, 1048576);  // Xb

  int L = 1024;
  for (int l = 0; l < 3; l++) {
    int U = (L == 256) ? 30 : 35;
    int rows = B * L;
    dim3 g512(rows / 128, 4);

    // per-layer weight conversion
    cast4_kernel<<<256, 256, 0, stream>>>(Wq + (size_t)l * 262144, Wqb, 65536);
    cast4_kernel<<<256, 256, 0, stream>>>(Wk + (size_t)l * 262144, Wkb, 65536);
    cast4_kernel<<<256, 256, 0, stream>>>(Wv + (size_t)l * 262144, Wvb, 65536);
    cast4_kernel<<<256, 256, 0, stream>>>(Wo + (size_t)l * 262144, Wob, 65536);
    cast4_kernel<<<1024, 256, 0, stream>>>(c1w + (size_t)l * 1048576, c1wb, 262144);
    cast4_kernel<<<1024, 256, 0, stream>>>(c2w + (size_t)l * 1048576, c2wb, 262144);
    if (l < 2)
      wperm_kernel<<<3072, 256, 0, stream>>>(dcw + (size_t)l * 786432, wcvb);

    // QKV projections (fp32 out for attention math)
    bgemm_kernel<<<g512, 256, 0, stream>>>(INb, Wqb, bq + l * 512, nullptr, 0,
                                           Qf, nullptr, rows, 512, 512, 0, 0);
    bgemm_kernel<<<g512, 256, 0, stream>>>(INb, Wkb, bk + l * 512, nullptr, 0,
                                           Kf, nullptr, rows, 512, 512, 0, 0);
    bgemm_kernel<<<g512, 256, 0, stream>>>(INb, Wvb, bv + l * 512, nullptr, 0,
                                           Vf, nullptr, rows, 512, 512, 0, 0);

    int half = L * U / 2;
    idx_kernel<<<(half + 255) / 256, 256, 0, stream>>>(IDX, L, U, l);
    transposeK_kernel<<<dim3(L / 64, B * H), 256, 0, stream>>>(Kf, KT, B, H, L);
    sparsity_kernel<<<(B * H * L) / 4, 256, 0, stream>>>(Qf, Kf, IDX, MBUF, B, H, L, U);
    topk_kernel<<<B * H, 256, 0, stream>>>(MBUF, TOP, L, U);
    vmean_kernel<<<B * H, 64, 0, stream>>>(Vf, VMEAN, B, H, L);
    bcast_ctx_kernel<<<(rows * 512) / 256, 256, 0, stream>>>(VMEAN, ATTb, B, L);
    attn_kernel<<<B * H * U, 256, 0, stream>>>(Qf, KT, Vf, TOP, ATTb, B, H, L, U);

    // O-proj + residual
    bgemm_kernel<<<g512, 256, 0, stream>>>(ATTb, Wob, bo + l * 512, X, 0,
                                           X, nullptr, rows, 512, 512, 0, 0);
    ln_kernel<<<rows, 256, 0, stream>>>(X, n1g + l * 512, n1b + l * 512, XLN, INb, rows);
    // FFN
    bgemm_kernel<<<dim3(rows / 128, 16), 256, 0, stream>>>(
        INb, c1wb, c1b + l * 2048, nullptr, 0, nullptr, H2b, rows, 2048, 512, 1, 2);
    bgemm_kernel<<<g512, 256, 0, stream>>>(H2b, c2wb, c2b + l * 512, XLN, 0,
                                           X, nullptr, rows, 512, 2048, 0, 0);
    ln_kernel<<<rows, 256, 0, stream>>>(X, n2g + l * 512, n2b + l * 512, X, nullptr, rows);

    if (l < 2) {
      im2col_kernel<<<(int)(((size_t)rows * 1536) / 256), 256, 0, stream>>>(X, XCOLb, B, L);
      bgemm_kernel<<<g512, 256, 0, stream>>>(XCOLb, wcvb, dcb + l * 512, nullptr, 0,
                                             Yc, nullptr, rows, 512, 1536, 0, 0);
      zero_kernel<<<4, 256, 0, stream>>>(BNACC, 1024);
      bnstat_kernel<<<128, 256, 0, stream>>>(Yc, BNACC, rows);
      bnpool_kernel<<<(rows / 2 * 512) / 256, 256, 0, stream>>>(
          Yc, BNACC, bng + l * 512, bnb + l * 512, X, INb, B, L, rows);
      L >>= 1;
    }
  }

  int rowsF = B * L;  // L = 256
  ln_kernel<<<rowsF, 256, 0, stream>>>(X, fng, fnb, XLN, nullptr, rowsF);
  meanrows_kernel<<<B, 512, 0, stream>>>(XLN, (float*)d_out, L);
}

// Round 3
// 1639.874 us; speedup vs baseline: 2.1144x; 1.2303x over previous
//
#include <hip/hip_runtime.h>
#include <hip/hip_bf16.h>
#include <math.h>

typedef __hip_bfloat16 bf16;
typedef short bf16x8 __attribute__((ext_vector_type(8)));
typedef float f32x4 __attribute__((ext_vector_type(4)));

// ---------------- Threefry-2x32 (JAX-exact, 20 rounds) ----------------
__device__ inline void threefry2x32(unsigned k0, unsigned k1,
                                    unsigned x0, unsigned x1,
                                    unsigned& o0, unsigned& o1) {
  unsigned ks[3] = {k0, k1, k0 ^ k1 ^ 0x1BD11BDAu};
  const int rot[2][4] = {{13, 15, 26, 6}, {17, 29, 16, 24}};
  x0 += ks[0];
  x1 += ks[1];
  #pragma unroll
  for (int i = 0; i < 5; i++) {
    const int* r = rot[i & 1];
    #pragma unroll
    for (int j = 0; j < 4; j++) {
      x0 += x1;
      x1 = (x1 << r[j]) | (x1 >> (32 - r[j]));
      x1 ^= x0;
    }
    x0 += ks[(i + 1) % 3];
    x1 += ks[(i + 2) % 3] + (unsigned)(i + 1);
  }
  o0 = x0;
  o1 = x1;
}

__global__ void idx_kernel(int* __restrict__ idx, int L, int U, int layer) {
  int total = L * U, half = total / 2;
  int i = blockIdx.x * blockDim.x + threadIdx.x;
  if (i >= half) return;
  unsigned k0, k1;
  threefry2x32(0u, 42u, 0u, (unsigned)layer, k0, k1);
  unsigned o0, o1;
  threefry2x32(k0, k1, (unsigned)i, (unsigned)(half + i), o0, o1);
  idx[i] = (int)(o0 & (unsigned)(L - 1));
  idx[half + i] = (int)(o1 & (unsigned)(L - 1));
}

// ---------------- bf16 MFMA GEMM: C = A[M,K] @ W[N,K]^T (+bias)(+R)(relu) ---
__global__ __launch_bounds__(256) void bgemm_kernel(
    const bf16* __restrict__ A, const bf16* __restrict__ W,
    const float* __restrict__ bias, const float* __restrict__ R, int rmod,
    float* __restrict__ C, bf16* __restrict__ Cb,
    int M, int N, int K, int relu, int outmode) {
  __shared__ bf16 As[128 * 32];
  __shared__ bf16 Ws[128 * 32];
  int tid = threadIdx.x;
  int lane = tid & 63, w = tid >> 6;
  size_t row0 = (size_t)blockIdx.x * 128, col0 = (size_t)blockIdx.y * 128;
  int srow = (w << 4) + (lane >> 2);
  int scol = (lane & 3) << 3;
  const bf16* ag0 = A + (row0 + srow) * K + scol;
  const bf16* ag1 = A + (row0 + 64 + srow) * K + scol;
  const bf16* wg0 = W + (col0 + srow) * K + scol;
  const bf16* wg1 = W + (col0 + 64 + srow) * K + scol;
  int wb0 = (w << 9) + (lane << 3);
  int wb1 = wb0 + 2048;
  int wr = (w >> 1) << 6, wc = (w & 1) << 6;
  int fr = lane & 15, fk = (lane >> 4) << 3;
  f32x4 acc[4][4] = {};
  bf16x8 ra0 = *(const bf16x8*)ag0;
  bf16x8 ra1 = *(const bf16x8*)ag1;
  bf16x8 rw0 = *(const bf16x8*)wg0;
  bf16x8 rw1 = *(const bf16x8*)wg1;
  for (int k0 = 0; k0 < K; k0 += 32) {
    __syncthreads();
    *(bf16x8*)(As + wb0) = ra0;
    *(bf16x8*)(As + wb1) = ra1;
    *(bf16x8*)(Ws + wb0) = rw0;
    *(bf16x8*)(Ws + wb1) = rw1;
    if (k0 + 32 < K) {
      ag0 += 32; ag1 += 32; wg0 += 32; wg1 += 32;
      ra0 = *(const bf16x8*)ag0;
      ra1 = *(const bf16x8*)ag1;
      rw0 = *(const bf16x8*)wg0;
      rw1 = *(const bf16x8*)wg1;
    }
    __syncthreads();
    bf16x8 af[4], bfv[4];
    #pragma unroll
    for (int m = 0; m < 4; m++)
      af[m] = *(const bf16x8*)(As + (wr + m * 16 + fr) * 32 + fk);
    #pragma unroll
    for (int n = 0; n < 4; n++)
      bfv[n] = *(const bf16x8*)(Ws + (wc + n * 16 + fr) * 32 + fk);
    #pragma unroll
    for (int m = 0; m < 4; m++)
      #pragma unroll
      for (int n = 0; n < 4; n++)
        acc[m][n] = __builtin_amdgcn_mfma_f32_16x16x32_bf16(af[m], bfv[n], acc[m][n], 0, 0, 0);
  }
  int cr = (lane >> 4) << 2;
  int cc0 = lane & 15;
  #pragma unroll
  for (int m = 0; m < 4; m++) {
    #pragma unroll
    for (int n = 0; n < 4; n++) {
      #pragma unroll
      for (int r = 0; r < 4; r++) {
        size_t rr = row0 + wr + m * 16 + cr + r;
        size_t cc = col0 + wc + n * 16 + cc0;
        float v = acc[m][n][r];
        if (bias) v += bias[cc];
        if (R) v += rmod ? R[(rr % rmod) * N + cc] : R[rr * N + cc];
        if (relu) v = fmaxf(v, 0.f);
        if (outmode != 2) C[rr * N + cc] = v;
        if (outmode) Cb[rr * N + cc] = __float2bfloat16(v);
      }
    }
  }
}

// ---------------- weight/activation casts -----------------------------------
__global__ void cast4_kernel(const float* __restrict__ s, bf16* __restrict__ d, int n4) {
  int i = blockIdx.x * 256 + threadIdx.x;
  if (i >= n4) return;
  float4 v = ((const float4*)s)[i];
  d[i * 4 + 0] = __float2bfloat16(v.x);
  d[i * 4 + 1] = __float2bfloat16(v.y);
  d[i * 4 + 2] = __float2bfloat16(v.z);
  d[i * 4 + 3] = __float2bfloat16(v.w);
}

// dcw [o][c][k] -> wcol[o][k*512+c] bf16
__global__ void wperm_kernel(const float* __restrict__ w, bf16* __restrict__ wcol) {
  int i = blockIdx.x * 256 + threadIdx.x;
  if (i >= 512 * 1536) return;
  int o = i / 1536, r = i % 1536, k = r / 512, c = r % 512;
  wcol[i] = __float2bfloat16(w[o * 1536 + c * 3 + k]);
}

// tok_w [o][c][k] (c<64,k<3) -> [o][k*64+c] bf16
__global__ void tokperm_kernel(const float* __restrict__ w, bf16* __restrict__ d) {
  int i = blockIdx.x * 256 + threadIdx.x;
  if (i >= 512 * 192) return;
  int o = i / 192, r = i % 192, k = r / 64, c = r % 64;
  d[i] = __float2bfloat16(w[o * 192 + c * 3 + k]);
}

// PE table [1024][512] fp32
__global__ void pe_kernel(float* __restrict__ PE) {
  int t = blockIdx.x, o = threadIdx.x;
  int i2 = o >> 1;
  float div = expf((float)(2 * i2) * (-9.210340371976184f / 512.f));
  float ang = (float)t * div;
  PE[t * 512 + o] = (o & 1) ? cosf(ang) : sinf(ang);
}

// embedding im2col: x_enc -> [B*L, 192] bf16 (j = k*64+c), +1e-10
__global__ void im2col_e_kernel(const float* __restrict__ x, bf16* __restrict__ d,
                                int B, int L) {
  size_t i = (size_t)blockIdx.x * 256 + threadIdx.x;
  if (i >= (size_t)B * L * 192) return;
  int j = (int)(i % 192);
  size_t row = i / 192;
  int k = j >> 6, c = j & 63;
  int t = (int)(row % L), b = (int)(row / L);
  int ts = (t - 1 + k) & (L - 1);
  d[i] = __float2bfloat16(x[((size_t)(b * L + ts)) * 64 + c] + 1e-10f);
}

// ---------------- K transpose per head: KT[b,h,d,t] --------------------------
__global__ __launch_bounds__(256) void transposeK_kernel(
    const float* __restrict__ Kf, float* __restrict__ KT, int B, int H, int L) {
  __shared__ float tile[64][65];
  int bh = blockIdx.y;
  int h = bh % H, b = bh / H;
  int t0 = blockIdx.x * 64;
  int tid = threadIdx.x;
  for (int it = 0; it < 16; it++) {
    int r = it * 4 + (tid >> 6), c = tid & 63;
    tile[r][c] = Kf[((size_t)(b * L + t0 + r)) * 512 + h * 64 + c];
  }
  __syncthreads();
  for (int it = 0; it < 16; it++) {
    int d = it * 4 + (tid >> 6), t = tid & 63;
    KT[((size_t)bh * 64 + d) * L + t0 + t] = tile[t][d];
  }
}

// ---------------- sparsity measure M ----------------------------------------
__global__ __launch_bounds__(256) void sparsity_kernel(
    const float* __restrict__ Q, const float* __restrict__ Kf,
    const int* __restrict__ idx, float* __restrict__ M,
    int B, int H, int L, int U) {
  int gid = blockIdx.x * blockDim.x + threadIdx.x;
  int wid = gid >> 6;
  int lane = threadIdx.x & 63;
  if (wid >= B * H * L) return;
  int t = wid % L, h = (wid / L) % H, b = wid / (L * H);
  float dot = 0.f;
  if (lane < U) {
    int kt = idx[t * U + lane];
    const float* qrow = Q + ((size_t)(b * L + t)) * 512 + h * 64;
    const float* krow = Kf + ((size_t)(b * L + kt)) * 512 + h * 64;
    #pragma unroll 8
    for (int d = 0; d < 64; d++) dot += qrow[d] * krow[d];
  }
  float mx = (lane < U) ? dot : -INFINITY;
  float sm = (lane < U) ? dot : 0.f;
  #pragma unroll
  for (int off = 32; off; off >>= 1) {
    mx = fmaxf(mx, __shfl_xor(mx, off));
    sm += __shfl_xor(sm, off);
  }
  if (lane == 0) M[wid] = mx - sm / (float)L;
}

// ---------------- top-k: 1 wave per (b,h), shfl butterfly argmax -------------
__global__ __launch_bounds__(64) void topk_kernel(
    const float* __restrict__ M, int* __restrict__ top, int L, int U) {
  __shared__ float mv[1024];
  int bh = blockIdx.x, lane = threadIdx.x;
  for (int t = lane; t < L; t += 64) mv[t] = M[(size_t)bh * L + t];
  __syncthreads();
  for (int it = 0; it < U; it++) {
    float bv = -INFINITY;
    int bi = L;
    for (int t = lane; t < L; t += 64) {
      float v = mv[t];
      if (v > bv || (v == bv && t < bi)) { bv = v; bi = t; }
    }
    #pragma unroll
    for (int off = 32; off; off >>= 1) {
      float ov = __shfl_xor(bv, off);
      int oi = __shfl_xor(bi, off);
      if (ov > bv || (ov == bv && oi < bi)) { bv = ov; bi = oi; }
    }
    if (lane == 0) {
      top[bh * U + it] = bi;
      mv[bi] = -INFINITY;
    }
    __syncthreads();
  }
}

// ---------------- V mean: deterministic 2-stage -----------------------------
__global__ __launch_bounds__(512) void vmean_part_kernel(
    const float* __restrict__ V, float* __restrict__ VP, int L, int segs) {
  int b = blockIdx.x, s = blockIdx.y, c = threadIdx.x;
  int per = L / segs;
  const float* vb = V + ((size_t)(b * L + s * per)) * 512 + c;
  float acc = 0.f;
  for (int t = 0; t < per; t++) acc += vb[(size_t)t * 512];
  VP[((size_t)(b * segs + s)) * 512 + c] = acc;
}

__global__ void vmean_reduce_kernel(const float* __restrict__ VP, float* __restrict__ Vmean,
                                    int segs, int L) {
  int i = blockIdx.x * 256 + threadIdx.x;  // B*512
  if (i >= 8 * 512) return;
  int b = i >> 9, c = i & 511;
  float acc = 0.f;
  for (int s = 0; s < segs; s++) acc += VP[((size_t)(b * segs + s)) * 512 + c];
  Vmean[i] = acc / (float)L;
}

// ---------------- broadcast ctx = Vmean (bf16 out) ---------------------------
__global__ void bcast_ctx_kernel(const float* __restrict__ Vmean, bf16* __restrict__ ATTb,
                                 int B, int L) {
  size_t i = (size_t)blockIdx.x * 256 + threadIdx.x;
  if (i >= (size_t)B * L * 512) return;
  int c = (int)(i % 512);
  int b = (int)(i / ((size_t)512 * L));
  ATTb[i] = __float2bfloat16(Vmean[b * 512 + c]);
}

// ---------------- full attention for top-u queries (bf16 out) ---------------
__global__ __launch_bounds__(256) void attn_kernel(
    const float* __restrict__ Q, const float* __restrict__ KT,
    const float* __restrict__ V, const int* __restrict__ top,
    bf16* __restrict__ ATTb, int B, int H, int L, int U) {
  __shared__ float qs[64];
  __shared__ float sc[1024];
  __shared__ float red[256];
  int u = blockIdx.x % U, h = (blockIdx.x / U) % H, b = blockIdx.x / (U * H);
  int tid = threadIdx.x;
  int tq = top[(b * H + h) * U + u];
  if (tid < 64) qs[tid] = Q[((size_t)(b * L + tq)) * 512 + h * 64 + tid];
  __syncthreads();
  const float* ktbase = KT + ((size_t)(b * H + h) * 64) * L;
  for (int t = tid; t < L; t += 256) {
    float s = 0.f;
    #pragma unroll 8
    for (int d = 0; d < 64; d++) s += qs[d] * ktbase[(size_t)d * L + t];
    sc[t] = s * 0.125f;
  }
  __syncthreads();
  float mx = -INFINITY;
  for (int t = tid; t < L; t += 256) mx = fmaxf(mx, sc[t]);
  red[tid] = mx;
  __syncthreads();
  for (int s = 128; s > 0; s >>= 1) {
    if (tid < s) red[tid] = fmaxf(red[tid], red[tid + s]);
    __syncthreads();
  }
  mx = red[0];
  __syncthreads();
  float sm = 0.f;
  for (int t = tid; t < L; t += 256) {
    float e = expf(sc[t] - mx);
    sc[t] = e;
    sm += e;
  }
  red[tid] = sm;
  __syncthreads();
  for (int s = 128; s > 0; s >>= 1) {
    if (tid < s) red[tid] += red[tid + s];
    __syncthreads();
  }
  float inv = 1.f / red[0];
  __syncthreads();
  int d = tid & 63, g = tid >> 6;
  float acc = 0.f;
  const float* vbase = V + (size_t)b * L * 512 + h * 64 + d;
  for (int t = g; t < L; t += 4) acc += sc[t] * vbase[(size_t)t * 512];
  red[tid] = acc;
  __syncthreads();
  if (tid < 64) {
    float r = red[tid] + red[tid + 64] + red[tid + 128] + red[tid + 192];
    ATTb[((size_t)(b * L + tq)) * 512 + h * 64 + tid] = __float2bfloat16(r * inv);
  }
}

// ---------------- row LayerNorm (+ optional bf16 out) ------------------------
__global__ __launch_bounds__(256) void ln_kernel(
    const float* __restrict__ Xin, const float* __restrict__ g,
    const float* __restrict__ bta, float* __restrict__ Xout,
    bf16* __restrict__ Xoutb, int rows) {
  __shared__ float red[256];
  int r = blockIdx.x, tid = threadIdx.x;
  const float* xr = Xin + (size_t)r * 512;
  float v0 = xr[tid], v1 = xr[tid + 256];
  red[tid] = v0 + v1;
  __syncthreads();
  for (int s = 128; s > 0; s >>= 1) {
    if (tid < s) red[tid] += red[tid + s];
    __syncthreads();
  }
  float mean = red[0] / 512.f;
  __syncthreads();
  float d0 = v0 - mean, d1 = v1 - mean;
  red[tid] = d0 * d0 + d1 * d1;
  __syncthreads();
  for (int s = 128; s > 0; s >>= 1) {
    if (tid < s) red[tid] += red[tid + s];
    __syncthreads();
  }
  float rs = rsqrtf(red[0] / 512.f + 1e-5f);
  float o0 = d0 * rs * g[tid] + bta[tid];
  float o1 = d1 * rs * g[tid + 256] + bta[tid + 256];
  float* out = Xout + (size_t)r * 512;
  out[tid] = o0;
  out[tid + 256] = o1;
  if (Xoutb) {
    Xoutb[(size_t)r * 512 + tid] = __float2bfloat16(o0);
    Xoutb[(size_t)r * 512 + tid + 256] = __float2bfloat16(o1);
  }
}

// ---------------- im2col for k=3 circular conv (bf16 out) -------------------
__global__ void im2col_kernel(const float* __restrict__ X, bf16* __restrict__ XCOL,
                              int B, int L) {
  size_t i = (size_t)blockIdx.x * 256 + threadIdx.x;
  size_t total = (size_t)B * L * 1536;
  if (i >= total) return;
  int c = (int)(i % 512);
  int k = (int)((i / 512) % 3);
  size_t row = i / 1536;
  int t = (int)(row % L), b = (int)(row / L);
  int ts = (t - 1 + k + L) % L;
  XCOL[i] = __float2bfloat16(X[((size_t)(b * L + ts)) * 512 + c]);
}

// ---------------- BatchNorm stats -------------------------------------------
__global__ void zero_kernel(float* p, int n) {
  int i = blockIdx.x * 256 + threadIdx.x;
  if (i < n) p[i] = 0.f;
}

__global__ __launch_bounds__(256) void bnstat_kernel(
    const float* __restrict__ Y, float* __restrict__ acc, int rows) {
  int tid = threadIdx.x;
  int c0 = tid, c1 = tid + 256;
  float s0 = 0, s1 = 0, q0 = 0, q1 = 0;
  for (int r = blockIdx.x; r < rows; r += gridDim.x) {
    float v0 = Y[(size_t)r * 512 + c0];
    float v1 = Y[(size_t)r * 512 + c1];
    s0 += v0; q0 += v0 * v0;
    s1 += v1; q1 += v1 * v1;
  }
  atomicAdd(&acc[c0], s0);
  atomicAdd(&acc[c1], s1);
  atomicAdd(&acc[512 + c0], q0);
  atomicAdd(&acc[512 + c1], q1);
}

// ---------------- fused BN + ELU + MaxPool(3,2,1) (+bf16 out) ---------------
__global__ void bnpool_kernel(const float* __restrict__ Y, const float* __restrict__ acc,
                              const float* __restrict__ g, const float* __restrict__ be,
                              float* __restrict__ Xout, bf16* __restrict__ Xoutb,
                              int B, int L, int rows) {
  int Lout = L / 2;
  size_t i = (size_t)blockIdx.x * 256 + threadIdx.x;
  if (i >= (size_t)B * Lout * 512) return;
  int c = (int)(i % 512);
  size_t orow = i / 512;
  int to = (int)(orow % Lout), b = (int)(orow / Lout);
  float mu = acc[c] / (float)rows;
  float var = acc[512 + c] / (float)rows - mu * mu;
  float rs = rsqrtf(var + 1e-5f) * g[c];
  float mx = -INFINITY;
  #pragma unroll
  for (int dj = -1; dj <= 1; dj++) {
    int j = 2 * to + dj;
    if (j < 0 || j >= L) continue;
    float v = (Y[((size_t)(b * L + j)) * 512 + c] - mu) * rs + be[c];
    v = v > 0.f ? v : expm1f(v);
    mx = fmaxf(mx, v);
  }
  Xout[i] = mx;
  Xoutb[i] = __float2bfloat16(mx);
}

// ---------------- final mean over rows --------------------------------------
__global__ void meanrows_kernel(const float* __restrict__ Xin, float* __restrict__ out, int L) {
  int b = blockIdx.x, d = threadIdx.x;
  float s = 0.f;
  for (int t = 0; t < L; t++) s += Xin[((size_t)(b * L + t)) * 512 + d];
  out[b * 512 + d] = s / (float)L;
}

// ============================================================================
extern "C" void kernel_launch(void* const* d_in, const int* in_sizes, int n_in,
                              void* d_out, int out_size, void* d_ws, size_t ws_size,
                              hipStream_t stream) {
  const float* x_enc = (const float*)d_in[0];
  const float* tok_w = (const float*)d_in[1];
  const float* Wq = (const float*)d_in[2];
  const float* bq = (const float*)d_in[3];
  const float* Wk = (const float*)d_in[4];
  const float* bk = (const float*)d_in[5];
  const float* Wv = (const float*)d_in[6];
  const float* bv = (const float*)d_in[7];
  const float* Wo = (const float*)d_in[8];
  const float* bo = (const float*)d_in[9];
  const float* c1w = (const float*)d_in[10];
  const float* c1b = (const float*)d_in[11];
  const float* c2w = (const float*)d_in[12];
  const float* c2b = (const float*)d_in[13];
  const float* n1g = (const float*)d_in[14];
  const float* n1b = (const float*)d_in[15];
  const float* n2g = (const float*)d_in[16];
  const float* n2b = (const float*)d_in[17];
  const float* dcw = (const float*)d_in[18];
  const float* dcb = (const float*)d_in[19];
  const float* bng = (const float*)d_in[20];
  const float* bnb = (const float*)d_in[21];
  const float* fng = (const float*)d_in[22];
  const float* fnb = (const float*)d_in[23];

  const int B = 8, H = 8;
  const size_t NX = 4194304;  // 8*1024*512

  float* ws = (float*)d_ws;
  float* X    = ws;
  float* XLN  = ws + NX;
  float* KT   = XLN;
  float* Qf   = ws + 2 * NX;
  float* Kf   = ws + 3 * NX;
  float* Vf   = ws + 4 * NX;
  bf16* INb   = (bf16*)(ws + 5 * NX);
  bf16* ATTb  = (bf16*)(ws + 5 * NX + NX / 2);
  bf16* H2b   = (bf16*)Qf;
  bf16* XCOLb = (bf16*)Vf;
  float* Yc   = Qf;
  float* WB   = ws + 6 * NX;
  bf16* Wqb  = (bf16*)(WB);
  bf16* Wkb  = (bf16*)(WB + 131072);
  bf16* Wvb  = (bf16*)(WB + 262144);
  bf16* Wob  = (bf16*)(WB + 393216);
  bf16* c1wb = (bf16*)(WB + 524288);
  bf16* c2wb = (bf16*)(WB + 1048576);
  bf16* wcvb = (bf16*)(WB + 1572864);
  bf16* tokwb = (bf16*)(WB + 1966080);
  float* PE   = WB + 2015232;
  float* MBUF = PE + 524288;
  float* VMEAN = MBUF + 65536;
  float* BNACC = VMEAN + 4096;
  int* IDX = (int*)(BNACC + 1024);
  int* TOP = IDX + 35840;
  float* VPART = (float*)(TOP + 2240);   // [8][32][512] = 131072 floats

  // ---- embedding as GEMM ----
  pe_kernel<<<1024, 512, 0, stream>>>(PE);
  tokperm_kernel<<<(512 * 192 + 255) / 256, 256, 0, stream>>>(tok_w, tokwb);
  im2col_e_kernel<<<(int)(((size_t)B * 1024 * 192 + 255) / 256), 256, 0, stream>>>(
      x_enc, INb, B, 1024);
  bgemm_kernel<<<dim3(64, 4), 256, 0, stream>>>(INb, tokwb, nullptr, PE, 1024,
                                                X, nullptr, 8192, 512, 192, 0, 0);
  cast4_kernel<<<4096, 256, 0, stream>>>(X, INb, 1048576);

  int L = 1024;
  for (int l = 0; l < 3; l++) {
    int U = (L == 256) ? 30 : 35;
    int rows = B * L;
    dim3 g512(rows / 128, 4);

    cast4_kernel<<<256, 256, 0, stream>>>(Wq + (size_t)l * 262144, Wqb, 65536);
    cast4_kernel<<<256, 256, 0, stream>>>(Wk + (size_t)l * 262144, Wkb, 65536);
    cast4_kernel<<<256, 256, 0, stream>>>(Wv + (size_t)l * 262144, Wvb, 65536);
    cast4_kernel<<<256, 256, 0, stream>>>(Wo + (size_t)l * 262144, Wob, 65536);
    cast4_kernel<<<1024, 256, 0, stream>>>(c1w + (size_t)l * 1048576, c1wb, 262144);
    cast4_kernel<<<1024, 256, 0, stream>>>(c2w + (size_t)l * 1048576, c2wb, 262144);
    if (l < 2)
      wperm_kernel<<<3072, 256, 0, stream>>>(dcw + (size_t)l * 786432, wcvb);

    bgemm_kernel<<<g512, 256, 0, stream>>>(INb, Wqb, bq + l * 512, nullptr, 0,
                                           Qf, nullptr, rows, 512, 512, 0, 0);
    bgemm_kernel<<<g512, 256, 0, stream>>>(INb, Wkb, bk + l * 512, nullptr, 0,
                                           Kf, nullptr, rows, 512, 512, 0, 0);
    bgemm_kernel<<<g512, 256, 0, stream>>>(INb, Wvb, bv + l * 512, nullptr, 0,
                                           Vf, nullptr, rows, 512, 512, 0, 0);

    int half = L * U / 2;
    idx_kernel<<<(half + 255) / 256, 256, 0, stream>>>(IDX, L, U, l);
    transposeK_kernel<<<dim3(L / 64, B * H), 256, 0, stream>>>(Kf, KT, B, H, L);
    sparsity_kernel<<<(B * H * L) / 4, 256, 0, stream>>>(Qf, Kf, IDX, MBUF, B, H, L, U);
    topk_kernel<<<B * H, 64, 0, stream>>>(MBUF, TOP, L, U);
    vmean_part_kernel<<<dim3(B, 32), 512, 0, stream>>>(Vf, VPART, L, 32);
    vmean_reduce_kernel<<<16, 256, 0, stream>>>(VPART, VMEAN, 32, L);
    bcast_ctx_kernel<<<(rows * 512) / 256, 256, 0, stream>>>(VMEAN, ATTb, B, L);
    attn_kernel<<<B * H * U, 256, 0, stream>>>(Qf, KT, Vf, TOP, ATTb, B, H, L, U);

    bgemm_kernel<<<g512, 256, 0, stream>>>(ATTb, Wob, bo + l * 512, X, 0,
                                           X, nullptr, rows, 512, 512, 0, 0);
    ln_kernel<<<rows, 256, 0, stream>>>(X, n1g + l * 512, n1b + l * 512, XLN, INb, rows);
    bgemm_kernel<<<dim3(rows / 128, 16), 256, 0, stream>>>(
        INb, c1wb, c1b + l * 2048, nullptr, 0, nullptr, H2b, rows, 2048, 512, 1, 2);
    bgemm_kernel<<<g512, 256, 0, stream>>>(H2b, c2wb, c2b + l * 512, XLN, 0,
                                           X, nullptr, rows, 512, 2048, 0, 0);
    ln_kernel<<<rows, 256, 0, stream>>>(X, n2g + l * 512, n2b + l * 512, X, nullptr, rows);

    if (l < 2) {
      im2col_kernel<<<(int)(((size_t)rows * 1536) / 256), 256, 0, stream>>>(X, XCOLb, B, L);
      bgemm_kernel<<<g512, 256, 0, stream>>>(XCOLb, wcvb, dcb + l * 512, nullptr, 0,
                                             Yc, nullptr, rows, 512, 1536, 0, 0);
      zero_kernel<<<4, 256, 0, stream>>>(BNACC, 1024);
      bnstat_kernel<<<128, 256, 0, stream>>>(Yc, BNACC, rows);
      bnpool_kernel<<<(rows / 2 * 512) / 256, 256, 0, stream>>>(
          Yc, BNACC, bng + l * 512, bnb + l * 512, X, INb, B, L, rows);
      L >>= 1;
    }
  }

  int rowsF = B * L;  // L = 256
  ln_kernel<<<rowsF, 256, 0, stream>>>(X, fng, fnb, XLN, nullptr, rowsF);
  meanrows_kernel<<<B, 512, 0, stream>>>(XLN, (float*)d_out, L);
}

// Round 4
// 1461.267 us; speedup vs baseline: 2.3729x; 1.1222x over previous
//
#include <hip/hip_runtime.h>
#include <hip/hip_bf16.h>
#include <math.h>

typedef __hip_bfloat16 bf16;
typedef short bf16x8 __attribute__((ext_vector_type(8)));
typedef float f32x4 __attribute__((ext_vector_type(4)));

__device__ inline short f2bs(float x) {
  bf16 h = __float2bfloat16(x);
  return *reinterpret_cast<short*>(&h);
}

// ---------------- Threefry-2x32 (JAX-exact, 20 rounds) ----------------
__device__ inline void threefry2x32(unsigned k0, unsigned k1,
                                    unsigned x0, unsigned x1,
                                    unsigned& o0, unsigned& o1) {
  unsigned ks[3] = {k0, k1, k0 ^ k1 ^ 0x1BD11BDAu};
  const int rot[2][4] = {{13, 15, 26, 6}, {17, 29, 16, 24}};
  x0 += ks[0];
  x1 += ks[1];
  #pragma unroll
  for (int i = 0; i < 5; i++) {
    const int* r = rot[i & 1];
    #pragma unroll
    for (int j = 0; j < 4; j++) {
      x0 += x1;
      x1 = (x1 << r[j]) | (x1 >> (32 - r[j]));
      x1 ^= x0;
    }
    x0 += ks[(i + 1) % 3];
    x1 += ks[(i + 2) % 3] + (unsigned)(i + 1);
  }
  o0 = x0;
  o1 = x1;
}

__global__ void idx_kernel(int* __restrict__ idx, int L, int U, int layer) {
  int total = L * U, half = total / 2;
  int i = blockIdx.x * blockDim.x + threadIdx.x;
  if (i >= half) return;
  unsigned k0, k1;
  threefry2x32(0u, 42u, 0u, (unsigned)layer, k0, k1);
  unsigned o0, o1;
  threefry2x32(k0, k1, (unsigned)i, (unsigned)(half + i), o0, o1);
  idx[i] = (int)(o0 & (unsigned)(L - 1));
  idx[half + i] = (int)(o1 & (unsigned)(L - 1));
}

// ---------------- bf16 MFMA GEMM: C = A[M,K] @ W[N,K]^T (+bias)(+R)(relu) ---
__global__ __launch_bounds__(256) void bgemm_kernel(
    const bf16* __restrict__ A, const bf16* __restrict__ W,
    const float* __restrict__ bias, const float* __restrict__ R, int rmod,
    float* __restrict__ C, bf16* __restrict__ Cb,
    int M, int N, int K, int relu, int outmode) {
  __shared__ bf16 As[128 * 32];
  __shared__ bf16 Ws[128 * 32];
  int tid = threadIdx.x;
  int lane = tid & 63, w = tid >> 6;
  size_t row0 = (size_t)blockIdx.x * 128, col0 = (size_t)blockIdx.y * 128;
  int srow = (w << 4) + (lane >> 2);
  int scol = (lane & 3) << 3;
  const bf16* ag0 = A + (row0 + srow) * K + scol;
  const bf16* ag1 = A + (row0 + 64 + srow) * K + scol;
  const bf16* wg0 = W + (col0 + srow) * K + scol;
  const bf16* wg1 = W + (col0 + 64 + srow) * K + scol;
  int wb0 = (w << 9) + (lane << 3);
  int wb1 = wb0 + 2048;
  int wr = (w >> 1) << 6, wc = (w & 1) << 6;
  int fr = lane & 15, fk = (lane >> 4) << 3;
  f32x4 acc[4][4] = {};
  bf16x8 ra0 = *(const bf16x8*)ag0;
  bf16x8 ra1 = *(const bf16x8*)ag1;
  bf16x8 rw0 = *(const bf16x8*)wg0;
  bf16x8 rw1 = *(const bf16x8*)wg1;
  for (int k0 = 0; k0 < K; k0 += 32) {
    __syncthreads();
    *(bf16x8*)(As + wb0) = ra0;
    *(bf16x8*)(As + wb1) = ra1;
    *(bf16x8*)(Ws + wb0) = rw0;
    *(bf16x8*)(Ws + wb1) = rw1;
    if (k0 + 32 < K) {
      ag0 += 32; ag1 += 32; wg0 += 32; wg1 += 32;
      ra0 = *(const bf16x8*)ag0;
      ra1 = *(const bf16x8*)ag1;
      rw0 = *(const bf16x8*)wg0;
      rw1 = *(const bf16x8*)wg1;
    }
    __syncthreads();
    bf16x8 af[4], bfv[4];
    #pragma unroll
    for (int m = 0; m < 4; m++)
      af[m] = *(const bf16x8*)(As + (wr + m * 16 + fr) * 32 + fk);
    #pragma unroll
    for (int n = 0; n < 4; n++)
      bfv[n] = *(const bf16x8*)(Ws + (wc + n * 16 + fr) * 32 + fk);
    #pragma unroll
    for (int m = 0; m < 4; m++)
      #pragma unroll
      for (int n = 0; n < 4; n++)
        acc[m][n] = __builtin_amdgcn_mfma_f32_16x16x32_bf16(af[m], bfv[n], acc[m][n], 0, 0, 0);
  }
  int cr = (lane >> 4) << 2;
  int cc0 = lane & 15;
  #pragma unroll
  for (int m = 0; m < 4; m++) {
    #pragma unroll
    for (int n = 0; n < 4; n++) {
      #pragma unroll
      for (int r = 0; r < 4; r++) {
        size_t rr = row0 + wr + m * 16 + cr + r;
        size_t cc = col0 + wc + n * 16 + cc0;
        float v = acc[m][n][r];
        if (bias) v += bias[cc];
        if (R) v += rmod ? R[(rr % rmod) * N + cc] : R[rr * N + cc];
        if (relu) v = fmaxf(v, 0.f);
        if (outmode != 2) C[rr * N + cc] = v;
        if (outmode) Cb[rr * N + cc] = __float2bfloat16(v);
      }
    }
  }
}

// ---------------- weight/activation casts -----------------------------------
__global__ void cast4_kernel(const float* __restrict__ s, bf16* __restrict__ d, int n4) {
  int i = blockIdx.x * 256 + threadIdx.x;
  if (i >= n4) return;
  float4 v = ((const float4*)s)[i];
  d[i * 4 + 0] = __float2bfloat16(v.x);
  d[i * 4 + 1] = __float2bfloat16(v.y);
  d[i * 4 + 2] = __float2bfloat16(v.z);
  d[i * 4 + 3] = __float2bfloat16(v.w);
}

// dcw [o][c][k] -> wcol[o][k*512+c] bf16
__global__ void wperm_kernel(const float* __restrict__ w, bf16* __restrict__ wcol) {
  int i = blockIdx.x * 256 + threadIdx.x;
  if (i >= 512 * 1536) return;
  int o = i / 1536, r = i % 1536, k = r / 512, c = r % 512;
  wcol[i] = __float2bfloat16(w[o * 1536 + c * 3 + k]);
}

// tok_w [o][c][k] (c<64,k<3) -> [o][k*64+c] bf16
__global__ void tokperm_kernel(const float* __restrict__ w, bf16* __restrict__ d) {
  int i = blockIdx.x * 256 + threadIdx.x;
  if (i >= 512 * 192) return;
  int o = i / 192, r = i % 192, k = r / 64, c = r % 64;
  d[i] = __float2bfloat16(w[o * 192 + c * 3 + k]);
}

// PE table [1024][512] fp32
__global__ void pe_kernel(float* __restrict__ PE) {
  int t = blockIdx.x, o = threadIdx.x;
  int i2 = o >> 1;
  float div = expf((float)(2 * i2) * (-9.210340371976184f / 512.f));
  float ang = (float)t * div;
  PE[t * 512 + o] = (o & 1) ? cosf(ang) : sinf(ang);
}

// embedding im2col: x_enc -> [B*L, 192] bf16 (j = k*64+c), +1e-10
__global__ void im2col_e_kernel(const float* __restrict__ x, bf16* __restrict__ d,
                                int B, int L) {
  size_t i = (size_t)blockIdx.x * 256 + threadIdx.x;
  if (i >= (size_t)B * L * 192) return;
  int j = (int)(i % 192);
  size_t row = i / 192;
  int k = j >> 6, c = j & 63;
  int t = (int)(row % L), b = (int)(row / L);
  int ts = (t - 1 + k) & (L - 1);
  d[i] = __float2bfloat16(x[((size_t)(b * L + ts)) * 64 + c] + 1e-10f);
}

// ---------------- sparsity measure M ----------------------------------------
__global__ __launch_bounds__(256) void sparsity_kernel(
    const float* __restrict__ Q, const float* __restrict__ Kf,
    const int* __restrict__ idx, float* __restrict__ M,
    int B, int H, int L, int U) {
  int gid = blockIdx.x * blockDim.x + threadIdx.x;
  int wid = gid >> 6;
  int lane = threadIdx.x & 63;
  if (wid >= B * H * L) return;
  int t = wid % L, h = (wid / L) % H, b = wid / (L * H);
  float dot = 0.f;
  if (lane < U) {
    int kt = idx[t * U + lane];
    const float* qrow = Q + ((size_t)(b * L + t)) * 512 + h * 64;
    const float* krow = Kf + ((size_t)(b * L + kt)) * 512 + h * 64;
    #pragma unroll 8
    for (int d = 0; d < 64; d++) dot += qrow[d] * krow[d];
  }
  float mx = (lane < U) ? dot : -INFINITY;
  float sm = (lane < U) ? dot : 0.f;
  #pragma unroll
  for (int off = 32; off; off >>= 1) {
    mx = fmaxf(mx, __shfl_xor(mx, off));
    sm += __shfl_xor(sm, off);
  }
  if (lane == 0) M[wid] = mx - sm / (float)L;
}

// ---------------- top-k: 1 wave per (b,h), shfl butterfly argmax -------------
__global__ __launch_bounds__(64) void topk_kernel(
    const float* __restrict__ M, int* __restrict__ top, int L, int U) {
  __shared__ float mv[1024];
  int bh = blockIdx.x, lane = threadIdx.x;
  for (int t = lane; t < L; t += 64) mv[t] = M[(size_t)bh * L + t];
  __syncthreads();
  for (int it = 0; it < U; it++) {
    float bv = -INFINITY;
    int bi = L;
    for (int t = lane; t < L; t += 64) {
      float v = mv[t];
      if (v > bv || (v == bv && t < bi)) { bv = v; bi = t; }
    }
    #pragma unroll
    for (int off = 32; off; off >>= 1) {
      float ov = __shfl_xor(bv, off);
      int oi = __shfl_xor(bi, off);
      if (ov > bv || (ov == bv && oi < bi)) { bv = ov; bi = oi; }
    }
    if (lane == 0) {
      top[bh * U + it] = bi;
      mv[bi] = -INFINITY;
    }
    __syncthreads();
  }
}

// ---------------- V mean: deterministic 2-stage -----------------------------
__global__ __launch_bounds__(512) void vmean_part_kernel(
    const float* __restrict__ V, float* __restrict__ VP, int L, int segs) {
  int b = blockIdx.x, s = blockIdx.y, c = threadIdx.x;
  int per = L / segs;
  const float* vb = V + ((size_t)(b * L + s * per)) * 512 + c;
  float acc = 0.f;
  for (int t = 0; t < per; t++) acc += vb[(size_t)t * 512];
  VP[((size_t)(b * segs + s)) * 512 + c] = acc;
}

__global__ void vmean_reduce_kernel(const float* __restrict__ VP, float* __restrict__ Vmean,
                                    int segs, int L) {
  int i = blockIdx.x * 256 + threadIdx.x;  // B*512
  if (i >= 8 * 512) return;
  int b = i >> 9, c = i & 511;
  float acc = 0.f;
  for (int s = 0; s < segs; s++) acc += VP[((size_t)(b * segs + s)) * 512 + c];
  Vmean[i] = acc / (float)L;
}

// ---------------- broadcast ctx = Vmean (bf16 out) ---------------------------
__global__ void bcast_ctx_kernel(const float* __restrict__ Vmean, bf16* __restrict__ ATTb,
                                 int B, int L) {
  size_t i = (size_t)blockIdx.x * 256 + threadIdx.x;
  if (i >= (size_t)B * L * 512) return;
  int c = (int)(i % 512);
  int b = (int)(i / ((size_t)512 * L));
  ATTb[i] = __float2bfloat16(Vmean[b * 512 + c]);
}

// ---------------- batched MFMA flash attention for top-U queries ------------
// one block per (b,h); 4 waves; Qr padded to 64 rows; key tiles of 64.
__global__ __launch_bounds__(256) void attn_mfma_kernel(
    const float* __restrict__ Qf, const float* __restrict__ Kf,
    const float* __restrict__ Vf, const int* __restrict__ top,
    bf16* __restrict__ ATTb, int B, int H, int L, int U) {
  __shared__ short q_lds[64 * 72];       // [q][d]   stride 72
  __shared__ short k_lds[64 * 72];       // [key][d] stride 72 (B-op: N=key,K=d)
  __shared__ short vt_lds[64 * 72];      // [d][key] stride 72 (B-op: N=d,K=key)
  __shared__ short p_lds[4][16 * 72];    // per-wave P [q16][key64]
  int bh = blockIdx.x;
  int h = bh & 7, b = bh >> 3;
  int tid = threadIdx.x;
  int lane = tid & 63, w = tid >> 6;
  int r = tid >> 2, q4 = tid & 3, c0 = q4 << 4;
  int fr = lane & 15, fk = (lane >> 4) << 3, g = lane >> 4;

  // ---- stage Qr (rows >= U zero-padded) ----
  {
    short tmp[16];
    if (r < U) {
      int tq = top[bh * U + r];
      const float* src = Qf + ((size_t)(b * L + tq)) * 512 + h * 64 + c0;
      #pragma unroll
      for (int i = 0; i < 4; i++) {
        float4 v = ((const float4*)src)[i];
        tmp[i * 4 + 0] = f2bs(v.x); tmp[i * 4 + 1] = f2bs(v.y);
        tmp[i * 4 + 2] = f2bs(v.z); tmp[i * 4 + 3] = f2bs(v.w);
      }
    } else {
      #pragma unroll
      for (int i = 0; i < 16; i++) tmp[i] = 0;
    }
    *(bf16x8*)&q_lds[r * 72 + c0] = *(bf16x8*)&tmp[0];
    *(bf16x8*)&q_lds[r * 72 + c0 + 8] = *(bf16x8*)&tmp[8];
  }
  __syncthreads();
  bf16x8 aq0 = *(const bf16x8*)&q_lds[(w * 16 + fr) * 72 + fk];
  bf16x8 aq1 = *(const bf16x8*)&q_lds[(w * 16 + fr) * 72 + 32 + fk];

  f32x4 ctx[4] = {};
  float m_run[4], l_run[4];
  #pragma unroll
  for (int i = 0; i < 4; i++) { m_run[i] = -INFINITY; l_run[i] = 0.f; }

  for (int t0 = 0; t0 < L; t0 += 64) {
    __syncthreads();
    // stage K tile [key][d] and V tile transposed [d][key]
    {
      const float* ks = Kf + ((size_t)(b * L + t0 + r)) * 512 + h * 64 + c0;
      const float* vs = Vf + ((size_t)(b * L + t0 + r)) * 512 + h * 64 + c0;
      short kt[16];
      #pragma unroll
      for (int i = 0; i < 4; i++) {
        float4 v = ((const float4*)ks)[i];
        kt[i * 4 + 0] = f2bs(v.x); kt[i * 4 + 1] = f2bs(v.y);
        kt[i * 4 + 2] = f2bs(v.z); kt[i * 4 + 3] = f2bs(v.w);
      }
      *(bf16x8*)&k_lds[r * 72 + c0] = *(bf16x8*)&kt[0];
      *(bf16x8*)&k_lds[r * 72 + c0 + 8] = *(bf16x8*)&kt[8];
      #pragma unroll
      for (int i = 0; i < 4; i++) {
        float4 v = ((const float4*)vs)[i];
        vt_lds[(c0 + i * 4 + 0) * 72 + r] = f2bs(v.x);
        vt_lds[(c0 + i * 4 + 1) * 72 + r] = f2bs(v.y);
        vt_lds[(c0 + i * 4 + 2) * 72 + r] = f2bs(v.z);
        vt_lds[(c0 + i * 4 + 3) * 72 + r] = f2bs(v.w);
      }
    }
    __syncthreads();
    // ---- QK^T for this wave's 16 q rows ----
    f32x4 s[4];
    #pragma unroll
    for (int n = 0; n < 4; n++) {
      bf16x8 b0 = *(const bf16x8*)&k_lds[(n * 16 + fr) * 72 + fk];
      bf16x8 b1 = *(const bf16x8*)&k_lds[(n * 16 + fr) * 72 + 32 + fk];
      f32x4 z = {};
      z = __builtin_amdgcn_mfma_f32_16x16x32_bf16(aq0, b0, z, 0, 0, 0);
      s[n] = __builtin_amdgcn_mfma_f32_16x16x32_bf16(aq1, b1, z, 0, 0, 0);
    }
    #pragma unroll
    for (int n = 0; n < 4; n++)
      #pragma unroll
      for (int rg = 0; rg < 4; rg++) s[n][rg] *= 0.125f;
    // ---- online softmax (rows = g*4+rg, cols across fr and n) ----
    #pragma unroll
    for (int rg = 0; rg < 4; rg++) {
      float tm = fmaxf(fmaxf(s[0][rg], s[1][rg]), fmaxf(s[2][rg], s[3][rg]));
      #pragma unroll
      for (int off = 1; off < 16; off <<= 1) tm = fmaxf(tm, __shfl_xor(tm, off));
      float mnew = fmaxf(m_run[rg], tm);
      float sc_old = expf(m_run[rg] - mnew);
      float rowsum = 0.f;
      #pragma unroll
      for (int n = 0; n < 4; n++) {
        float p = expf(s[n][rg] - mnew);
        s[n][rg] = p;
        rowsum += p;
      }
      #pragma unroll
      for (int off = 1; off < 16; off <<= 1) rowsum += __shfl_xor(rowsum, off);
      l_run[rg] = l_run[rg] * sc_old + rowsum;
      m_run[rg] = mnew;
      #pragma unroll
      for (int nd = 0; nd < 4; nd++) ctx[nd][rg] *= sc_old;
    }
    // ---- P -> LDS (per-wave), then PV ----
    short* pw = p_lds[w];
    #pragma unroll
    for (int n = 0; n < 4; n++)
      #pragma unroll
      for (int rg = 0; rg < 4; rg++)
        pw[(g * 4 + rg) * 72 + n * 16 + fr] = f2bs(s[n][rg]);
    bf16x8 pa0 = *(const bf16x8*)&pw[fr * 72 + fk];
    bf16x8 pa1 = *(const bf16x8*)&pw[fr * 72 + 32 + fk];
    #pragma unroll
    for (int nd = 0; nd < 4; nd++) {
      bf16x8 v0 = *(const bf16x8*)&vt_lds[(nd * 16 + fr) * 72 + fk];
      bf16x8 v1 = *(const bf16x8*)&vt_lds[(nd * 16 + fr) * 72 + 32 + fk];
      ctx[nd] = __builtin_amdgcn_mfma_f32_16x16x32_bf16(pa0, v0, ctx[nd], 0, 0, 0);
      ctx[nd] = __builtin_amdgcn_mfma_f32_16x16x32_bf16(pa1, v1, ctx[nd], 0, 0, 0);
    }
  }
  // ---- epilogue: scatter ctx/l to top rows ----
  #pragma unroll
  for (int rg = 0; rg < 4; rg++) {
    int qq = w * 16 + g * 4 + rg;
    if (qq < U) {
      int tq = top[bh * U + qq];
      float inv = 1.f / l_run[rg];
      #pragma unroll
      for (int nd = 0; nd < 4; nd++) {
        int d = nd * 16 + fr;
        ATTb[((size_t)(b * L + tq)) * 512 + h * 64 + d] =
            __float2bfloat16(ctx[nd][rg] * inv);
      }
    }
  }
}

// ---------------- row LayerNorm (+ optional bf16 out) ------------------------
__global__ __launch_bounds__(256) void ln_kernel(
    const float* __restrict__ Xin, const float* __restrict__ g,
    const float* __restrict__ bta, float* __restrict__ Xout,
    bf16* __restrict__ Xoutb, int rows) {
  __shared__ float red[256];
  int r = blockIdx.x, tid = threadIdx.x;
  const float* xr = Xin + (size_t)r * 512;
  float v0 = xr[tid], v1 = xr[tid + 256];
  red[tid] = v0 + v1;
  __syncthreads();
  for (int s = 128; s > 0; s >>= 1) {
    if (tid < s) red[tid] += red[tid + s];
    __syncthreads();
  }
  float mean = red[0] / 512.f;
  __syncthreads();
  float d0 = v0 - mean, d1 = v1 - mean;
  red[tid] = d0 * d0 + d1 * d1;
  __syncthreads();
  for (int s = 128; s > 0; s >>= 1) {
    if (tid < s) red[tid] += red[tid + s];
    __syncthreads();
  }
  float rs = rsqrtf(red[0] / 512.f + 1e-5f);
  float o0 = d0 * rs * g[tid] + bta[tid];
  float o1 = d1 * rs * g[tid + 256] + bta[tid + 256];
  float* out = Xout + (size_t)r * 512;
  out[tid] = o0;
  out[tid + 256] = o1;
  if (Xoutb) {
    Xoutb[(size_t)r * 512 + tid] = __float2bfloat16(o0);
    Xoutb[(size_t)r * 512 + tid + 256] = __float2bfloat16(o1);
  }
}

// ---------------- im2col for k=3 circular conv (bf16 out) -------------------
__global__ void im2col_kernel(const float* __restrict__ X, bf16* __restrict__ XCOL,
                              int B, int L) {
  size_t i = (size_t)blockIdx.x * 256 + threadIdx.x;
  size_t total = (size_t)B * L * 1536;
  if (i >= total) return;
  int c = (int)(i % 512);
  int k = (int)((i / 512) % 3);
  size_t row = i / 1536;
  int t = (int)(row % L), b = (int)(row / L);
  int ts = (t - 1 + k + L) % L;
  XCOL[i] = __float2bfloat16(X[((size_t)(b * L + ts)) * 512 + c]);
}

// ---------------- BatchNorm stats -------------------------------------------
__global__ void zero_kernel(float* p, int n) {
  int i = blockIdx.x * 256 + threadIdx.x;
  if (i < n) p[i] = 0.f;
}

__global__ __launch_bounds__(256) void bnstat_kernel(
    const float* __restrict__ Y, float* __restrict__ acc, int rows) {
  int tid = threadIdx.x;
  int c0 = tid, c1 = tid + 256;
  float s0 = 0, s1 = 0, q0 = 0, q1 = 0;
  for (int r = blockIdx.x; r < rows; r += gridDim.x) {
    float v0 = Y[(size_t)r * 512 + c0];
    float v1 = Y[(size_t)r * 512 + c1];
    s0 += v0; q0 += v0 * v0;
    s1 += v1; q1 += v1 * v1;
  }
  atomicAdd(&acc[c0], s0);
  atomicAdd(&acc[c1], s1);
  atomicAdd(&acc[512 + c0], q0);
  atomicAdd(&acc[512 + c1], q1);
}

// ---------------- fused BN + ELU + MaxPool(3,2,1) (+bf16 out) ---------------
__global__ void bnpool_kernel(const float* __restrict__ Y, const float* __restrict__ acc,
                              const float* __restrict__ g, const float* __restrict__ be,
                              float* __restrict__ Xout, bf16* __restrict__ Xoutb,
                              int B, int L, int rows) {
  int Lout = L / 2;
  size_t i = (size_t)blockIdx.x * 256 + threadIdx.x;
  if (i >= (size_t)B * Lout * 512) return;
  int c = (int)(i % 512);
  size_t orow = i / 512;
  int to = (int)(orow % Lout), b = (int)(orow / Lout);
  float mu = acc[c] / (float)rows;
  float var = acc[512 + c] / (float)rows - mu * mu;
  float rs = rsqrtf(var + 1e-5f) * g[c];
  float mx = -INFINITY;
  #pragma unroll
  for (int dj = -1; dj <= 1; dj++) {
    int j = 2 * to + dj;
    if (j < 0 || j >= L) continue;
    float v = (Y[((size_t)(b * L + j)) * 512 + c] - mu) * rs + be[c];
    v = v > 0.f ? v : expm1f(v);
    mx = fmaxf(mx, v);
  }
  Xout[i] = mx;
  Xoutb[i] = __float2bfloat16(mx);
}

// ---------------- final mean over rows --------------------------------------
__global__ void meanrows_kernel(const float* __restrict__ Xin, float* __restrict__ out, int L) {
  int b = blockIdx.x, d = threadIdx.x;
  float s = 0.f;
  for (int t = 0; t < L; t++) s += Xin[((size_t)(b * L + t)) * 512 + d];
  out[b * 512 + d] = s / (float)L;
}

// ============================================================================
extern "C" void kernel_launch(void* const* d_in, const int* in_sizes, int n_in,
                              void* d_out, int out_size, void* d_ws, size_t ws_size,
                              hipStream_t stream) {
  const float* x_enc = (const float*)d_in[0];
  const float* tok_w = (const float*)d_in[1];
  const float* Wq = (const float*)d_in[2];
  const float* bq = (const float*)d_in[3];
  const float* Wk = (const float*)d_in[4];
  const float* bk = (const float*)d_in[5];
  const float* Wv = (const float*)d_in[6];
  const float* bv = (const float*)d_in[7];
  const float* Wo = (const float*)d_in[8];
  const float* bo = (const float*)d_in[9];
  const float* c1w = (const float*)d_in[10];
  const float* c1b = (const float*)d_in[11];
  const float* c2w = (const float*)d_in[12];
  const float* c2b = (const float*)d_in[13];
  const float* n1g = (const float*)d_in[14];
  const float* n1b = (const float*)d_in[15];
  const float* n2g = (const float*)d_in[16];
  const float* n2b = (const float*)d_in[17];
  const float* dcw = (const float*)d_in[18];
  const float* dcb = (const float*)d_in[19];
  const float* bng = (const float*)d_in[20];
  const float* bnb = (const float*)d_in[21];
  const float* fng = (const float*)d_in[22];
  const float* fnb = (const float*)d_in[23];

  const int B = 8, H = 8;
  const size_t NX = 4194304;  // 8*1024*512

  float* ws = (float*)d_ws;
  float* X    = ws;
  float* XLN  = ws + NX;
  float* Qf   = ws + 2 * NX;
  float* Kf   = ws + 3 * NX;
  float* Vf   = ws + 4 * NX;
  bf16* INb   = (bf16*)(ws + 5 * NX);
  bf16* ATTb  = (bf16*)(ws + 5 * NX + NX / 2);
  bf16* H2b   = (bf16*)Qf;
  bf16* XCOLb = (bf16*)Vf;
  float* Yc   = Qf;
  float* WB   = ws + 6 * NX;
  bf16* Wqb  = (bf16*)(WB);
  bf16* Wkb  = (bf16*)(WB + 131072);
  bf16* Wvb  = (bf16*)(WB + 262144);
  bf16* Wob  = (bf16*)(WB + 393216);
  bf16* c1wb = (bf16*)(WB + 524288);
  bf16* c2wb = (bf16*)(WB + 1048576);
  bf16* wcvb = (bf16*)(WB + 1572864);
  bf16* tokwb = (bf16*)(WB + 1966080);
  float* PE   = WB + 2015232;
  float* MBUF = PE + 524288;
  float* VMEAN = MBUF + 65536;
  float* BNACC = VMEAN + 4096;
  int* IDX = (int*)(BNACC + 1024);
  int* TOP = IDX + 35840;
  float* VPART = (float*)(TOP + 2240);   // [8][32][512]

  // ---- embedding as GEMM ----
  pe_kernel<<<1024, 512, 0, stream>>>(PE);
  tokperm_kernel<<<(512 * 192 + 255) / 256, 256, 0, stream>>>(tok_w, tokwb);
  im2col_e_kernel<<<(int)(((size_t)B * 1024 * 192 + 255) / 256), 256, 0, stream>>>(
      x_enc, INb, B, 1024);
  bgemm_kernel<<<dim3(64, 4), 256, 0, stream>>>(INb, tokwb, nullptr, PE, 1024,
                                                X, nullptr, 8192, 512, 192, 0, 0);
  cast4_kernel<<<4096, 256, 0, stream>>>(X, INb, 1048576);

  int L = 1024;
  for (int l = 0; l < 3; l++) {
    int U = (L == 256) ? 30 : 35;
    int rows = B * L;
    dim3 g512(rows / 128, 4);

    cast4_kernel<<<256, 256, 0, stream>>>(Wq + (size_t)l * 262144, Wqb, 65536);
    cast4_kernel<<<256, 256, 0, stream>>>(Wk + (size_t)l * 262144, Wkb, 65536);
    cast4_kernel<<<256, 256, 0, stream>>>(Wv + (size_t)l * 262144, Wvb, 65536);
    cast4_kernel<<<256, 256, 0, stream>>>(Wo + (size_t)l * 262144, Wob, 65536);
    cast4_kernel<<<1024, 256, 0, stream>>>(c1w + (size_t)l * 1048576, c1wb, 262144);
    cast4_kernel<<<1024, 256, 0, stream>>>(c2w + (size_t)l * 1048576, c2wb, 262144);
    if (l < 2)
      wperm_kernel<<<3072, 256, 0, stream>>>(dcw + (size_t)l * 786432, wcvb);

    bgemm_kernel<<<g512, 256, 0, stream>>>(INb, Wqb, bq + l * 512, nullptr, 0,
                                           Qf, nullptr, rows, 512, 512, 0, 0);
    bgemm_kernel<<<g512, 256, 0, stream>>>(INb, Wkb, bk + l * 512, nullptr, 0,
                                           Kf, nullptr, rows, 512, 512, 0, 0);
    bgemm_kernel<<<g512, 256, 0, stream>>>(INb, Wvb, bv + l * 512, nullptr, 0,
                                           Vf, nullptr, rows, 512, 512, 0, 0);

    int half = L * U / 2;
    idx_kernel<<<(half + 255) / 256, 256, 0, stream>>>(IDX, L, U, l);
    sparsity_kernel<<<(B * H * L) / 4, 256, 0, stream>>>(Qf, Kf, IDX, MBUF, B, H, L, U);
    topk_kernel<<<B * H, 64, 0, stream>>>(MBUF, TOP, L, U);
    vmean_part_kernel<<<dim3(B, 32), 512, 0, stream>>>(Vf, VPART, L, 32);
    vmean_reduce_kernel<<<16, 256, 0, stream>>>(VPART, VMEAN, 32, L);
    bcast_ctx_kernel<<<(rows * 512) / 256, 256, 0, stream>>>(VMEAN, ATTb, B, L);
    attn_mfma_kernel<<<B * H, 256, 0, stream>>>(Qf, Kf, Vf, TOP, ATTb, B, H, L, U);

    bgemm_kernel<<<g512, 256, 0, stream>>>(ATTb, Wob, bo + l * 512, X, 0,
                                           X, nullptr, rows, 512, 512, 0, 0);
    ln_kernel<<<rows, 256, 0, stream>>>(X, n1g + l * 512, n1b + l * 512, XLN, INb, rows);
    bgemm_kernel<<<dim3(rows / 128, 16), 256, 0, stream>>>(
        INb, c1wb, c1b + l * 2048, nullptr, 0, nullptr, H2b, rows, 2048, 512, 1, 2);
    bgemm_kernel<<<g512, 256, 0, stream>>>(H2b, c2wb, c2b + l * 512, XLN, 0,
                                           X, nullptr, rows, 512, 2048, 0, 0);
    ln_kernel<<<rows, 256, 0, stream>>>(X, n2g + l * 512, n2b + l * 512, X, nullptr, rows);

    if (l < 2) {
      im2col_kernel<<<(int)(((size_t)rows * 1536) / 256), 256, 0, stream>>>(X, XCOLb, B, L);
      bgemm_kernel<<<g512, 256, 0, stream>>>(XCOLb, wcvb, dcb + l * 512, nullptr, 0,
                                             Yc, nullptr, rows, 512, 1536, 0, 0);
      zero_kernel<<<4, 256, 0, stream>>>(BNACC, 1024);
      bnstat_kernel<<<128, 256, 0, stream>>>(Yc, BNACC, rows);
      bnpool_kernel<<<(rows / 2 * 512) / 256, 256, 0, stream>>>(
          Yc, BNACC, bng + l * 512, bnb + l * 512, X, INb, B, L, rows);
      L >>= 1;
    }
  }

  int rowsF = B * L;  // L = 256
  ln_kernel<<<rowsF, 256, 0, stream>>>(X, fng, fnb, XLN, nullptr, rowsF);
  meanrows_kernel<<<B, 512, 0, stream>>>(XLN, (float*)d_out, L);
}

// Round 5
// 1374.597 us; speedup vs baseline: 2.5225x; 1.0631x over previous
//
#include <hip/hip_runtime.h>
#include <hip/hip_bf16.h>
#include <math.h>

typedef __hip_bfloat16 bf16;
typedef short bf16x8 __attribute__((ext_vector_type(8)));
typedef float f32x4 __attribute__((ext_vector_type(4)));

__device__ inline short f2bs(float x) {
  bf16 h = __float2bfloat16(x);
  return *reinterpret_cast<short*>(&h);
}

// ---------------- Threefry-2x32 (JAX-exact, 20 rounds) ----------------
__device__ inline void threefry2x32(unsigned k0, unsigned k1,
                                    unsigned x0, unsigned x1,
                                    unsigned& o0, unsigned& o1) {
  unsigned ks[3] = {k0, k1, k0 ^ k1 ^ 0x1BD11BDAu};
  const int rot[2][4] = {{13, 15, 26, 6}, {17, 29, 16, 24}};
  x0 += ks[0];
  x1 += ks[1];
  #pragma unroll
  for (int i = 0; i < 5; i++) {
    const int* r = rot[i & 1];
    #pragma unroll
    for (int j = 0; j < 4; j++) {
      x0 += x1;
      x1 = (x1 << r[j]) | (x1 >> (32 - r[j]));
      x1 ^= x0;
    }
    x0 += ks[(i + 1) % 3];
    x1 += ks[(i + 2) % 3] + (unsigned)(i + 1);
  }
  o0 = x0;
  o1 = x1;
}

__global__ void idx_kernel(int* __restrict__ idx, int L, int U, int layer) {
  int total = L * U, half = total / 2;
  int i = blockIdx.x * blockDim.x + threadIdx.x;
  if (i >= half) return;
  unsigned k0, k1;
  threefry2x32(0u, 42u, 0u, (unsigned)layer, k0, k1);
  unsigned o0, o1;
  threefry2x32(k0, k1, (unsigned)i, (unsigned)(half + i), o0, o1);
  idx[i] = (int)(o0 & (unsigned)(L - 1));
  idx[half + i] = (int)(o1 & (unsigned)(L - 1));
}

// ---------------- bf16 MFMA GEMM: C = A[M,K] @ W[N,K]^T (+bias)(+R)(relu) ---
__global__ __launch_bounds__(256) void bgemm_kernel(
    const bf16* __restrict__ A, const bf16* __restrict__ W,
    const float* __restrict__ bias, const float* __restrict__ R, int rmod,
    float* __restrict__ C, bf16* __restrict__ Cb,
    int M, int N, int K, int relu, int outmode) {
  __shared__ bf16 As[128 * 32];
  __shared__ bf16 Ws[128 * 32];
  int tid = threadIdx.x;
  int lane = tid & 63, w = tid >> 6;
  size_t row0 = (size_t)blockIdx.x * 128, col0 = (size_t)blockIdx.y * 128;
  int srow = (w << 4) + (lane >> 2);
  int scol = (lane & 3) << 3;
  const bf16* ag0 = A + (row0 + srow) * K + scol;
  const bf16* ag1 = A + (row0 + 64 + srow) * K + scol;
  const bf16* wg0 = W + (col0 + srow) * K + scol;
  const bf16* wg1 = W + (col0 + 64 + srow) * K + scol;
  int wb0 = (w << 9) + (lane << 3);
  int wb1 = wb0 + 2048;
  int wr = (w >> 1) << 6, wc = (w & 1) << 6;
  int fr = lane & 15, fk = (lane >> 4) << 3;
  f32x4 acc[4][4] = {};
  bf16x8 ra0 = *(const bf16x8*)ag0;
  bf16x8 ra1 = *(const bf16x8*)ag1;
  bf16x8 rw0 = *(const bf16x8*)wg0;
  bf16x8 rw1 = *(const bf16x8*)wg1;
  for (int k0 = 0; k0 < K; k0 += 32) {
    __syncthreads();
    *(bf16x8*)(As + wb0) = ra0;
    *(bf16x8*)(As + wb1) = ra1;
    *(bf16x8*)(Ws + wb0) = rw0;
    *(bf16x8*)(Ws + wb1) = rw1;
    if (k0 + 32 < K) {
      ag0 += 32; ag1 += 32; wg0 += 32; wg1 += 32;
      ra0 = *(const bf16x8*)ag0;
      ra1 = *(const bf16x8*)ag1;
      rw0 = *(const bf16x8*)wg0;
      rw1 = *(const bf16x8*)wg1;
    }
    __syncthreads();
    bf16x8 af[4], bfv[4];
    #pragma unroll
    for (int m = 0; m < 4; m++)
      af[m] = *(const bf16x8*)(As + (wr + m * 16 + fr) * 32 + fk);
    #pragma unroll
    for (int n = 0; n < 4; n++)
      bfv[n] = *(const bf16x8*)(Ws + (wc + n * 16 + fr) * 32 + fk);
    #pragma unroll
    for (int m = 0; m < 4; m++)
      #pragma unroll
      for (int n = 0; n < 4; n++)
        acc[m][n] = __builtin_amdgcn_mfma_f32_16x16x32_bf16(af[m], bfv[n], acc[m][n], 0, 0, 0);
  }
  int cr = (lane >> 4) << 2;
  int cc0 = lane & 15;
  #pragma unroll
  for (int m = 0; m < 4; m++) {
    #pragma unroll
    for (int n = 0; n < 4; n++) {
      #pragma unroll
      for (int r = 0; r < 4; r++) {
        size_t rr = row0 + wr + m * 16 + cr + r;
        size_t cc = col0 + wc + n * 16 + cc0;
        float v = acc[m][n][r];
        if (bias) v += bias[cc];
        if (R) v += rmod ? R[(rr % rmod) * N + cc] : R[rr * N + cc];
        if (relu) v = fmaxf(v, 0.f);
        if (outmode != 2) C[rr * N + cc] = v;
        if (outmode) Cb[rr * N + cc] = __float2bfloat16(v);
      }
    }
  }
}

// ---------------- weight/activation casts -----------------------------------
__global__ void cast4_kernel(const float* __restrict__ s, bf16* __restrict__ d, int n4) {
  int i = blockIdx.x * 256 + threadIdx.x;
  if (i >= n4) return;
  float4 v = ((const float4*)s)[i];
  d[i * 4 + 0] = __float2bfloat16(v.x);
  d[i * 4 + 1] = __float2bfloat16(v.y);
  d[i * 4 + 2] = __float2bfloat16(v.z);
  d[i * 4 + 3] = __float2bfloat16(v.w);
}

// dcw [o][c][k] -> wcol[o][k*512+c] bf16
__global__ void wperm_kernel(const float* __restrict__ w, bf16* __restrict__ wcol) {
  int i = blockIdx.x * 256 + threadIdx.x;
  if (i >= 512 * 1536) return;
  int o = i / 1536, r = i % 1536, k = r / 512, c = r % 512;
  wcol[i] = __float2bfloat16(w[o * 1536 + c * 3 + k]);
}

// tok_w [o][c][k] (c<64,k<3) -> [o][k*64+c] bf16
__global__ void tokperm_kernel(const float* __restrict__ w, bf16* __restrict__ d) {
  int i = blockIdx.x * 256 + threadIdx.x;
  if (i >= 512 * 192) return;
  int o = i / 192, r = i % 192, k = r / 64, c = r % 64;
  d[i] = __float2bfloat16(w[o * 192 + c * 3 + k]);
}

// PE table [1024][512] fp32
__global__ void pe_kernel(float* __restrict__ PE) {
  int t = blockIdx.x, o = threadIdx.x;
  int i2 = o >> 1;
  float div = expf((float)(2 * i2) * (-9.210340371976184f / 512.f));
  float ang = (float)t * div;
  PE[t * 512 + o] = (o & 1) ? cosf(ang) : sinf(ang);
}

// embedding im2col: x_enc -> [B*L, 192] bf16 (j = k*64+c), +1e-10
__global__ void im2col_e_kernel(const float* __restrict__ x, bf16* __restrict__ d,
                                int B, int L) {
  size_t i = (size_t)blockIdx.x * 256 + threadIdx.x;
  if (i >= (size_t)B * L * 192) return;
  int j = (int)(i % 192);
  size_t row = i / 192;
  int k = j >> 6, c = j & 63;
  int t = (int)(row % L), b = (int)(row / L);
  int ts = (t - 1 + k) & (L - 1);
  d[i] = __float2bfloat16(x[((size_t)(b * L + ts)) * 64 + c] + 1e-10f);
}

// ---------------- sparsity measure M: 16-lane cooperative gather dots -------
// wave per (b,h,t); lane = u_local*16 + j; 16 lanes read one K row coalesced.
__global__ __launch_bounds__(256) void sparsity_kernel(
    const float* __restrict__ Q, const float* __restrict__ Kf,
    const int* __restrict__ idx, float* __restrict__ M,
    int B, int H, int L, int U) {
  int wid = blockIdx.x * 4 + (threadIdx.x >> 6);
  if (wid >= B * H * L) return;
  int lane = threadIdx.x & 63;
  int t = wid % L, h = (wid / L) % H, b = wid / (L * H);
  int ul = lane >> 4;   // u_local 0..3
  int j = lane & 15;    // d-chunk index
  const float* qrow = Q + ((size_t)(b * L + t)) * 512 + h * 64;
  float4 q4 = *(const float4*)(qrow + j * 4);
  const float* kbase = Kf + (size_t)b * L * 512 + h * 64;
  const int* irow = idx + t * U;
  float mx = -INFINITY, sm = 0.f;
  int iters = (U + 3) >> 2;   // 9 for U=35, 8 for U=30 (wait 30/4=7.5 -> 8)
  for (int i = 0; i < iters; i++) {
    int u = i * 4 + ul;
    bool valid = (u < U);
    int kt = valid ? irow[u] : 0;
    float4 k4 = *(const float4*)(kbase + (size_t)kt * 512 + j * 4);
    float part = q4.x * k4.x + q4.y * k4.y + q4.z * k4.z + q4.w * k4.w;
    #pragma unroll
    for (int off = 1; off < 16; off <<= 1) part += __shfl_xor(part, off);
    if (valid) { mx = fmaxf(mx, part); sm += part; }
  }
  // combine the 4 u-groups (lanes within a group hold identical values)
  #pragma unroll
  for (int off = 16; off < 64; off <<= 1) {
    mx = fmaxf(mx, __shfl_xor(mx, off));
    sm += __shfl_xor(sm, off);
  }
  if (lane == 0) M[wid] = mx - sm / (float)L;
}

// ---------------- top-k: 1 wave per (b,h), shfl butterfly argmax -------------
__global__ __launch_bounds__(64) void topk_kernel(
    const float* __restrict__ M, int* __restrict__ top, int L, int U) {
  __shared__ float mv[1024];
  int bh = blockIdx.x, lane = threadIdx.x;
  for (int t = lane; t < L; t += 64) mv[t] = M[(size_t)bh * L + t];
  __syncthreads();
  for (int it = 0; it < U; it++) {
    float bv = -INFINITY;
    int bi = L;
    for (int t = lane; t < L; t += 64) {
      float v = mv[t];
      if (v > bv || (v == bv && t < bi)) { bv = v; bi = t; }
    }
    #pragma unroll
    for (int off = 32; off; off >>= 1) {
      float ov = __shfl_xor(bv, off);
      int oi = __shfl_xor(bi, off);
      if (ov > bv || (ov == bv && oi < bi)) { bv = ov; bi = oi; }
    }
    if (lane == 0) {
      top[bh * U + it] = bi;
      mv[bi] = -INFINITY;
    }
    __syncthreads();
  }
}

// ---------------- V mean: deterministic 2-stage -----------------------------
__global__ __launch_bounds__(512) void vmean_part_kernel(
    const float* __restrict__ V, float* __restrict__ VP, int L, int segs) {
  int b = blockIdx.x, s = blockIdx.y, c = threadIdx.x;
  int per = L / segs;
  const float* vb = V + ((size_t)(b * L + s * per)) * 512 + c;
  float acc = 0.f;
  for (int t = 0; t < per; t++) acc += vb[(size_t)t * 512];
  VP[((size_t)(b * segs + s)) * 512 + c] = acc;
}

__global__ void vmean_reduce_kernel(const float* __restrict__ VP, float* __restrict__ Vmean,
                                    int segs, int L) {
  int i = blockIdx.x * 256 + threadIdx.x;  // B*512
  if (i >= 8 * 512) return;
  int b = i >> 9, c = i & 511;
  float acc = 0.f;
  for (int s = 0; s < segs; s++) acc += VP[((size_t)(b * segs + s)) * 512 + c];
  Vmean[i] = acc / (float)L;
}

// ---------------- broadcast ctx = Vmean (bf16 out) ---------------------------
__global__ void bcast_ctx_kernel(const float* __restrict__ Vmean, bf16* __restrict__ ATTb,
                                 int B, int L) {
  size_t i = (size_t)blockIdx.x * 256 + threadIdx.x;
  if (i >= (size_t)B * L * 512) return;
  int c = (int)(i % 512);
  int b = (int)(i / ((size_t)512 * L));
  ATTb[i] = __float2bfloat16(Vmean[b * 512 + c]);
}

// ---------------- batched MFMA flash attention for top-U queries ------------
__global__ __launch_bounds__(256) void attn_mfma_kernel(
    const float* __restrict__ Qf, const float* __restrict__ Kf,
    const float* __restrict__ Vf, const int* __restrict__ top,
    bf16* __restrict__ ATTb, int B, int H, int L, int U) {
  __shared__ short q_lds[64 * 72];
  __shared__ short k_lds[64 * 72];
  __shared__ short vt_lds[64 * 72];
  __shared__ short p_lds[4][16 * 72];
  int bh = blockIdx.x;
  int h = bh & 7, b = bh >> 3;
  int tid = threadIdx.x;
  int lane = tid & 63, w = tid >> 6;
  int r = tid >> 2, q4 = tid & 3, c0 = q4 << 4;
  int fr = lane & 15, fk = (lane >> 4) << 3, g = lane >> 4;

  {
    short tmp[16];
    if (r < U) {
      int tq = top[bh * U + r];
      const float* src = Qf + ((size_t)(b * L + tq)) * 512 + h * 64 + c0;
      #pragma unroll
      for (int i = 0; i < 4; i++) {
        float4 v = ((const float4*)src)[i];
        tmp[i * 4 + 0] = f2bs(v.x); tmp[i * 4 + 1] = f2bs(v.y);
        tmp[i * 4 + 2] = f2bs(v.z); tmp[i * 4 + 3] = f2bs(v.w);
      }
    } else {
      #pragma unroll
      for (int i = 0; i < 16; i++) tmp[i] = 0;
    }
    *(bf16x8*)&q_lds[r * 72 + c0] = *(bf16x8*)&tmp[0];
    *(bf16x8*)&q_lds[r * 72 + c0 + 8] = *(bf16x8*)&tmp[8];
  }
  __syncthreads();
  bf16x8 aq0 = *(const bf16x8*)&q_lds[(w * 16 + fr) * 72 + fk];
  bf16x8 aq1 = *(const bf16x8*)&q_lds[(w * 16 + fr) * 72 + 32 + fk];

  f32x4 ctx[4] = {};
  float m_run[4], l_run[4];
  #pragma unroll
  for (int i = 0; i < 4; i++) { m_run[i] = -INFINITY; l_run[i] = 0.f; }

  for (int t0 = 0; t0 < L; t0 += 64) {
    __syncthreads();
    {
      const float* ks = Kf + ((size_t)(b * L + t0 + r)) * 512 + h * 64 + c0;
      const float* vs = Vf + ((size_t)(b * L + t0 + r)) * 512 + h * 64 + c0;
      short kt[16];
      #pragma unroll
      for (int i = 0; i < 4; i++) {
        float4 v = ((const float4*)ks)[i];
        kt[i * 4 + 0] = f2bs(v.x); kt[i * 4 + 1] = f2bs(v.y);
        kt[i * 4 + 2] = f2bs(v.z); kt[i * 4 + 3] = f2bs(v.w);
      }
      *(bf16x8*)&k_lds[r * 72 + c0] = *(bf16x8*)&kt[0];
      *(bf16x8*)&k_lds[r * 72 + c0 + 8] = *(bf16x8*)&kt[8];
      #pragma unroll
      for (int i = 0; i < 4; i++) {
        float4 v = ((const float4*)vs)[i];
        vt_lds[(c0 + i * 4 + 0) * 72 + r] = f2bs(v.x);
        vt_lds[(c0 + i * 4 + 1) * 72 + r] = f2bs(v.y);
        vt_lds[(c0 + i * 4 + 2) * 72 + r] = f2bs(v.z);
        vt_lds[(c0 + i * 4 + 3) * 72 + r] = f2bs(v.w);
      }
    }
    __syncthreads();
    f32x4 s[4];
    #pragma unroll
    for (int n = 0; n < 4; n++) {
      bf16x8 b0 = *(const bf16x8*)&k_lds[(n * 16 + fr) * 72 + fk];
      bf16x8 b1 = *(const bf16x8*)&k_lds[(n * 16 + fr) * 72 + 32 + fk];
      f32x4 z = {};
      z = __builtin_amdgcn_mfma_f32_16x16x32_bf16(aq0, b0, z, 0, 0, 0);
      s[n] = __builtin_amdgcn_mfma_f32_16x16x32_bf16(aq1, b1, z, 0, 0, 0);
    }
    #pragma unroll
    for (int n = 0; n < 4; n++)
      #pragma unroll
      for (int rg = 0; rg < 4; rg++) s[n][rg] *= 0.125f;
    #pragma unroll
    for (int rg = 0; rg < 4; rg++) {
      float tm = fmaxf(fmaxf(s[0][rg], s[1][rg]), fmaxf(s[2][rg], s[3][rg]));
      #pragma unroll
      for (int off = 1; off < 16; off <<= 1) tm = fmaxf(tm, __shfl_xor(tm, off));
      float mnew = fmaxf(m_run[rg], tm);
      float sc_old = expf(m_run[rg] - mnew);
      float rowsum = 0.f;
      #pragma unroll
      for (int n = 0; n < 4; n++) {
        float p = expf(s[n][rg] - mnew);
        s[n][rg] = p;
        rowsum += p;
      }
      #pragma unroll
      for (int off = 1; off < 16; off <<= 1) rowsum += __shfl_xor(rowsum, off);
      l_run[rg] = l_run[rg] * sc_old + rowsum;
      m_run[rg] = mnew;
      #pragma unroll
      for (int nd = 0; nd < 4; nd++) ctx[nd][rg] *= sc_old;
    }
    short* pw = p_lds[w];
    #pragma unroll
    for (int n = 0; n < 4; n++)
      #pragma unroll
      for (int rg = 0; rg < 4; rg++)
        pw[(g * 4 + rg) * 72 + n * 16 + fr] = f2bs(s[n][rg]);
    bf16x8 pa0 = *(const bf16x8*)&pw[fr * 72 + fk];
    bf16x8 pa1 = *(const bf16x8*)&pw[fr * 72 + 32 + fk];
    #pragma unroll
    for (int nd = 0; nd < 4; nd++) {
      bf16x8 v0 = *(const bf16x8*)&vt_lds[(nd * 16 + fr) * 72 + fk];
      bf16x8 v1 = *(const bf16x8*)&vt_lds[(nd * 16 + fr) * 72 + 32 + fk];
      ctx[nd] = __builtin_amdgcn_mfma_f32_16x16x32_bf16(pa0, v0, ctx[nd], 0, 0, 0);
      ctx[nd] = __builtin_amdgcn_mfma_f32_16x16x32_bf16(pa1, v1, ctx[nd], 0, 0, 0);
    }
  }
  #pragma unroll
  for (int rg = 0; rg < 4; rg++) {
    int qq = w * 16 + g * 4 + rg;
    if (qq < U) {
      int tq = top[bh * U + qq];
      float inv = 1.f / l_run[rg];
      #pragma unroll
      for (int nd = 0; nd < 4; nd++) {
        int d = nd * 16 + fr;
        ATTb[((size_t)(b * L + tq)) * 512 + h * 64 + d] =
            __float2bfloat16(ctx[nd][rg] * inv);
      }
    }
  }
}

// ---------------- row LayerNorm (+ optional bf16 out) ------------------------
__global__ __launch_bounds__(256) void ln_kernel(
    const float* __restrict__ Xin, const float* __restrict__ g,
    const float* __restrict__ bta, float* __restrict__ Xout,
    bf16* __restrict__ Xoutb, int rows) {
  __shared__ float red[256];
  int r = blockIdx.x, tid = threadIdx.x;
  const float* xr = Xin + (size_t)r * 512;
  float v0 = xr[tid], v1 = xr[tid + 256];
  red[tid] = v0 + v1;
  __syncthreads();
  for (int s = 128; s > 0; s >>= 1) {
    if (tid < s) red[tid] += red[tid + s];
    __syncthreads();
  }
  float mean = red[0] / 512.f;
  __syncthreads();
  float d0 = v0 - mean, d1 = v1 - mean;
  red[tid] = d0 * d0 + d1 * d1;
  __syncthreads();
  for (int s = 128; s > 0; s >>= 1) {
    if (tid < s) red[tid] += red[tid + s];
    __syncthreads();
  }
  float rs = rsqrtf(red[0] / 512.f + 1e-5f);
  float o0 = d0 * rs * g[tid] + bta[tid];
  float o1 = d1 * rs * g[tid + 256] + bta[tid + 256];
  float* out = Xout + (size_t)r * 512;
  out[tid] = o0;
  out[tid + 256] = o1;
  if (Xoutb) {
    Xoutb[(size_t)r * 512 + tid] = __float2bfloat16(o0);
    Xoutb[(size_t)r * 512 + tid + 256] = __float2bfloat16(o1);
  }
}

// ---------------- im2col for k=3 circular conv (bf16 out) -------------------
__global__ void im2col_kernel(const float* __restrict__ X, bf16* __restrict__ XCOL,
                              int B, int L) {
  size_t i = (size_t)blockIdx.x * 256 + threadIdx.x;
  size_t total = (size_t)B * L * 1536;
  if (i >= total) return;
  int c = (int)(i % 512);
  int k = (int)((i / 512) % 3);
  size_t row = i / 1536;
  int t = (int)(row % L), b = (int)(row / L);
  int ts = (t - 1 + k + L) % L;
  XCOL[i] = __float2bfloat16(X[((size_t)(b * L + ts)) * 512 + c]);
}

// ---------------- BatchNorm stats -------------------------------------------
__global__ void zero_kernel(float* p, int n) {
  int i = blockIdx.x * 256 + threadIdx.x;
  if (i < n) p[i] = 0.f;
}

__global__ __launch_bounds__(256) void bnstat_kernel(
    const float* __restrict__ Y, float* __restrict__ acc, int rows) {
  int tid = threadIdx.x;
  int c0 = tid, c1 = tid + 256;
  float s0 = 0, s1 = 0, q0 = 0, q1 = 0;
  for (int r = blockIdx.x; r < rows; r += gridDim.x) {
    float v0 = Y[(size_t)r * 512 + c0];
    float v1 = Y[(size_t)r * 512 + c1];
    s0 += v0; q0 += v0 * v0;
    s1 += v1; q1 += v1 * v1;
  }
  atomicAdd(&acc[c0], s0);
  atomicAdd(&acc[c1], s1);
  atomicAdd(&acc[512 + c0], q0);
  atomicAdd(&acc[512 + c1], q1);
}

// ---------------- fused BN + ELU + MaxPool(3,2,1) (+bf16 out) ---------------
__global__ void bnpool_kernel(const float* __restrict__ Y, const float* __restrict__ acc,
                              const float* __restrict__ g, const float* __restrict__ be,
                              float* __restrict__ Xout, bf16* __restrict__ Xoutb,
                              int B, int L, int rows) {
  int Lout = L / 2;
  size_t i = (size_t)blockIdx.x * 256 + threadIdx.x;
  if (i >= (size_t)B * Lout * 512) return;
  int c = (int)(i % 512);
  size_t orow = i / 512;
  int to = (int)(orow % Lout), b = (int)(orow / Lout);
  float mu = acc[c] / (float)rows;
  float var = acc[512 + c] / (float)rows - mu * mu;
  float rs = rsqrtf(var + 1e-5f) * g[c];
  float mx = -INFINITY;
  #pragma unroll
  for (int dj = -1; dj <= 1; dj++) {
    int j = 2 * to + dj;
    if (j < 0 || j >= L) continue;
    float v = (Y[((size_t)(b * L + j)) * 512 + c] - mu) * rs + be[c];
    v = v > 0.f ? v : expm1f(v);
    mx = fmaxf(mx, v);
  }
  Xout[i] = mx;
  Xoutb[i] = __float2bfloat16(mx);
}

// ---------------- final mean over rows --------------------------------------
__global__ void meanrows_kernel(const float* __restrict__ Xin, float* __restrict__ out, int L) {
  int b = blockIdx.x, d = threadIdx.x;
  float s = 0.f;
  for (int t = 0; t < L; t++) s += Xin[((size_t)(b * L + t)) * 512 + d];
  out[b * 512 + d] = s / (float)L;
}

// ============================================================================
extern "C" void kernel_launch(void* const* d_in, const int* in_sizes, int n_in,
                              void* d_out, int out_size, void* d_ws, size_t ws_size,
                              hipStream_t stream) {
  const float* x_enc = (const float*)d_in[0];
  const float* tok_w = (const float*)d_in[1];
  const float* Wq = (const float*)d_in[2];
  const float* bq = (const float*)d_in[3];
  const float* Wk = (const float*)d_in[4];
  const float* bk = (const float*)d_in[5];
  const float* Wv = (const float*)d_in[6];
  const float* bv = (const float*)d_in[7];
  const float* Wo = (const float*)d_in[8];
  const float* bo = (const float*)d_in[9];
  const float* c1w = (const float*)d_in[10];
  const float* c1b = (const float*)d_in[11];
  const float* c2w = (const float*)d_in[12];
  const float* c2b = (const float*)d_in[13];
  const float* n1g = (const float*)d_in[14];
  const float* n1b = (const float*)d_in[15];
  const float* n2g = (const float*)d_in[16];
  const float* n2b = (const float*)d_in[17];
  const float* dcw = (const float*)d_in[18];
  const float* dcb = (const float*)d_in[19];
  const float* bng = (const float*)d_in[20];
  const float* bnb = (const float*)d_in[21];
  const float* fng = (const float*)d_in[22];
  const float* fnb = (const float*)d_in[23];

  const int B = 8, H = 8;
  const size_t NX = 4194304;  // 8*1024*512

  float* ws = (float*)d_ws;
  float* X    = ws;
  float* XLN  = ws + NX;
  float* Qf   = ws + 2 * NX;
  float* Kf   = ws + 3 * NX;
  float* Vf   = ws + 4 * NX;
  bf16* INb   = (bf16*)(ws + 5 * NX);
  bf16* ATTb  = (bf16*)(ws + 5 * NX + NX / 2);
  bf16* H2b   = (bf16*)Qf;
  bf16* XCOLb = (bf16*)Vf;
  float* Yc   = Qf;
  float* WB   = ws + 6 * NX;
  bf16* Wqb  = (bf16*)(WB);
  bf16* Wkb  = (bf16*)(WB + 131072);
  bf16* Wvb  = (bf16*)(WB + 262144);
  bf16* Wob  = (bf16*)(WB + 393216);
  bf16* c1wb = (bf16*)(WB + 524288);
  bf16* c2wb = (bf16*)(WB + 1048576);
  bf16* wcvb = (bf16*)(WB + 1572864);
  bf16* tokwb = (bf16*)(WB + 1966080);
  float* PE   = WB + 2015232;
  float* MBUF = PE + 524288;
  float* VMEAN = MBUF + 65536;
  float* BNACC = VMEAN + 4096;
  int* IDX = (int*)(BNACC + 1024);
  int* TOP = IDX + 35840;
  float* VPART = (float*)(TOP + 2240);   // [8][32][512]

  // ---- embedding as GEMM ----
  pe_kernel<<<1024, 512, 0, stream>>>(PE);
  tokperm_kernel<<<(512 * 192 + 255) / 256, 256, 0, stream>>>(tok_w, tokwb);
  im2col_e_kernel<<<(int)(((size_t)B * 1024 * 192 + 255) / 256), 256, 0, stream>>>(
      x_enc, INb, B, 1024);
  bgemm_kernel<<<dim3(64, 4), 256, 0, stream>>>(INb, tokwb, nullptr, PE, 1024,
                                                X, nullptr, 8192, 512, 192, 0, 0);
  cast4_kernel<<<4096, 256, 0, stream>>>(X, INb, 1048576);

  int L = 1024;
  for (int l = 0; l < 3; l++) {
    int U = (L == 256) ? 30 : 35;
    int rows = B * L;
    dim3 g512(rows / 128, 4);

    cast4_kernel<<<256, 256, 0, stream>>>(Wq + (size_t)l * 262144, Wqb, 65536);
    cast4_kernel<<<256, 256, 0, stream>>>(Wk + (size_t)l * 262144, Wkb, 65536);
    cast4_kernel<<<256, 256, 0, stream>>>(Wv + (size_t)l * 262144, Wvb, 65536);
    cast4_kernel<<<256, 256, 0, stream>>>(Wo + (size_t)l * 262144, Wob, 65536);
    cast4_kernel<<<1024, 256, 0, stream>>>(c1w + (size_t)l * 1048576, c1wb, 262144);
    cast4_kernel<<<1024, 256, 0, stream>>>(c2w + (size_t)l * 1048576, c2wb, 262144);
    if (l < 2)
      wperm_kernel<<<3072, 256, 0, stream>>>(dcw + (size_t)l * 786432, wcvb);

    bgemm_kernel<<<g512, 256, 0, stream>>>(INb, Wqb, bq + l * 512, nullptr, 0,
                                           Qf, nullptr, rows, 512, 512, 0, 0);
    bgemm_kernel<<<g512, 256, 0, stream>>>(INb, Wkb, bk + l * 512, nullptr, 0,
                                           Kf, nullptr, rows, 512, 512, 0, 0);
    bgemm_kernel<<<g512, 256, 0, stream>>>(INb, Wvb, bv + l * 512, nullptr, 0,
                                           Vf, nullptr, rows, 512, 512, 0, 0);

    int half = L * U / 2;
    idx_kernel<<<(half + 255) / 256, 256, 0, stream>>>(IDX, L, U, l);
    sparsity_kernel<<<(B * H * L + 3) / 4, 256, 0, stream>>>(Qf, Kf, IDX, MBUF, B, H, L, U);
    topk_kernel<<<B * H, 64, 0, stream>>>(MBUF, TOP, L, U);
    vmean_part_kernel<<<dim3(B, 32), 512, 0, stream>>>(Vf, VPART, L, 32);
    vmean_reduce_kernel<<<16, 256, 0, stream>>>(VPART, VMEAN, 32, L);
    bcast_ctx_kernel<<<(rows * 512) / 256, 256, 0, stream>>>(VMEAN, ATTb, B, L);
    attn_mfma_kernel<<<B * H, 256, 0, stream>>>(Qf, Kf, Vf, TOP, ATTb, B, H, L, U);

    bgemm_kernel<<<g512, 256, 0, stream>>>(ATTb, Wob, bo + l * 512, X, 0,
                                           X, nullptr, rows, 512, 512, 0, 0);
    ln_kernel<<<rows, 256, 0, stream>>>(X, n1g + l * 512, n1b + l * 512, XLN, INb, rows);
    bgemm_kernel<<<dim3(rows / 128, 16), 256, 0, stream>>>(
        INb, c1wb, c1b + l * 2048, nullptr, 0, nullptr, H2b, rows, 2048, 512, 1, 2);
    bgemm_kernel<<<g512, 256, 0, stream>>>(H2b, c2wb, c2b + l * 512, XLN, 0,
                                           X, nullptr, rows, 512, 2048, 0, 0);
    ln_kernel<<<rows, 256, 0, stream>>>(X, n2g + l * 512, n2b + l * 512, X, nullptr, rows);

    if (l < 2) {
      im2col_kernel<<<(int)(((size_t)rows * 1536) / 256), 256, 0, stream>>>(X, XCOLb, B, L);
      bgemm_kernel<<<g512, 256, 0, stream>>>(XCOLb, wcvb, dcb + l * 512, nullptr, 0,
                                             Yc, nullptr, rows, 512, 1536, 0, 0);
      zero_kernel<<<4, 256, 0, stream>>>(BNACC, 1024);
      bnstat_kernel<<<128, 256, 0, stream>>>(Yc, BNACC, rows);
      bnpool_kernel<<<(rows / 2 * 512) / 256, 256, 0, stream>>>(
          Yc, BNACC, bng + l * 512, bnb + l * 512, X, INb, B, L, rows);
      L >>= 1;
    }
  }

  int rowsF = B * L;  // L = 256
  ln_kernel<<<rowsF, 256, 0, stream>>>(X, fng, fnb, XLN, nullptr, rowsF);
  meanrows_kernel<<<B, 512, 0, stream>>>(XLN, (float*)d_out, L);
}

// Round 6
// 1073.367 us; speedup vs baseline: 3.2304x; 1.2806x over previous
//
#include <hip/hip_runtime.h>
#include <hip/hip_bf16.h>
#include <math.h>

typedef __hip_bfloat16 bf16;
typedef short bf16x8 __attribute__((ext_vector_type(8)));
typedef float f32x4 __attribute__((ext_vector_type(4)));

__device__ inline short f2bs(float x) {
  bf16 h = __float2bfloat16(x);
  return *reinterpret_cast<short*>(&h);
}

// ---------------- Threefry-2x32 (JAX-exact, 20 rounds) ----------------
__device__ inline void threefry2x32(unsigned k0, unsigned k1,
                                    unsigned x0, unsigned x1,
                                    unsigned& o0, unsigned& o1) {
  unsigned ks[3] = {k0, k1, k0 ^ k1 ^ 0x1BD11BDAu};
  const int rot[2][4] = {{13, 15, 26, 6}, {17, 29, 16, 24}};
  x0 += ks[0];
  x1 += ks[1];
  #pragma unroll
  for (int i = 0; i < 5; i++) {
    const int* r = rot[i & 1];
    #pragma unroll
    for (int j = 0; j < 4; j++) {
      x0 += x1;
      x1 = (x1 << r[j]) | (x1 >> (32 - r[j]));
      x1 ^= x0;
    }
    x0 += ks[(i + 1) % 3];
    x1 += ks[(i + 2) % 3] + (unsigned)(i + 1);
  }
  o0 = x0;
  o1 = x1;
}

__global__ void idx_kernel(int* __restrict__ idx, int L, int U, int layer) {
  int total = L * U, half = total / 2;
  int i = blockIdx.x * blockDim.x + threadIdx.x;
  if (i >= half) return;
  unsigned k0, k1;
  threefry2x32(0u, 42u, 0u, (unsigned)layer, k0, k1);
  unsigned o0, o1;
  threefry2x32(k0, k1, (unsigned)i, (unsigned)(half + i), o0, o1);
  idx[i] = (int)(o0 & (unsigned)(L - 1));
  idx[half + i] = (int)(o1 & (unsigned)(L - 1));
}

// ---------------- bf16 MFMA GEMM (templated tile): C = A @ W^T ... ----------
// BM x BN tile, BK=32, 4 waves (2x2), wave tile (BM/2)x(BN/2).
template <int BM, int BN>
__global__ __launch_bounds__(256) void bgemm_t(
    const bf16* __restrict__ A, const bf16* __restrict__ W,
    const float* __restrict__ bias, const float* __restrict__ R, int rmod,
    float* __restrict__ C, bf16* __restrict__ Cb,
    int M, int N, int K, int relu, int outmode) {
  constexpr int MR = BM / 32;  // 16-row fragments per wave (M)
  constexpr int NR = BN / 32;  // 16-col fragments per wave (N)
  __shared__ bf16 As[BM * 32];
  __shared__ bf16 Ws[BN * 32];
  int tid = threadIdx.x;
  int lane = tid & 63, w = tid >> 6;
  size_t row0 = (size_t)blockIdx.x * BM, col0 = (size_t)blockIdx.y * BN;
  int srow = (w << 4) + (lane >> 2);   // 0..63
  int scol = (lane & 3) << 3;
  const bf16* ag0 = A + (row0 + srow) * K + scol;
  const bf16* wg0 = W + (col0 + srow) * K + scol;
  int wb0 = (w << 9) + (lane << 3);    // 2048 elems per staging pass
  int wr = (w >> 1) * (BM / 2), wc = (w & 1) * (BN / 2);
  int fr = lane & 15, fk = (lane >> 4) << 3;
  f32x4 acc[MR][NR] = {};
  bf16x8 ra0, ra1, rw0, rw1;
  ra0 = *(const bf16x8*)ag0;
  if constexpr (BM == 128) ra1 = *(const bf16x8*)(ag0 + 64 * K);
  rw0 = *(const bf16x8*)wg0;
  if constexpr (BN == 128) rw1 = *(const bf16x8*)(wg0 + 64 * K);
  for (int k0 = 0; k0 < K; k0 += 32) {
    __syncthreads();
    *(bf16x8*)(As + wb0) = ra0;
    if constexpr (BM == 128) *(bf16x8*)(As + wb0 + 2048) = ra1;
    *(bf16x8*)(Ws + wb0) = rw0;
    if constexpr (BN == 128) *(bf16x8*)(Ws + wb0 + 2048) = rw1;
    if (k0 + 32 < K) {
      ag0 += 32; wg0 += 32;
      ra0 = *(const bf16x8*)ag0;
      if constexpr (BM == 128) ra1 = *(const bf16x8*)(ag0 + 64 * K);
      rw0 = *(const bf16x8*)wg0;
      if constexpr (BN == 128) rw1 = *(const bf16x8*)(wg0 + 64 * K);
    }
    __syncthreads();
    bf16x8 af[MR], bfv[NR];
    #pragma unroll
    for (int m = 0; m < MR; m++)
      af[m] = *(const bf16x8*)(As + (wr + m * 16 + fr) * 32 + fk);
    #pragma unroll
    for (int n = 0; n < NR; n++)
      bfv[n] = *(const bf16x8*)(Ws + (wc + n * 16 + fr) * 32 + fk);
    #pragma unroll
    for (int m = 0; m < MR; m++)
      #pragma unroll
      for (int n = 0; n < NR; n++)
        acc[m][n] = __builtin_amdgcn_mfma_f32_16x16x32_bf16(af[m], bfv[n], acc[m][n], 0, 0, 0);
  }
  int cr = (lane >> 4) << 2;
  int cc0 = lane & 15;
  #pragma unroll
  for (int m = 0; m < MR; m++) {
    #pragma unroll
    for (int n = 0; n < NR; n++) {
      #pragma unroll
      for (int r = 0; r < 4; r++) {
        size_t rr = row0 + wr + m * 16 + cr + r;
        size_t cc = col0 + wc + n * 16 + cc0;
        float v = acc[m][n][r];
        if (bias) v += bias[cc];
        if (R) v += rmod ? R[(rr % rmod) * N + cc] : R[rr * N + cc];
        if (relu) v = fmaxf(v, 0.f);
        if (outmode != 2) C[rr * N + cc] = v;
        if (outmode) Cb[rr * N + cc] = __float2bfloat16(v);
      }
    }
  }
}

// ---------------- weight/activation casts -----------------------------------
__global__ void cast4_kernel(const float* __restrict__ s, bf16* __restrict__ d, int n4) {
  int i = blockIdx.x * 256 + threadIdx.x;
  if (i >= n4) return;
  float4 v = ((const float4*)s)[i];
  d[i * 4 + 0] = __float2bfloat16(v.x);
  d[i * 4 + 1] = __float2bfloat16(v.y);
  d[i * 4 + 2] = __float2bfloat16(v.z);
  d[i * 4 + 3] = __float2bfloat16(v.w);
}

// dcw [o][c][k] -> wcol[o][k*512+c] bf16
__global__ void wperm_kernel(const float* __restrict__ w, bf16* __restrict__ wcol) {
  int i = blockIdx.x * 256 + threadIdx.x;
  if (i >= 512 * 1536) return;
  int o = i / 1536, r = i % 1536, k = r / 512, c = r % 512;
  wcol[i] = __float2bfloat16(w[o * 1536 + c * 3 + k]);
}

// tok_w [o][c][k] (c<64,k<3) -> [o][k*64+c] bf16
__global__ void tokperm_kernel(const float* __restrict__ w, bf16* __restrict__ d) {
  int i = blockIdx.x * 256 + threadIdx.x;
  if (i >= 512 * 192) return;
  int o = i / 192, r = i % 192, k = r / 64, c = r % 64;
  d[i] = __float2bfloat16(w[o * 192 + c * 3 + k]);
}

// PE table [1024][512] fp32
__global__ void pe_kernel(float* __restrict__ PE) {
  int t = blockIdx.x, o = threadIdx.x;
  int i2 = o >> 1;
  float div = expf((float)(2 * i2) * (-9.210340371976184f / 512.f));
  float ang = (float)t * div;
  PE[t * 512 + o] = (o & 1) ? cosf(ang) : sinf(ang);
}

// embedding im2col: x_enc -> [B*L, 192] bf16 (j = k*64+c), +1e-10
__global__ void im2col_e_kernel(const float* __restrict__ x, bf16* __restrict__ d,
                                int B, int L) {
  size_t i = (size_t)blockIdx.x * 256 + threadIdx.x;
  if (i >= (size_t)B * L * 192) return;
  int j = (int)(i % 192);
  size_t row = i / 192;
  int k = j >> 6, c = j & 63;
  int t = (int)(row % L), b = (int)(row / L);
  int ts = (t - 1 + k) & (L - 1);
  d[i] = __float2bfloat16(x[((size_t)(b * L + ts)) * 64 + c] + 1e-10f);
}

// ---------------- sparsity measure M: 16-lane cooperative gather dots -------
__global__ __launch_bounds__(256) void sparsity_kernel(
    const float* __restrict__ Q, const float* __restrict__ Kf,
    const int* __restrict__ idx, float* __restrict__ M,
    int B, int H, int L, int U) {
  int wid = blockIdx.x * 4 + (threadIdx.x >> 6);
  if (wid >= B * H * L) return;
  int lane = threadIdx.x & 63;
  int t = wid % L, h = (wid / L) % H, b = wid / (L * H);
  int ul = lane >> 4;
  int j = lane & 15;
  const float* qrow = Q + ((size_t)(b * L + t)) * 512 + h * 64;
  float4 q4 = *(const float4*)(qrow + j * 4);
  const float* kbase = Kf + (size_t)b * L * 512 + h * 64;
  const int* irow = idx + t * U;
  float mx = -INFINITY, sm = 0.f;
  int iters = (U + 3) >> 2;
  for (int i = 0; i < iters; i++) {
    int u = i * 4 + ul;
    bool valid = (u < U);
    int kt = valid ? irow[u] : 0;
    float4 k4 = *(const float4*)(kbase + (size_t)kt * 512 + j * 4);
    float part = q4.x * k4.x + q4.y * k4.y + q4.z * k4.z + q4.w * k4.w;
    #pragma unroll
    for (int off = 1; off < 16; off <<= 1) part += __shfl_xor(part, off);
    if (valid) { mx = fmaxf(mx, part); sm += part; }
  }
  #pragma unroll
  for (int off = 16; off < 64; off <<= 1) {
    mx = fmaxf(mx, __shfl_xor(mx, off));
    sm += __shfl_xor(sm, off);
  }
  if (lane == 0) M[wid] = mx - sm / (float)L;
}

// ---------------- top-k: 1024 threads/block, value-in-register argmax -------
__global__ __launch_bounds__(1024) void topk_kernel(
    const float* __restrict__ M, int* __restrict__ top, int L, int U) {
  __shared__ float wv[16];
  __shared__ int wi[16];
  __shared__ int best_s;
  int bh = blockIdx.x, tid = threadIdx.x;
  int lane = tid & 63, w = tid >> 6;
  float v = (tid < L) ? M[(size_t)bh * L + tid] : -INFINITY;
  int myt = tid;
  for (int it = 0; it < U; it++) {
    float bv = v;
    int bi = myt;
    #pragma unroll
    for (int off = 32; off; off >>= 1) {
      float ov = __shfl_xor(bv, off);
      int oi = __shfl_xor(bi, off);
      if (ov > bv || (ov == bv && oi < bi)) { bv = ov; bi = oi; }
    }
    if (lane == 0) { wv[w] = bv; wi[w] = bi; }
    __syncthreads();
    if (w == 0) {
      float v2 = (lane < 16) ? wv[lane] : -INFINITY;
      int i2 = (lane < 16) ? wi[lane] : 0x7fffffff;
      #pragma unroll
      for (int off = 8; off; off >>= 1) {
        float ov = __shfl_xor(v2, off);
        int oi = __shfl_xor(i2, off);
        if (ov > v2 || (ov == v2 && oi < i2)) { v2 = ov; i2 = oi; }
      }
      if (lane == 0) { best_s = i2; top[bh * U + it] = i2; }
    }
    __syncthreads();
    if (myt == best_s) v = -INFINITY;
  }
}

// ---------------- V mean: deterministic 2-stage -----------------------------
__global__ __launch_bounds__(512) void vmean_part_kernel(
    const float* __restrict__ V, float* __restrict__ VP, int L, int segs) {
  int b = blockIdx.x, s = blockIdx.y, c = threadIdx.x;
  int per = L / segs;
  const float* vb = V + ((size_t)(b * L + s * per)) * 512 + c;
  float acc = 0.f;
  for (int t = 0; t < per; t++) acc += vb[(size_t)t * 512];
  VP[((size_t)(b * segs + s)) * 512 + c] = acc;
}

__global__ void vmean_reduce_kernel(const float* __restrict__ VP, float* __restrict__ Vmean,
                                    int segs, int L) {
  int i = blockIdx.x * 256 + threadIdx.x;  // B*512
  if (i >= 8 * 512) return;
  int b = i >> 9, c = i & 511;
  float acc = 0.f;
  for (int s = 0; s < segs; s++) acc += VP[((size_t)(b * segs + s)) * 512 + c];
  Vmean[i] = acc / (float)L;
}

// ---------------- broadcast ctx = Vmean (bf16 out) ---------------------------
__global__ void bcast_ctx_kernel(const float* __restrict__ Vmean, bf16* __restrict__ ATTb,
                                 int B, int L) {
  size_t i = (size_t)blockIdx.x * 256 + threadIdx.x;
  if (i >= (size_t)B * L * 512) return;
  int c = (int)(i % 512);
  int b = (int)(i / ((size_t)512 * L));
  ATTb[i] = __float2bfloat16(Vmean[b * 512 + c]);
}

// ---------------- batched MFMA flash attention for top-U queries ------------
__global__ __launch_bounds__(256) void attn_mfma_kernel(
    const float* __restrict__ Qf, const float* __restrict__ Kf,
    const float* __restrict__ Vf, const int* __restrict__ top,
    bf16* __restrict__ ATTb, int B, int H, int L, int U) {
  __shared__ short q_lds[64 * 72];
  __shared__ short k_lds[64 * 72];
  __shared__ short vt_lds[64 * 72];
  __shared__ short p_lds[4][16 * 72];
  int bh = blockIdx.x;
  int h = bh & 7, b = bh >> 3;
  int tid = threadIdx.x;
  int lane = tid & 63, w = tid >> 6;
  int r = tid >> 2, q4 = tid & 3, c0 = q4 << 4;
  int fr = lane & 15, fk = (lane >> 4) << 3, g = lane >> 4;

  {
    short tmp[16];
    if (r < U) {
      int tq = top[bh * U + r];
      const float* src = Qf + ((size_t)(b * L + tq)) * 512 + h * 64 + c0;
      #pragma unroll
      for (int i = 0; i < 4; i++) {
        float4 v = ((const float4*)src)[i];
        tmp[i * 4 + 0] = f2bs(v.x); tmp[i * 4 + 1] = f2bs(v.y);
        tmp[i * 4 + 2] = f2bs(v.z); tmp[i * 4 + 3] = f2bs(v.w);
      }
    } else {
      #pragma unroll
      for (int i = 0; i < 16; i++) tmp[i] = 0;
    }
    *(bf16x8*)&q_lds[r * 72 + c0] = *(bf16x8*)&tmp[0];
    *(bf16x8*)&q_lds[r * 72 + c0 + 8] = *(bf16x8*)&tmp[8];
  }
  __syncthreads();
  bf16x8 aq0 = *(const bf16x8*)&q_lds[(w * 16 + fr) * 72 + fk];
  bf16x8 aq1 = *(const bf16x8*)&q_lds[(w * 16 + fr) * 72 + 32 + fk];

  f32x4 ctx[4] = {};
  float m_run[4], l_run[4];
  #pragma unroll
  for (int i = 0; i < 4; i++) { m_run[i] = -INFINITY; l_run[i] = 0.f; }

  for (int t0 = 0; t0 < L; t0 += 64) {
    __syncthreads();
    {
      const float* ks = Kf + ((size_t)(b * L + t0 + r)) * 512 + h * 64 + c0;
      const float* vs = Vf + ((size_t)(b * L + t0 + r)) * 512 + h * 64 + c0;
      short kt[16];
      #pragma unroll
      for (int i = 0; i < 4; i++) {
        float4 v = ((const float4*)ks)[i];
        kt[i * 4 + 0] = f2bs(v.x); kt[i * 4 + 1] = f2bs(v.y);
        kt[i * 4 + 2] = f2bs(v.z); kt[i * 4 + 3] = f2bs(v.w);
      }
      *(bf16x8*)&k_lds[r * 72 + c0] = *(bf16x8*)&kt[0];
      *(bf16x8*)&k_lds[r * 72 + c0 + 8] = *(bf16x8*)&kt[8];
      #pragma unroll
      for (int i = 0; i < 4; i++) {
        float4 v = ((const float4*)vs)[i];
        vt_lds[(c0 + i * 4 + 0) * 72 + r] = f2bs(v.x);
        vt_lds[(c0 + i * 4 + 1) * 72 + r] = f2bs(v.y);
        vt_lds[(c0 + i * 4 + 2) * 72 + r] = f2bs(v.z);
        vt_lds[(c0 + i * 4 + 3) * 72 + r] = f2bs(v.w);
      }
    }
    __syncthreads();
    f32x4 s[4];
    #pragma unroll
    for (int n = 0; n < 4; n++) {
      bf16x8 b0 = *(const bf16x8*)&k_lds[(n * 16 + fr) * 72 + fk];
      bf16x8 b1 = *(const bf16x8*)&k_lds[(n * 16 + fr) * 72 + 32 + fk];
      f32x4 z = {};
      z = __builtin_amdgcn_mfma_f32_16x16x32_bf16(aq0, b0, z, 0, 0, 0);
      s[n] = __builtin_amdgcn_mfma_f32_16x16x32_bf16(aq1, b1, z, 0, 0, 0);
    }
    #pragma unroll
    for (int n = 0; n < 4; n++)
      #pragma unroll
      for (int rg = 0; rg < 4; rg++) s[n][rg] *= 0.125f;
    #pragma unroll
    for (int rg = 0; rg < 4; rg++) {
      float tm = fmaxf(fmaxf(s[0][rg], s[1][rg]), fmaxf(s[2][rg], s[3][rg]));
      #pragma unroll
      for (int off = 1; off < 16; off <<= 1) tm = fmaxf(tm, __shfl_xor(tm, off));
      float mnew = fmaxf(m_run[rg], tm);
      float sc_old = expf(m_run[rg] - mnew);
      float rowsum = 0.f;
      #pragma unroll
      for (int n = 0; n < 4; n++) {
        float p = expf(s[n][rg] - mnew);
        s[n][rg] = p;
        rowsum += p;
      }
      #pragma unroll
      for (int off = 1; off < 16; off <<= 1) rowsum += __shfl_xor(rowsum, off);
      l_run[rg] = l_run[rg] * sc_old + rowsum;
      m_run[rg] = mnew;
      #pragma unroll
      for (int nd = 0; nd < 4; nd++) ctx[nd][rg] *= sc_old;
    }
    short* pw = p_lds[w];
    #pragma unroll
    for (int n = 0; n < 4; n++)
      #pragma unroll
      for (int rg = 0; rg < 4; rg++)
        pw[(g * 4 + rg) * 72 + n * 16 + fr] = f2bs(s[n][rg]);
    bf16x8 pa0 = *(const bf16x8*)&pw[fr * 72 + fk];
    bf16x8 pa1 = *(const bf16x8*)&pw[fr * 72 + 32 + fk];
    #pragma unroll
    for (int nd = 0; nd < 4; nd++) {
      bf16x8 v0 = *(const bf16x8*)&vt_lds[(nd * 16 + fr) * 72 + fk];
      bf16x8 v1 = *(const bf16x8*)&vt_lds[(nd * 16 + fr) * 72 + 32 + fk];
      ctx[nd] = __builtin_amdgcn_mfma_f32_16x16x32_bf16(pa0, v0, ctx[nd], 0, 0, 0);
      ctx[nd] = __builtin_amdgcn_mfma_f32_16x16x32_bf16(pa1, v1, ctx[nd], 0, 0, 0);
    }
  }
  #pragma unroll
  for (int rg = 0; rg < 4; rg++) {
    int qq = w * 16 + g * 4 + rg;
    if (qq < U) {
      int tq = top[bh * U + qq];
      float inv = 1.f / l_run[rg];
      #pragma unroll
      for (int nd = 0; nd < 4; nd++) {
        int d = nd * 16 + fr;
        ATTb[((size_t)(b * L + tq)) * 512 + h * 64 + d] =
            __float2bfloat16(ctx[nd][rg] * inv);
      }
    }
  }
}

// ---------------- row LayerNorm (+ optional bf16 out) ------------------------
__global__ __launch_bounds__(256) void ln_kernel(
    const float* __restrict__ Xin, const float* __restrict__ g,
    const float* __restrict__ bta, float* __restrict__ Xout,
    bf16* __restrict__ Xoutb, int rows) {
  __shared__ float red[256];
  int r = blockIdx.x, tid = threadIdx.x;
  const float* xr = Xin + (size_t)r * 512;
  float v0 = xr[tid], v1 = xr[tid + 256];
  red[tid] = v0 + v1;
  __syncthreads();
  for (int s = 128; s > 0; s >>= 1) {
    if (tid < s) red[tid] += red[tid + s];
    __syncthreads();
  }
  float mean = red[0] / 512.f;
  __syncthreads();
  float d0 = v0 - mean, d1 = v1 - mean;
  red[tid] = d0 * d0 + d1 * d1;
  __syncthreads();
  for (int s = 128; s > 0; s >>= 1) {
    if (tid < s) red[tid] += red[tid + s];
    __syncthreads();
  }
  float rs = rsqrtf(red[0] / 512.f + 1e-5f);
  float o0 = d0 * rs * g[tid] + bta[tid];
  float o1 = d1 * rs * g[tid + 256] + bta[tid + 256];
  float* out = Xout + (size_t)r * 512;
  out[tid] = o0;
  out[tid + 256] = o1;
  if (Xoutb) {
    Xoutb[(size_t)r * 512 + tid] = __float2bfloat16(o0);
    Xoutb[(size_t)r * 512 + tid + 256] = __float2bfloat16(o1);
  }
}

// ---------------- im2col for k=3 circular conv (bf16 out) -------------------
__global__ void im2col_kernel(const float* __restrict__ X, bf16* __restrict__ XCOL,
                              int B, int L) {
  size_t i = (size_t)blockIdx.x * 256 + threadIdx.x;
  size_t total = (size_t)B * L * 1536;
  if (i >= total) return;
  int c = (int)(i % 512);
  int k = (int)((i / 512) % 3);
  size_t row = i / 1536;
  int t = (int)(row % L), b = (int)(row / L);
  int ts = (t - 1 + k + L) % L;
  XCOL[i] = __float2bfloat16(X[((size_t)(b * L + ts)) * 512 + c]);
}

// ---------------- BatchNorm stats -------------------------------------------
__global__ void zero_kernel(float* p, int n) {
  int i = blockIdx.x * 256 + threadIdx.x;
  if (i < n) p[i] = 0.f;
}

__global__ __launch_bounds__(256) void bnstat_kernel(
    const float* __restrict__ Y, float* __restrict__ acc, int rows) {
  int tid = threadIdx.x;
  int c0 = tid, c1 = tid + 256;
  float s0 = 0, s1 = 0, q0 = 0, q1 = 0;
  for (int r = blockIdx.x; r < rows; r += gridDim.x) {
    float v0 = Y[(size_t)r * 512 + c0];
    float v1 = Y[(size_t)r * 512 + c1];
    s0 += v0; q0 += v0 * v0;
    s1 += v1; q1 += v1 * v1;
  }
  atomicAdd(&acc[c0], s0);
  atomicAdd(&acc[c1], s1);
  atomicAdd(&acc[512 + c0], q0);
  atomicAdd(&acc[512 + c1], q1);
}

// ---------------- fused BN + ELU + MaxPool(3,2,1) (+bf16 out) ---------------
__global__ void bnpool_kernel(const float* __restrict__ Y, const float* __restrict__ acc,
                              const float* __restrict__ g, const float* __restrict__ be,
                              float* __restrict__ Xout, bf16* __restrict__ Xoutb,
                              int B, int L, int rows) {
  int Lout = L / 2;
  size_t i = (size_t)blockIdx.x * 256 + threadIdx.x;
  if (i >= (size_t)B * Lout * 512) return;
  int c = (int)(i % 512);
  size_t orow = i / 512;
  int to = (int)(orow % Lout), b = (int)(orow / Lout);
  float mu = acc[c] / (float)rows;
  float var = acc[512 + c] / (float)rows - mu * mu;
  float rs = rsqrtf(var + 1e-5f) * g[c];
  float mx = -INFINITY;
  #pragma unroll
  for (int dj = -1; dj <= 1; dj++) {
    int j = 2 * to + dj;
    if (j < 0 || j >= L) continue;
    float v = (Y[((size_t)(b * L + j)) * 512 + c] - mu) * rs + be[c];
    v = v > 0.f ? v : expm1f(v);
    mx = fmaxf(mx, v);
  }
  Xout[i] = mx;
  Xoutb[i] = __float2bfloat16(mx);
}

// ---------------- final mean over rows --------------------------------------
__global__ void meanrows_kernel(const float* __restrict__ Xin, float* __restrict__ out, int L) {
  int b = blockIdx.x, d = threadIdx.x;
  float s = 0.f;
  for (int t = 0; t < L; t++) s += Xin[((size_t)(b * L + t)) * 512 + d];
  out[b * 512 + d] = s / (float)L;
}

// ============================================================================
extern "C" void kernel_launch(void* const* d_in, const int* in_sizes, int n_in,
                              void* d_out, int out_size, void* d_ws, size_t ws_size,
                              hipStream_t stream) {
  const float* x_enc = (const float*)d_in[0];
  const float* tok_w = (const float*)d_in[1];
  const float* Wq = (const float*)d_in[2];
  const float* bq = (const float*)d_in[3];
  const float* Wk = (const float*)d_in[4];
  const float* bk = (const float*)d_in[5];
  const float* Wv = (const float*)d_in[6];
  const float* bv = (const float*)d_in[7];
  const float* Wo = (const float*)d_in[8];
  const float* bo = (const float*)d_in[9];
  const float* c1w = (const float*)d_in[10];
  const float* c1b = (const float*)d_in[11];
  const float* c2w = (const float*)d_in[12];
  const float* c2b = (const float*)d_in[13];
  const float* n1g = (const float*)d_in[14];
  const float* n1b = (const float*)d_in[15];
  const float* n2g = (const float*)d_in[16];
  const float* n2b = (const float*)d_in[17];
  const float* dcw = (const float*)d_in[18];
  const float* dcb = (const float*)d_in[19];
  const float* bng = (const float*)d_in[20];
  const float* bnb = (const float*)d_in[21];
  const float* fng = (const float*)d_in[22];
  const float* fnb = (const float*)d_in[23];

  const int B = 8, H = 8;
  const size_t NX = 4194304;  // 8*1024*512

  float* ws = (float*)d_ws;
  float* X    = ws;
  float* XLN  = ws + NX;
  float* Qf   = ws + 2 * NX;
  float* Kf   = ws + 3 * NX;
  float* Vf   = ws + 4 * NX;
  bf16* INb   = (bf16*)(ws + 5 * NX);
  bf16* ATTb  = (bf16*)(ws + 5 * NX + NX / 2);
  bf16* H2b   = (bf16*)Qf;
  bf16* XCOLb = (bf16*)Vf;
  float* Yc   = Qf;
  float* WB   = ws + 6 * NX;
  bf16* Wqb  = (bf16*)(WB);
  bf16* Wkb  = (bf16*)(WB + 131072);
  bf16* Wvb  = (bf16*)(WB + 262144);
  bf16* Wob  = (bf16*)(WB + 393216);
  bf16* c1wb = (bf16*)(WB + 524288);
  bf16* c2wb = (bf16*)(WB + 1048576);
  bf16* wcvb = (bf16*)(WB + 1572864);
  bf16* tokwb = (bf16*)(WB + 1966080);
  float* PE   = WB + 2015232;
  float* MBUF = PE + 524288;
  float* VMEAN = MBUF + 65536;
  float* BNACC = VMEAN + 4096;
  int* IDX = (int*)(BNACC + 1024);
  int* TOP = IDX + 35840;
  float* VPART = (float*)(TOP + 2240);   // [8][32][512]

  // ---- embedding as GEMM ----
  pe_kernel<<<1024, 512, 0, stream>>>(PE);
  tokperm_kernel<<<(512 * 192 + 255) / 256, 256, 0, stream>>>(tok_w, tokwb);
  im2col_e_kernel<<<(int)(((size_t)B * 1024 * 192 + 255) / 256), 256, 0, stream>>>(
      x_enc, INb, B, 1024);
  bgemm_t<64, 64><<<dim3(128, 8), 256, 0, stream>>>(INb, tokwb, nullptr, PE, 1024,
                                                    X, nullptr, 8192, 512, 192, 0, 0);
  cast4_kernel<<<4096, 256, 0, stream>>>(X, INb, 1048576);

  int L = 1024;
  for (int l = 0; l < 3; l++) {
    int U = (L == 256) ? 30 : 35;
    int rows = B * L;
    dim3 g64(rows / 64, 8);

    cast4_kernel<<<256, 256, 0, stream>>>(Wq + (size_t)l * 262144, Wqb, 65536);
    cast4_kernel<<<256, 256, 0, stream>>>(Wk + (size_t)l * 262144, Wkb, 65536);
    cast4_kernel<<<256, 256, 0, stream>>>(Wv + (size_t)l * 262144, Wvb, 65536);
    cast4_kernel<<<256, 256, 0, stream>>>(Wo + (size_t)l * 262144, Wob, 65536);
    cast4_kernel<<<1024, 256, 0, stream>>>(c1w + (size_t)l * 1048576, c1wb, 262144);
    cast4_kernel<<<1024, 256, 0, stream>>>(c2w + (size_t)l * 1048576, c2wb, 262144);
    if (l < 2)
      wperm_kernel<<<3072, 256, 0, stream>>>(dcw + (size_t)l * 786432, wcvb);

    bgemm_t<64, 64><<<g64, 256, 0, stream>>>(INb, Wqb, bq + l * 512, nullptr, 0,
                                             Qf, nullptr, rows, 512, 512, 0, 0);
    bgemm_t<64, 64><<<g64, 256, 0, stream>>>(INb, Wkb, bk + l * 512, nullptr, 0,
                                             Kf, nullptr, rows, 512, 512, 0, 0);
    bgemm_t<64, 64><<<g64, 256, 0, stream>>>(INb, Wvb, bv + l * 512, nullptr, 0,
                                             Vf, nullptr, rows, 512, 512, 0, 0);

    int half = L * U / 2;
    idx_kernel<<<(half + 255) / 256, 256, 0, stream>>>(IDX, L, U, l);
    sparsity_kernel<<<(B * H * L + 3) / 4, 256, 0, stream>>>(Qf, Kf, IDX, MBUF, B, H, L, U);
    topk_kernel<<<B * H, 1024, 0, stream>>>(MBUF, TOP, L, U);
    vmean_part_kernel<<<dim3(B, 32), 512, 0, stream>>>(Vf, VPART, L, 32);
    vmean_reduce_kernel<<<16, 256, 0, stream>>>(VPART, VMEAN, 32, L);
    bcast_ctx_kernel<<<(rows * 512) / 256, 256, 0, stream>>>(VMEAN, ATTb, B, L);
    attn_mfma_kernel<<<B * H, 256, 0, stream>>>(Qf, Kf, Vf, TOP, ATTb, B, H, L, U);

    bgemm_t<64, 64><<<g64, 256, 0, stream>>>(ATTb, Wob, bo + l * 512, X, 0,
                                             X, nullptr, rows, 512, 512, 0, 0);
    ln_kernel<<<rows, 256, 0, stream>>>(X, n1g + l * 512, n1b + l * 512, XLN, INb, rows);
    bgemm_t<128, 128><<<dim3(rows / 128, 16), 256, 0, stream>>>(
        INb, c1wb, c1b + l * 2048, nullptr, 0, nullptr, H2b, rows, 2048, 512, 1, 2);
    bgemm_t<64, 64><<<g64, 256, 0, stream>>>(H2b, c2wb, c2b + l * 512, XLN, 0,
                                             X, nullptr, rows, 512, 2048, 0, 0);
    ln_kernel<<<rows, 256, 0, stream>>>(X, n2g + l * 512, n2b + l * 512, X, nullptr, rows);

    if (l < 2) {
      im2col_kernel<<<(int)(((size_t)rows * 1536) / 256), 256, 0, stream>>>(X, XCOLb, B, L);
      bgemm_t<64, 64><<<g64, 256, 0, stream>>>(XCOLb, wcvb, dcb + l * 512, nullptr, 0,
                                               Yc, nullptr, rows, 512, 1536, 0, 0);
      zero_kernel<<<4, 256, 0, stream>>>(BNACC, 1024);
      bnstat_kernel<<<128, 256, 0, stream>>>(Yc, BNACC, rows);
      bnpool_kernel<<<(rows / 2 * 512) / 256, 256, 0, stream>>>(
          Yc, BNACC, bng + l * 512, bnb + l * 512, X, INb, B, L, rows);
      L >>= 1;
    }
  }

  int rowsF = B * L;  // L = 256
  ln_kernel<<<rowsF, 256, 0, stream>>>(X, fng, fnb, XLN, nullptr, rowsF);
  meanrows_kernel<<<B, 512, 0, stream>>>(XLN, (float*)d_out, L);
}

// Round 7
// 947.068 us; speedup vs baseline: 3.6612x; 1.1334x over previous
//
#include <hip/hip_runtime.h>
#include <hip/hip_bf16.h>
#include <math.h>

typedef __hip_bfloat16 bf16;
typedef short bf16x8 __attribute__((ext_vector_type(8)));
typedef float f32x4 __attribute__((ext_vector_type(4)));

__device__ inline short f2bs(float x) {
  bf16 h = __float2bfloat16(x);
  return *reinterpret_cast<short*>(&h);
}

// ---------------- Threefry-2x32 (JAX-exact, 20 rounds) ----------------
__device__ inline void threefry2x32(unsigned k0, unsigned k1,
                                    unsigned x0, unsigned x1,
                                    unsigned& o0, unsigned& o1) {
  unsigned ks[3] = {k0, k1, k0 ^ k1 ^ 0x1BD11BDAu};
  const int rot[2][4] = {{13, 15, 26, 6}, {17, 29, 16, 24}};
  x0 += ks[0];
  x1 += ks[1];
  #pragma unroll
  for (int i = 0; i < 5; i++) {
    const int* r = rot[i & 1];
    #pragma unroll
    for (int j = 0; j < 4; j++) {
      x0 += x1;
      x1 = (x1 << r[j]) | (x1 >> (32 - r[j]));
      x1 ^= x0;
    }
    x0 += ks[(i + 1) % 3];
    x1 += ks[(i + 2) % 3] + (unsigned)(i + 1);
  }
  o0 = x0;
  o1 = x1;
}

__global__ void idx_kernel(int* __restrict__ idx, int L, int U, int layer) {
  int total = L * U, half = total / 2;
  int i = blockIdx.x * blockDim.x + threadIdx.x;
  if (i >= half) return;
  unsigned k0, k1;
  threefry2x32(0u, 42u, 0u, (unsigned)layer, k0, k1);
  unsigned o0, o1;
  threefry2x32(k0, k1, (unsigned)i, (unsigned)(half + i), o0, o1);
  idx[i] = (int)(o0 & (unsigned)(L - 1));
  idx[half + i] = (int)(o1 & (unsigned)(L - 1));
}

// ---------------- bf16 MFMA GEMM (templated tile): C = A @ W^T ... ----------
template <int BM, int BN>
__global__ __launch_bounds__(256) void bgemm_t(
    const bf16* __restrict__ A, const bf16* __restrict__ W,
    const float* __restrict__ bias, const float* __restrict__ R, int rmod,
    float* __restrict__ C, bf16* __restrict__ Cb,
    int M, int N, int K, int relu, int outmode) {
  constexpr int MR = BM / 32;
  constexpr int NR = BN / 32;
  __shared__ bf16 As[BM * 32];
  __shared__ bf16 Ws[BN * 32];
  int tid = threadIdx.x;
  int lane = tid & 63, w = tid >> 6;
  size_t row0 = (size_t)blockIdx.x * BM, col0 = (size_t)blockIdx.y * BN;
  int srow = (w << 4) + (lane >> 2);
  int scol = (lane & 3) << 3;
  const bf16* ag0 = A + (row0 + srow) * K + scol;
  const bf16* wg0 = W + (col0 + srow) * K + scol;
  int wb0 = (w << 9) + (lane << 3);
  int wr = (w >> 1) * (BM / 2), wc = (w & 1) * (BN / 2);
  int fr = lane & 15, fk = (lane >> 4) << 3;
  f32x4 acc[MR][NR] = {};
  bf16x8 ra0, ra1, rw0, rw1;
  ra0 = *(const bf16x8*)ag0;
  if constexpr (BM == 128) ra1 = *(const bf16x8*)(ag0 + 64 * K);
  rw0 = *(const bf16x8*)wg0;
  if constexpr (BN == 128) rw1 = *(const bf16x8*)(wg0 + 64 * K);
  for (int k0 = 0; k0 < K; k0 += 32) {
    __syncthreads();
    *(bf16x8*)(As + wb0) = ra0;
    if constexpr (BM == 128) *(bf16x8*)(As + wb0 + 2048) = ra1;
    *(bf16x8*)(Ws + wb0) = rw0;
    if constexpr (BN == 128) *(bf16x8*)(Ws + wb0 + 2048) = rw1;
    if (k0 + 32 < K) {
      ag0 += 32; wg0 += 32;
      ra0 = *(const bf16x8*)ag0;
      if constexpr (BM == 128) ra1 = *(const bf16x8*)(ag0 + 64 * K);
      rw0 = *(const bf16x8*)wg0;
      if constexpr (BN == 128) rw1 = *(const bf16x8*)(wg0 + 64 * K);
    }
    __syncthreads();
    bf16x8 af[MR], bfv[NR];
    #pragma unroll
    for (int m = 0; m < MR; m++)
      af[m] = *(const bf16x8*)(As + (wr + m * 16 + fr) * 32 + fk);
    #pragma unroll
    for (int n = 0; n < NR; n++)
      bfv[n] = *(const bf16x8*)(Ws + (wc + n * 16 + fr) * 32 + fk);
    #pragma unroll
    for (int m = 0; m < MR; m++)
      #pragma unroll
      for (int n = 0; n < NR; n++)
        acc[m][n] = __builtin_amdgcn_mfma_f32_16x16x32_bf16(af[m], bfv[n], acc[m][n], 0, 0, 0);
  }
  int cr = (lane >> 4) << 2;
  int cc0 = lane & 15;
  #pragma unroll
  for (int m = 0; m < MR; m++) {
    #pragma unroll
    for (int n = 0; n < NR; n++) {
      #pragma unroll
      for (int r = 0; r < 4; r++) {
        size_t rr = row0 + wr + m * 16 + cr + r;
        size_t cc = col0 + wc + n * 16 + cc0;
        float v = acc[m][n][r];
        if (bias) v += bias[cc];
        if (R) v += rmod ? R[(rr % rmod) * N + cc] : R[rr * N + cc];
        if (relu) v = fmaxf(v, 0.f);
        if (outmode != 2) C[rr * N + cc] = v;
        if (outmode) Cb[rr * N + cc] = __float2bfloat16(v);
      }
    }
  }
}

// ---------------- fused per-layer weight cast --------------------------------
// regions (float4 idx): [0,64K) Wq | [64K,128K) Wk | [128K,192K) Wv |
// [192K,256K) Wo | [256K,512K) c1w | [512K,768K) c2w
__global__ void castw_kernel(const float* __restrict__ wq, const float* __restrict__ wk,
                             const float* __restrict__ wv, const float* __restrict__ wo,
                             const float* __restrict__ c1, const float* __restrict__ c2,
                             bf16* __restrict__ wqkv, bf16* __restrict__ wob,
                             bf16* __restrict__ c1b, bf16* __restrict__ c2b) {
  int i = blockIdx.x * 256 + threadIdx.x;
  if (i >= 786432) return;
  const float* s;
  bf16* d;
  int j;
  if (i < 196608) { s = (i < 65536) ? wq : (i < 131072) ? wk : wv;
                    j = i & 65535; j += (i >> 16) * 65536; s = (i < 65536) ? wq : (i < 131072) ? wk : wv;
                    float4 v = ((const float4*)s)[i & 65535];
                    d = wqkv + (size_t)(i) * 4;
                    d[0] = __float2bfloat16(v.x); d[1] = __float2bfloat16(v.y);
                    d[2] = __float2bfloat16(v.z); d[3] = __float2bfloat16(v.w);
                    return; }
  if (i < 262144) { s = wo; j = i - 196608; d = wob + (size_t)j * 4; }
  else if (i < 524288) { s = c1; j = i - 262144; d = c1b + (size_t)j * 4; }
  else { s = c2; j = i - 524288; d = c2b + (size_t)j * 4; }
  float4 v = ((const float4*)s)[j];
  d[0] = __float2bfloat16(v.x); d[1] = __float2bfloat16(v.y);
  d[2] = __float2bfloat16(v.z); d[3] = __float2bfloat16(v.w);
}

__global__ void catb3_kernel(const float* __restrict__ a, const float* __restrict__ b,
                             const float* __restrict__ c, float* __restrict__ d) {
  int i = blockIdx.x * 256 + threadIdx.x;
  if (i >= 1536) return;
  d[i] = (i < 512) ? a[i] : (i < 1024) ? b[i - 512] : c[i - 1024];
}

// ---------------- cast X -> bf16 --------------------------------------------
__global__ void cast4_kernel(const float* __restrict__ s, bf16* __restrict__ d, int n4) {
  int i = blockIdx.x * 256 + threadIdx.x;
  if (i >= n4) return;
  float4 v = ((const float4*)s)[i];
  d[i * 4 + 0] = __float2bfloat16(v.x);
  d[i * 4 + 1] = __float2bfloat16(v.y);
  d[i * 4 + 2] = __float2bfloat16(v.z);
  d[i * 4 + 3] = __float2bfloat16(v.w);
}

// dcw [o][c][k] -> wcol[o][k*512+c] bf16
__global__ void wperm_kernel(const float* __restrict__ w, bf16* __restrict__ wcol) {
  int i = blockIdx.x * 256 + threadIdx.x;
  if (i >= 512 * 1536) return;
  int o = i / 1536, r = i % 1536, k = r / 512, c = r % 512;
  wcol[i] = __float2bfloat16(w[o * 1536 + c * 3 + k]);
}

// tok_w [o][c][k] (c<64,k<3) -> [o][k*64+c] bf16
__global__ void tokperm_kernel(const float* __restrict__ w, bf16* __restrict__ d) {
  int i = blockIdx.x * 256 + threadIdx.x;
  if (i >= 512 * 192) return;
  int o = i / 192, r = i % 192, k = r / 64, c = r % 64;
  d[i] = __float2bfloat16(w[o * 192 + c * 3 + k]);
}

// PE table [1024][512] fp32
__global__ void pe_kernel(float* __restrict__ PE) {
  int t = blockIdx.x, o = threadIdx.x;
  int i2 = o >> 1;
  float div = expf((float)(2 * i2) * (-9.210340371976184f / 512.f));
  float ang = (float)t * div;
  PE[t * 512 + o] = (o & 1) ? cosf(ang) : sinf(ang);
}

// embedding im2col: x_enc -> [B*L, 192] bf16 (j = k*64+c), +1e-10
__global__ void im2col_e_kernel(const float* __restrict__ x, bf16* __restrict__ d,
                                int B, int L) {
  size_t i = (size_t)blockIdx.x * 256 + threadIdx.x;
  if (i >= (size_t)B * L * 192) return;
  int j = (int)(i % 192);
  size_t row = i / 192;
  int k = j >> 6, c = j & 63;
  int t = (int)(row % L), b = (int)(row / L);
  int ts = (t - 1 + k) & (L - 1);
  d[i] = __float2bfloat16(x[((size_t)(b * L + ts)) * 64 + c] + 1e-10f);
}

// ---------------- sparsity measure M (QKV stride 1536) ----------------------
__global__ __launch_bounds__(256) void sparsity_kernel(
    const float* __restrict__ QKV, const int* __restrict__ idx,
    float* __restrict__ M, int B, int H, int L, int U) {
  int wid = blockIdx.x * 4 + (threadIdx.x >> 6);
  if (wid >= B * H * L) return;
  int lane = threadIdx.x & 63;
  int t = wid % L, h = (wid / L) % H, b = wid / (L * H);
  int ul = lane >> 4;
  int j = lane & 15;
  const float* qrow = QKV + ((size_t)(b * L + t)) * 1536 + h * 64;
  float4 q4 = *(const float4*)(qrow + j * 4);
  const float* kbase = QKV + (size_t)b * L * 1536 + 512 + h * 64;
  const int* irow = idx + t * U;
  float mx = -INFINITY, sm = 0.f;
  int iters = (U + 3) >> 2;
  for (int i = 0; i < iters; i++) {
    int u = i * 4 + ul;
    bool valid = (u < U);
    int kt = valid ? irow[u] : 0;
    float4 k4 = *(const float4*)(kbase + (size_t)kt * 1536 + j * 4);
    float part = q4.x * k4.x + q4.y * k4.y + q4.z * k4.z + q4.w * k4.w;
    #pragma unroll
    for (int off = 1; off < 16; off <<= 1) part += __shfl_xor(part, off);
    if (valid) { mx = fmaxf(mx, part); sm += part; }
  }
  #pragma unroll
  for (int off = 16; off < 64; off <<= 1) {
    mx = fmaxf(mx, __shfl_xor(mx, off));
    sm += __shfl_xor(sm, off);
  }
  if (lane == 0) M[wid] = mx - sm / (float)L;
}

// ---------------- top-k: 1024 threads/block, value-in-register argmax -------
__global__ __launch_bounds__(1024) void topk_kernel(
    const float* __restrict__ M, int* __restrict__ top, int L, int U) {
  __shared__ float wv[16];
  __shared__ int wi[16];
  __shared__ int best_s;
  int bh = blockIdx.x, tid = threadIdx.x;
  int lane = tid & 63, w = tid >> 6;
  float v = (tid < L) ? M[(size_t)bh * L + tid] : -INFINITY;
  int myt = tid;
  for (int it = 0; it < U; it++) {
    float bv = v;
    int bi = myt;
    #pragma unroll
    for (int off = 32; off; off >>= 1) {
      float ov = __shfl_xor(bv, off);
      int oi = __shfl_xor(bi, off);
      if (ov > bv || (ov == bv && oi < bi)) { bv = ov; bi = oi; }
    }
    if (lane == 0) { wv[w] = bv; wi[w] = bi; }
    __syncthreads();
    if (w == 0) {
      float v2 = (lane < 16) ? wv[lane] : -INFINITY;
      int i2 = (lane < 16) ? wi[lane] : 0x7fffffff;
      #pragma unroll
      for (int off = 8; off; off >>= 1) {
        float ov = __shfl_xor(v2, off);
        int oi = __shfl_xor(i2, off);
        if (ov > v2 || (ov == v2 && oi < i2)) { v2 = ov; i2 = oi; }
      }
      if (lane == 0) { best_s = i2; top[bh * U + it] = i2; }
    }
    __syncthreads();
    if (myt == best_s) v = -INFINITY;
  }
}

// ---------------- V mean: deterministic 2-stage (QKV stride 1536) -----------
__global__ __launch_bounds__(512) void vmean_part_kernel(
    const float* __restrict__ QKV, float* __restrict__ VP, int L, int segs) {
  int b = blockIdx.x, s = blockIdx.y, c = threadIdx.x;
  int per = L / segs;
  const float* vb = QKV + ((size_t)(b * L + s * per)) * 1536 + 1024 + c;
  float acc = 0.f;
  for (int t = 0; t < per; t++) acc += vb[(size_t)t * 1536];
  VP[((size_t)(b * segs + s)) * 512 + c] = acc;
}

__global__ void vmean_reduce_kernel(const float* __restrict__ VP, float* __restrict__ Vmean,
                                    int segs, int L) {
  int i = blockIdx.x * 256 + threadIdx.x;
  if (i >= 8 * 512) return;
  int b = i >> 9, c = i & 511;
  float acc = 0.f;
  for (int s = 0; s < segs; s++) acc += VP[((size_t)(b * segs + s)) * 512 + c];
  Vmean[i] = acc / (float)L;
}

// ---------------- broadcast ctx = Vmean (bf16 out) ---------------------------
__global__ void bcast_ctx_kernel(const float* __restrict__ Vmean, bf16* __restrict__ ATTb,
                                 int B, int L) {
  size_t i = (size_t)blockIdx.x * 256 + threadIdx.x;
  if (i >= (size_t)B * L * 512) return;
  int c = (int)(i % 512);
  int b = (int)(i / ((size_t)512 * L));
  ATTb[i] = __float2bfloat16(Vmean[b * 512 + c]);
}

// ---------------- batched MFMA flash attention (QKV stride 1536) ------------
__global__ __launch_bounds__(256) void attn_mfma_kernel(
    const float* __restrict__ QKV, const int* __restrict__ top,
    bf16* __restrict__ ATTb, int B, int H, int L, int U) {
  __shared__ short q_lds[64 * 72];
  __shared__ short k_lds[64 * 72];
  __shared__ short vt_lds[64 * 72];
  __shared__ short p_lds[4][16 * 72];
  int bh = blockIdx.x;
  int h = bh & 7, b = bh >> 3;
  int tid = threadIdx.x;
  int lane = tid & 63, w = tid >> 6;
  int r = tid >> 2, q4 = tid & 3, c0 = q4 << 4;
  int fr = lane & 15, fk = (lane >> 4) << 3, g = lane >> 4;

  {
    short tmp[16];
    if (r < U) {
      int tq = top[bh * U + r];
      const float* src = QKV + ((size_t)(b * L + tq)) * 1536 + h * 64 + c0;
      #pragma unroll
      for (int i = 0; i < 4; i++) {
        float4 v = ((const float4*)src)[i];
        tmp[i * 4 + 0] = f2bs(v.x); tmp[i * 4 + 1] = f2bs(v.y);
        tmp[i * 4 + 2] = f2bs(v.z); tmp[i * 4 + 3] = f2bs(v.w);
      }
    } else {
      #pragma unroll
      for (int i = 0; i < 16; i++) tmp[i] = 0;
    }
    *(bf16x8*)&q_lds[r * 72 + c0] = *(bf16x8*)&tmp[0];
    *(bf16x8*)&q_lds[r * 72 + c0 + 8] = *(bf16x8*)&tmp[8];
  }
  __syncthreads();
  bf16x8 aq0 = *(const bf16x8*)&q_lds[(w * 16 + fr) * 72 + fk];
  bf16x8 aq1 = *(const bf16x8*)&q_lds[(w * 16 + fr) * 72 + 32 + fk];

  f32x4 ctx[4] = {};
  float m_run[4], l_run[4];
  #pragma unroll
  for (int i = 0; i < 4; i++) { m_run[i] = -INFINITY; l_run[i] = 0.f; }

  for (int t0 = 0; t0 < L; t0 += 64) {
    __syncthreads();
    {
      const float* ks = QKV + ((size_t)(b * L + t0 + r)) * 1536 + 512 + h * 64 + c0;
      const float* vs = ks + 512;
      short kt[16];
      #pragma unroll
      for (int i = 0; i < 4; i++) {
        float4 v = ((const float4*)ks)[i];
        kt[i * 4 + 0] = f2bs(v.x); kt[i * 4 + 1] = f2bs(v.y);
        kt[i * 4 + 2] = f2bs(v.z); kt[i * 4 + 3] = f2bs(v.w);
      }
      *(bf16x8*)&k_lds[r * 72 + c0] = *(bf16x8*)&kt[0];
      *(bf16x8*)&k_lds[r * 72 + c0 + 8] = *(bf16x8*)&kt[8];
      #pragma unroll
      for (int i = 0; i < 4; i++) {
        float4 v = ((const float4*)vs)[i];
        vt_lds[(c0 + i * 4 + 0) * 72 + r] = f2bs(v.x);
        vt_lds[(c0 + i * 4 + 1) * 72 + r] = f2bs(v.y);
        vt_lds[(c0 + i * 4 + 2) * 72 + r] = f2bs(v.z);
        vt_lds[(c0 + i * 4 + 3) * 72 + r] = f2bs(v.w);
      }
    }
    __syncthreads();
    f32x4 s[4];
    #pragma unroll
    for (int n = 0; n < 4; n++) {
      bf16x8 b0 = *(const bf16x8*)&k_lds[(n * 16 + fr) * 72 + fk];
      bf16x8 b1 = *(const bf16x8*)&k_lds[(n * 16 + fr) * 72 + 32 + fk];
      f32x4 z = {};
      z = __builtin_amdgcn_mfma_f32_16x16x32_bf16(aq0, b0, z, 0, 0, 0);
      s[n] = __builtin_amdgcn_mfma_f32_16x16x32_bf16(aq1, b1, z, 0, 0, 0);
    }
    #pragma unroll
    for (int n = 0; n < 4; n++)
      #pragma unroll
      for (int rg = 0; rg < 4; rg++) s[n][rg] *= 0.125f;
    #pragma unroll
    for (int rg = 0; rg < 4; rg++) {
      float tm = fmaxf(fmaxf(s[0][rg], s[1][rg]), fmaxf(s[2][rg], s[3][rg]));
      #pragma unroll
      for (int off = 1; off < 16; off <<= 1) tm = fmaxf(tm, __shfl_xor(tm, off));
      float mnew = fmaxf(m_run[rg], tm);
      float sc_old = expf(m_run[rg] - mnew);
      float rowsum = 0.f;
      #pragma unroll
      for (int n = 0; n < 4; n++) {
        float p = expf(s[n][rg] - mnew);
        s[n][rg] = p;
        rowsum += p;
      }
      #pragma unroll
      for (int off = 1; off < 16; off <<= 1) rowsum += __shfl_xor(rowsum, off);
      l_run[rg] = l_run[rg] * sc_old + rowsum;
      m_run[rg] = mnew;
      #pragma unroll
      for (int nd = 0; nd < 4; nd++) ctx[nd][rg] *= sc_old;
    }
    short* pw = p_lds[w];
    #pragma unroll
    for (int n = 0; n < 4; n++)
      #pragma unroll
      for (int rg = 0; rg < 4; rg++)
        pw[(g * 4 + rg) * 72 + n * 16 + fr] = f2bs(s[n][rg]);
    bf16x8 pa0 = *(const bf16x8*)&pw[fr * 72 + fk];
    bf16x8 pa1 = *(const bf16x8*)&pw[fr * 72 + 32 + fk];
    #pragma unroll
    for (int nd = 0; nd < 4; nd++) {
      bf16x8 v0 = *(const bf16x8*)&vt_lds[(nd * 16 + fr) * 72 + fk];
      bf16x8 v1 = *(const bf16x8*)&vt_lds[(nd * 16 + fr) * 72 + 32 + fk];
      ctx[nd] = __builtin_amdgcn_mfma_f32_16x16x32_bf16(pa0, v0, ctx[nd], 0, 0, 0);
      ctx[nd] = __builtin_amdgcn_mfma_f32_16x16x32_bf16(pa1, v1, ctx[nd], 0, 0, 0);
    }
  }
  #pragma unroll
  for (int rg = 0; rg < 4; rg++) {
    int qq = w * 16 + g * 4 + rg;
    if (qq < U) {
      int tq = top[bh * U + qq];
      float inv = 1.f / l_run[rg];
      #pragma unroll
      for (int nd = 0; nd < 4; nd++) {
        int d = nd * 16 + fr;
        ATTb[((size_t)(b * L + tq)) * 512 + h * 64 + d] =
            __float2bfloat16(ctx[nd][rg] * inv);
      }
    }
  }
}

// ---------------- row LayerNorm (shuffle-reduce, 2 barriers) -----------------
__global__ __launch_bounds__(256) void ln_kernel(
    const float* __restrict__ Xin, const float* __restrict__ g,
    const float* __restrict__ bta, float* __restrict__ Xout,
    bf16* __restrict__ Xoutb, int rows) {
  __shared__ float part[8];
  int r = blockIdx.x, tid = threadIdx.x;
  int lane = tid & 63, w = tid >> 6;
  const float* xr = Xin + (size_t)r * 512;
  float v0 = xr[tid], v1 = xr[tid + 256];
  float s = v0 + v1;
  #pragma unroll
  for (int off = 1; off < 64; off <<= 1) s += __shfl_xor(s, off);
  if (lane == 0) part[w] = s;
  __syncthreads();
  float mean = (part[0] + part[1] + part[2] + part[3]) * (1.f / 512.f);
  float d0 = v0 - mean, d1 = v1 - mean;
  float q = d0 * d0 + d1 * d1;
  #pragma unroll
  for (int off = 1; off < 64; off <<= 1) q += __shfl_xor(q, off);
  if (lane == 0) part[4 + w] = q;
  __syncthreads();
  float var = (part[4] + part[5] + part[6] + part[7]) * (1.f / 512.f);
  float rs = rsqrtf(var + 1e-5f);
  float o0 = d0 * rs * g[tid] + bta[tid];
  float o1 = d1 * rs * g[tid + 256] + bta[tid + 256];
  float* out = Xout + (size_t)r * 512;
  out[tid] = o0;
  out[tid + 256] = o1;
  if (Xoutb) {
    Xoutb[(size_t)r * 512 + tid] = __float2bfloat16(o0);
    Xoutb[(size_t)r * 512 + tid + 256] = __float2bfloat16(o1);
  }
}

// ---------------- im2col for k=3 circular conv (bf16 out) -------------------
__global__ void im2col_kernel(const float* __restrict__ X, bf16* __restrict__ XCOL,
                              int B, int L) {
  size_t i = (size_t)blockIdx.x * 256 + threadIdx.x;
  size_t total = (size_t)B * L * 1536;
  if (i >= total) return;
  int c = (int)(i % 512);
  int k = (int)((i / 512) % 3);
  size_t row = i / 1536;
  int t = (int)(row % L), b = (int)(row / L);
  int ts = (t - 1 + k + L) % L;
  XCOL[i] = __float2bfloat16(X[((size_t)(b * L + ts)) * 512 + c]);
}

// ---------------- BatchNorm stats -------------------------------------------
__global__ void zero_kernel(float* p, int n) {
  int i = blockIdx.x * 256 + threadIdx.x;
  if (i < n) p[i] = 0.f;
}

__global__ __launch_bounds__(256) void bnstat_kernel(
    const float* __restrict__ Y, float* __restrict__ acc, int rows) {
  int tid = threadIdx.x;
  int c0 = tid, c1 = tid + 256;
  float s0 = 0, s1 = 0, q0 = 0, q1 = 0;
  for (int r = blockIdx.x; r < rows; r += gridDim.x) {
    float v0 = Y[(size_t)r * 512 + c0];
    float v1 = Y[(size_t)r * 512 + c1];
    s0 += v0; q0 += v0 * v0;
    s1 += v1; q1 += v1 * v1;
  }
  atomicAdd(&acc[c0], s0);
  atomicAdd(&acc[c1], s1);
  atomicAdd(&acc[512 + c0], q0);
  atomicAdd(&acc[512 + c1], q1);
}

// ---------------- fused BN + ELU + MaxPool(3,2,1) (+bf16 out) ---------------
__global__ void bnpool_kernel(const float* __restrict__ Y, const float* __restrict__ acc,
                              const float* __restrict__ g, const float* __restrict__ be,
                              float* __restrict__ Xout, bf16* __restrict__ Xoutb,
                              int B, int L, int rows) {
  int Lout = L / 2;
  size_t i = (size_t)blockIdx.x * 256 + threadIdx.x;
  if (i >= (size_t)B * Lout * 512) return;
  int c = (int)(i % 512);
  size_t orow = i / 512;
  int to = (int)(orow % Lout), b = (int)(orow / Lout);
  float mu = acc[c] / (float)rows;
  float var = acc[512 + c] / (float)rows - mu * mu;
  float rs = rsqrtf(var + 1e-5f) * g[c];
  float mx = -INFINITY;
  #pragma unroll
  for (int dj = -1; dj <= 1; dj++) {
    int j = 2 * to + dj;
    if (j < 0 || j >= L) continue;
    float v = (Y[((size_t)(b * L + j)) * 512 + c] - mu) * rs + be[c];
    v = v > 0.f ? v : expm1f(v);
    mx = fmaxf(mx, v);
  }
  Xout[i] = mx;
  Xoutb[i] = __float2bfloat16(mx);
}

// ---------------- final mean over rows: 2-stage ------------------------------
__global__ void meanrows_part_kernel(const float* __restrict__ Xin, float* __restrict__ MP,
                                     int L, int segs) {
  int b = blockIdx.x, s = blockIdx.y, d = threadIdx.x;
  int per = L / segs;
  const float* base = Xin + ((size_t)(b * L + s * per)) * 512 + d;
  float acc = 0.f;
  for (int t = 0; t < per; t++) acc += base[(size_t)t * 512];
  MP[((size_t)(b * segs + s)) * 512 + d] = acc;
}

__global__ void meanrows_red_kernel(const float* __restrict__ MP, float* __restrict__ out,
                                    int segs, int L) {
  int i = blockIdx.x * 256 + threadIdx.x;
  if (i >= 8 * 512) return;
  int b = i >> 9, c = i & 511;
  float acc = 0.f;
  for (int s = 0; s < segs; s++) acc += MP[((size_t)(b * segs + s)) * 512 + c];
  out[i] = acc / (float)L;
}

// ============================================================================
extern "C" void kernel_launch(void* const* d_in, const int* in_sizes, int n_in,
                              void* d_out, int out_size, void* d_ws, size_t ws_size,
                              hipStream_t stream) {
  const float* x_enc = (const float*)d_in[0];
  const float* tok_w = (const float*)d_in[1];
  const float* Wq = (const float*)d_in[2];
  const float* bq = (const float*)d_in[3];
  const float* Wk = (const float*)d_in[4];
  const float* bk = (const float*)d_in[5];
  const float* Wv = (const float*)d_in[6];
  const float* bv = (const float*)d_in[7];
  const float* Wo = (const float*)d_in[8];
  const float* bo = (const float*)d_in[9];
  const float* c1w = (const float*)d_in[10];
  const float* c1b = (const float*)d_in[11];
  const float* c2w = (const float*)d_in[12];
  const float* c2b = (const float*)d_in[13];
  const float* n1g = (const float*)d_in[14];
  const float* n1b = (const float*)d_in[15];
  const float* n2g = (const float*)d_in[16];
  const float* n2b = (const float*)d_in[17];
  const float* dcw = (const float*)d_in[18];
  const float* dcb = (const float*)d_in[19];
  const float* bng = (const float*)d_in[20];
  const float* bnb = (const float*)d_in[21];
  const float* fng = (const float*)d_in[22];
  const float* fnb = (const float*)d_in[23];

  const int B = 8, H = 8;
  const size_t NX = 4194304;  // 8*1024*512

  float* ws = (float*)d_ws;
  float* X    = ws;                      // fp32 [rows,512]
  float* XLN  = ws + NX;                 // fp32 [rows,512]
  float* QKVf = ws + 2 * NX;             // fp32 [rows,1536] (3*NX)
  bf16* H2b   = (bf16*)(ws + 2 * NX);    // bf16 [rows,2048] (aliases QKV, dead then)
  float* Yc   = ws + 2 * NX;             // conv out fp32 (aliases H2b, dead then)
  bf16* XCOLb = (bf16*)(ws + 4 * NX);    // bf16 [rows,1536]
  bf16* INb   = (bf16*)(ws + 5 * NX);    // bf16 [rows,512]
  bf16* ATTb  = (bf16*)(ws + 5 * NX + NX / 2);
  float* WB   = ws + 6 * NX;
  bf16* WQKVb = (bf16*)(WB);             // [1536,512] bf16 (Wq|Wk|Wv rows)
  bf16* Wob  = (bf16*)(WB + 393216);
  bf16* c1wb = (bf16*)(WB + 524288);
  bf16* c2wb = (bf16*)(WB + 1048576);
  bf16* wcvb = (bf16*)(WB + 1572864);
  bf16* tokwb = (bf16*)(WB + 1966080);
  float* PE   = WB + 2015232;
  float* MBUF = PE + 524288;
  float* VMEAN = MBUF + 65536;
  float* BNACC = VMEAN + 4096;
  int* IDX = (int*)(BNACC + 1024);
  int* TOP = IDX + 35840;
  float* VPART = (float*)(TOP + 2240);   // [8][32][512] (also meanrows partials)
  float* BQKV = VPART + 131072;          // [1536]

  // ---- embedding as GEMM ----
  pe_kernel<<<1024, 512, 0, stream>>>(PE);
  tokperm_kernel<<<(512 * 192 + 255) / 256, 256, 0, stream>>>(tok_w, tokwb);
  im2col_e_kernel<<<(int)(((size_t)B * 1024 * 192 + 255) / 256), 256, 0, stream>>>(
      x_enc, INb, B, 1024);
  bgemm_t<64, 64><<<dim3(128, 8), 256, 0, stream>>>(INb, tokwb, nullptr, PE, 1024,
                                                    X, nullptr, 8192, 512, 192, 0, 0);
  cast4_kernel<<<4096, 256, 0, stream>>>(X, INb, 1048576);

  int L = 1024;
  for (int l = 0; l < 3; l++) {
    int U = (L == 256) ? 30 : 35;
    int rows = B * L;
    dim3 g64(rows / 64, 8);

    castw_kernel<<<3072, 256, 0, stream>>>(
        Wq + (size_t)l * 262144, Wk + (size_t)l * 262144, Wv + (size_t)l * 262144,
        Wo + (size_t)l * 262144, c1w + (size_t)l * 1048576, c2w + (size_t)l * 1048576,
        WQKVb, Wob, c1wb, c2wb);
    catb3_kernel<<<6, 256, 0, stream>>>(bq + l * 512, bk + l * 512, bv + l * 512, BQKV);
    if (l < 2)
      wperm_kernel<<<3072, 256, 0, stream>>>(dcw + (size_t)l * 786432, wcvb);

    // merged QKV projection: [rows,1536]
    bgemm_t<64, 64><<<dim3(rows / 64, 24), 256, 0, stream>>>(
        INb, WQKVb, BQKV, nullptr, 0, QKVf, nullptr, rows, 1536, 512, 0, 0);

    int half = L * U / 2;
    idx_kernel<<<(half + 255) / 256, 256, 0, stream>>>(IDX, L, U, l);
    sparsity_kernel<<<(B * H * L + 3) / 4, 256, 0, stream>>>(QKVf, IDX, MBUF, B, H, L, U);
    topk_kernel<<<B * H, 1024, 0, stream>>>(MBUF, TOP, L, U);
    vmean_part_kernel<<<dim3(B, 32), 512, 0, stream>>>(QKVf, VPART, L, 32);
    vmean_reduce_kernel<<<16, 256, 0, stream>>>(VPART, VMEAN, 32, L);
    bcast_ctx_kernel<<<(rows * 512) / 256, 256, 0, stream>>>(VMEAN, ATTb, B, L);
    attn_mfma_kernel<<<B * H, 256, 0, stream>>>(QKVf, TOP, ATTb, B, H, L, U);

    bgemm_t<64, 64><<<g64, 256, 0, stream>>>(ATTb, Wob, bo + l * 512, X, 0,
                                             X, nullptr, rows, 512, 512, 0, 0);
    ln_kernel<<<rows, 256, 0, stream>>>(X, n1g + l * 512, n1b + l * 512, XLN, INb, rows);
    bgemm_t<64, 64><<<dim3(rows / 64, 32), 256, 0, stream>>>(
        INb, c1wb, c1b + l * 2048, nullptr, 0, nullptr, H2b, rows, 2048, 512, 1, 2);
    bgemm_t<64, 64><<<g64, 256, 0, stream>>>(H2b, c2wb, c2b + l * 512, XLN, 0,
                                             X, nullptr, rows, 512, 2048, 0, 0);
    ln_kernel<<<rows, 256, 0, stream>>>(X, n2g + l * 512, n2b + l * 512, X, nullptr, rows);

    if (l < 2) {
      im2col_kernel<<<(int)(((size_t)rows * 1536) / 256), 256, 0, stream>>>(X, XCOLb, B, L);
      bgemm_t<64, 64><<<g64, 256, 0, stream>>>(XCOLb, wcvb, dcb + l * 512, nullptr, 0,
                                               Yc, nullptr, rows, 512, 1536, 0, 0);
      zero_kernel<<<4, 256, 0, stream>>>(BNACC, 1024);
      bnstat_kernel<<<128, 256, 0, stream>>>(Yc, BNACC, rows);
      bnpool_kernel<<<(rows / 2 * 512) / 256, 256, 0, stream>>>(
          Yc, BNACC, bng + l * 512, bnb + l * 512, X, INb, B, L, rows);
      L >>= 1;
    }
  }

  int rowsF = B * L;  // L = 256
  ln_kernel<<<rowsF, 256, 0, stream>>>(X, fng, fnb, XLN, nullptr, rowsF);
  meanrows_part_kernel<<<dim3(8, 8), 512, 0, stream>>>(XLN, VPART, L, 8);
  meanrows_red_kernel<<<16, 256, 0, stream>>>(VPART, (float*)d_out, 8, L);
}